// Round 8
// baseline (1269.181 us; speedup 1.0000x reference)
//
#include <hip/hip_runtime.h>
#include <hip/hip_bf16.h>
#include <math.h>

#define N_NODES 10000
#define N_EDGES 80000
#define N_ORI   12
#define N_ROWS  (N_NODES * N_ORI)

typedef __attribute__((ext_vector_type(8))) short bfrag;   // 8 bf16 = 4 VGPRs
typedef __attribute__((ext_vector_type(4))) float f32x4;

__device__ __forceinline__ float gelu_f(float x) {
    return 0.5f * x * (1.0f + erff(x * 0.70710678118654752440f));
}
__device__ __forceinline__ short f2bf(float x) {
    __hip_bfloat16 h = __float2bfloat16(x);
    return *reinterpret_cast<short*>(&h);
}

// ---------------------------------------------------------------------------
// CSR build: histogram by dst -> exclusive scan -> fill perm/srcOf.
// ---------------------------------------------------------------------------
__global__ __launch_bounds__(256) void csr_count(
    const int* __restrict__ ei, int* __restrict__ deg)
{
    int e = blockIdx.x*256 + threadIdx.x;
    if (e < N_EDGES) atomicAdd(&deg[ei[N_EDGES + e]], 1);
}

__global__ __launch_bounds__(256) void csr_scan(
    const int* __restrict__ deg, int* __restrict__ rp, int* __restrict__ wp)
{
    __shared__ int part[256];
    __shared__ int sbase[257];
    int t = threadIdx.x;
    int cs = t*40;
    int sum = 0;
    for (int i = 0; i < 40; i++) { int idx = cs+i; if (idx < N_NODES) sum += deg[idx]; }
    part[t] = sum;
    __syncthreads();
    if (t == 0) {
        int run = 0;
        for (int i = 0; i < 256; i++) { sbase[i] = run; run += part[i]; }
        sbase[256] = run;
    }
    __syncthreads();
    int run = sbase[t];
    for (int i = 0; i < 40; i++) {
        int idx = cs+i;
        if (idx < N_NODES) { rp[idx] = run; wp[idx] = run; run += deg[idx]; }
    }
    if (t == 0) rp[N_NODES] = sbase[256];
}

__global__ __launch_bounds__(256) void csr_fill(
    const int* __restrict__ ei, int* __restrict__ wp,
    int* __restrict__ perm, int* __restrict__ srcOf)
{
    int e = blockIdx.x*256 + threadIdx.x;
    if (e >= N_EDGES) return;
    int dn = ei[N_EDGES + e];
    int j = atomicAdd(&wp[dn], 1);
    perm[j] = e;
    srcOf[j] = ei[e];
}

// ---------------------------------------------------------------------------
// K0: weight prep (unchanged).
// ---------------------------------------------------------------------------
__global__ __launch_bounds__(256) void prep_weights(
    const float* __restrict__ W1, const float* __restrict__ W2,
    const float* __restrict__ Wb1, const float* __restrict__ Wb2,
    const float* __restrict__ Wk,
    short* __restrict__ W1B, short* __restrict__ W2B,
    short* __restrict__ W1K, short* __restrict__ W2K,
    short* __restrict__ WkB)
{
    if (blockIdx.x < 2) {
        int l = blockIdx.x;
        const float* w1 = W1 + l*16384; short* w1b = W1B + l*16384;
        const float* w2 = W2 + l*16384; short* w2b = W2B + l*16384;
        for (int i = threadIdx.x; i < 16384; i += 256) {
            int k = i >> 8, t = i & 255;
            w1b[t*64 + k] = f2bf(w1[i]);
            int t2 = i >> 6, c = i & 63;
            w2b[c*256 + t2] = f2bf(w2[i]);
        }
    } else if (blockIdx.x == 2) {
        for (int i = threadIdx.x; i < 2048; i += 256) {
            int t = i >> 5, k = i & 31;
            W1K[i] = (k < 30) ? f2bf(Wb1[k*64 + t]) : (short)0;
        }
        for (int i = threadIdx.x; i < 4096; i += 256) {
            int c = i >> 6, t = i & 63;
            W2K[i] = f2bf(Wb2[t*64 + c]);
        }
    } else {
        for (int i = threadIdx.x; i < 8192; i += 256) {
            int l = i >> 12, rem = i & 4095, k = rem >> 6, c = rem & 63;
            WkB[l*4096 + c*64 + k] = f2bf(Wk[l*4096 + k*64 + c]);
        }
    }
}

// ---------------------------------------------------------------------------
// K1: kb_ori MLP + fk (unchanged)
// ---------------------------------------------------------------------------
__global__ __launch_bounds__(64) void ori_kernel(
    const float* __restrict__ ori, const float* __restrict__ Wo1,
    const float* __restrict__ bo1, const float* __restrict__ Wo2,
    const float* __restrict__ bo2, const float* __restrict__ Wf,
    float* __restrict__ fkb)
{
    __shared__ float sh[64];
    __shared__ float skb[64];
    int i = blockIdx.x / 12, j = blockIdx.x % 12;
    int lane = threadIdx.x;
    float s = ori[3*i]*ori[3*j] + ori[3*i+1]*ori[3*j+1] + ori[3*i+2]*ori[3*j+2];
    float p1 = s, p2 = s*s, p3 = p2*s, p4 = p3*s;
    float acc = bo1[lane] + p1*Wo1[lane] + p2*Wo1[64+lane] + p3*Wo1[128+lane] + p4*Wo1[192+lane];
    sh[lane] = gelu_f(acc);
    __syncthreads();
    float acc2 = bo2[lane];
    #pragma unroll
    for (int k = 0; k < 64; k++) acc2 += sh[k] * Wo2[k*64 + lane];
    skb[lane] = gelu_f(acc2);
    __syncthreads();
    for (int l = 0; l < 2; l++) {
        float a = 0.f;
        #pragma unroll
        for (int k = 0; k < 64; k++) a += skb[k] * Wf[l*4096 + k*64 + lane];
        fkb[l*9216 + i*768 + j*64 + lane] = a;
    }
}

// ---------------------------------------------------------------------------
// K2: x = f @ We (unchanged)
// ---------------------------------------------------------------------------
__global__ __launch_bounds__(256) void embed_kernel(
    const float* __restrict__ f, const float* __restrict__ We, float* __restrict__ xe)
{
    int v = blockIdx.x*4 + (threadIdx.x >> 6);
    int lane = threadIdx.x & 63;
    if (v >= N_NODES) return;
    float acc = 0.f;
    #pragma unroll
    for (int k = 0; k < 16; k++) acc += f[v*16 + k] * We[k*64 + lane];
    xe[v*64 + lane] = acc;
}

// ---------------------------------------------------------------------------
// Packed bf16 store of one MFMA C column-group: lanes m16%4==0 store 8B
// (4 consecutive cols) -> full 128B rows, no partial sectors.
// ---------------------------------------------------------------------------
__device__ __forceinline__ void store_bf16_packed(
    __hip_bfloat16* base, int row64, int colBase, int m16, float val)
{
    int my = (int)(unsigned short)f2bf(val);
    int p1 = __shfl_xor(my, 1);
    int packed01 = my | (p1 << 16);
    int p2 = __shfl_xor(packed01, 2);
    if ((m16 & 3) == 0) {
        int2 st; st.x = packed01; st.y = p2;
        *(int2*)((short*)base + (size_t)row64*64 + colBase + m16) = st;
    }
}

// ---------------------------------------------------------------------------
// K3 (v4): kb MLP via MFMA, rows in DST-SORTED order.
// mode=1 (full ws): store akb0 AND akb1 bf16 (no atomics anywhere).
// mode=0 (fallback): fused atomic scatter for layer 0 + akb1 store (r7 path).
// ---------------------------------------------------------------------------
__global__ __launch_bounds__(256, 2) void kb_mfma(
    const float* __restrict__ pos, const float* __restrict__ ori,
    const short* __restrict__ W1K, const float* __restrict__ bb1,
    const short* __restrict__ W2K, const float* __restrict__ bb2,
    const short* __restrict__ WkB, const int* __restrict__ ei,
    const int* __restrict__ perm,
    const float* __restrict__ xe, float* __restrict__ x1a,
    __hip_bfloat16* __restrict__ akb0, __hip_bfloat16* __restrict__ akb1,
    int mode)
{
    __shared__ short sF[256*40];
    __shared__ short sH[256*72];
    __shared__ float sEnv[256];

    int tid = threadIdx.x;
    int blockRow = blockIdx.x * 256;

    // ---- Phase A: features (row -> sorted edge j -> orig edge e) ----
    {
        int row = blockRow + tid;
        int j = row / 12, o = row - j*12;
        int e = perm[j];
        int sn = ei[e], dn = ei[N_EDGES + e];
        float rx = pos[sn*3+0] - pos[dn*3+0];
        float ry = pos[sn*3+1] - pos[dn*3+1];
        float rz = pos[sn*3+2] - pos[dn*3+2];
        float d  = sqrtf(rx*rx + ry*ry + rz*rz);
        float u2 = d*d, u4 = u2*u2, u6 = u4*u2;
        float env = (d < 1.0f) ? (1.0f - 28.0f*u6 + 48.0f*u6*d - 21.0f*u6*u2) : 0.0f;
        sEnv[tid] = env;

        float ox = ori[3*o], oy = ori[3*o+1], oz = ori[3*o+2];
        float a  = rx*ox + ry*oy + rz*oz;
        float qx = rx - a*ox, qy = ry - a*oy, qz = rz - a*oz;
        float b  = sqrtf(qx*qx + qy*qy + qz*qz);

        float fv[32];
        fv[0] = a; fv[1] = b;
        fv[2] = a*a; fv[3] = a*b; fv[4] = b*a; fv[5] = b*b;
        #pragma unroll
        for (int i = 0; i < 4; i++) { fv[6+2*i] = fv[2+i]*a; fv[7+2*i] = fv[2+i]*b; }
        #pragma unroll
        for (int i = 0; i < 8; i++) { fv[14+2*i] = fv[6+i]*a; fv[15+2*i] = fv[6+i]*b; }
        fv[30] = 0.f; fv[31] = 0.f;

        short* dst = sF + tid*40;
        #pragma unroll
        for (int blk = 0; blk < 4; blk++) {
            union { short s[8]; int4 v4; } u;
            #pragma unroll
            for (int jj = 0; jj < 8; jj++) u.s[jj] = f2bf(fv[blk*8 + jj]);
            *(int4*)(dst + blk*8) = u.v4;
        }
    }
    __syncthreads();

    int w = tid >> 6, l = tid & 63;
    int m16 = l & 15, q = l >> 4;

    // ---- FFN1: K=32 ----
    bfrag a1[4];
    #pragma unroll
    for (int mt = 0; mt < 4; mt++)
        a1[mt] = *(const bfrag*)(sF + ((w*4 + mt)*16 + m16)*40 + q*8);

    #pragma unroll
    for (int nt = 0; nt < 4; nt++) {
        bfrag bb = *(const bfrag*)(W1K + (nt*16 + m16)*32 + q*8);
        float bias = bb1[nt*16 + m16];
        #pragma unroll
        for (int mt = 0; mt < 4; mt++) {
            f32x4 acc = (f32x4){0.f,0.f,0.f,0.f};
            acc = __builtin_amdgcn_mfma_f32_16x16x32_bf16(a1[mt], bb, acc, 0, 0, 0);
            #pragma unroll
            for (int r = 0; r < 4; r++) {
                int rl = (w*4 + mt)*16 + q*4 + r;
                sH[rl*72 + nt*16 + m16] = f2bf(gelu_f(acc[r] + bias));
            }
        }
    }
    __syncthreads();

    // ---- FFN2: K=64 -> kb = gelu(.)*env back into sH (wave-local rows) ----
    bfrag a2[4][2];
    #pragma unroll
    for (int mt = 0; mt < 4; mt++)
        #pragma unroll
        for (int kc = 0; kc < 2; kc++)
            a2[mt][kc] = *(const bfrag*)(sH + ((w*4 + mt)*16 + m16)*72 + kc*32 + q*8);

    #pragma unroll
    for (int nt = 0; nt < 4; nt++) {
        f32x4 acc[4];
        #pragma unroll
        for (int mt = 0; mt < 4; mt++) acc[mt] = (f32x4){0.f,0.f,0.f,0.f};
        #pragma unroll
        for (int kc = 0; kc < 2; kc++) {
            bfrag bb = *(const bfrag*)(W2K + (nt*16 + m16)*64 + kc*32 + q*8);
            #pragma unroll
            for (int mt = 0; mt < 4; mt++)
                acc[mt] = __builtin_amdgcn_mfma_f32_16x16x32_bf16(a2[mt][kc], bb, acc[mt], 0, 0, 0);
        }
        float bias = bb2[nt*16 + m16];
        #pragma unroll
        for (int mt = 0; mt < 4; mt++) {
            #pragma unroll
            for (int r = 0; r < 4; r++) {
                int rl = (w*4 + mt)*16 + q*4 + r;
                sH[rl*72 + nt*16 + m16] = f2bf(gelu_f(acc[mt][r] + bias) * sEnv[rl]);
            }
        }
    }
    // wave-local sH rows: intra-wave DS ordering suffices, no barrier.

    // ---- akb GEMMs: kb @ Wk[l] ----
    bfrag a3[4][2];
    #pragma unroll
    for (int mt = 0; mt < 4; mt++)
        #pragma unroll
        for (int kc = 0; kc < 2; kc++)
            a3[mt][kc] = *(const bfrag*)(sH + ((w*4 + mt)*16 + m16)*72 + kc*32 + q*8);

    if (mode == 1) {
        // layer 0: store akb0 bf16 (packed)
        #pragma unroll
        for (int nt = 0; nt < 4; nt++) {
            f32x4 acc[4];
            #pragma unroll
            for (int mt = 0; mt < 4; mt++) acc[mt] = (f32x4){0.f,0.f,0.f,0.f};
            #pragma unroll
            for (int kc = 0; kc < 2; kc++) {
                bfrag bb = *(const bfrag*)(WkB + (nt*16 + m16)*64 + kc*32 + q*8);
                #pragma unroll
                for (int mt = 0; mt < 4; mt++)
                    acc[mt] = __builtin_amdgcn_mfma_f32_16x16x32_bf16(a3[mt][kc], bb, acc[mt], 0, 0, 0);
            }
            #pragma unroll
            for (int mt = 0; mt < 4; mt++)
                #pragma unroll
                for (int r = 0; r < 4; r++) {
                    int R = blockRow + (w*4 + mt)*16 + q*4 + r;
                    store_bf16_packed(akb0, R, nt*16, m16, acc[mt][r]);
                }
        }
    } else {
        // fallback: fused atomic scatter for layer 0
        int oArr[4][4], snArr[4][4], dnArr[4][4];
        #pragma unroll
        for (int mt = 0; mt < 4; mt++)
            #pragma unroll
            for (int r = 0; r < 4; r++) {
                int R = blockRow + (w*4 + mt)*16 + q*4 + r;
                int j = R / 12;
                int e = perm[j];
                oArr[mt][r] = R - j*12;
                snArr[mt][r] = ei[e]; dnArr[mt][r] = ei[N_EDGES + e];
            }
        #pragma unroll
        for (int nt = 0; nt < 4; nt++) {
            f32x4 acc[4];
            #pragma unroll
            for (int mt = 0; mt < 4; mt++) acc[mt] = (f32x4){0.f,0.f,0.f,0.f};
            #pragma unroll
            for (int kc = 0; kc < 2; kc++) {
                bfrag bb = *(const bfrag*)(WkB + (nt*16 + m16)*64 + kc*32 + q*8);
                #pragma unroll
                for (int mt = 0; mt < 4; mt++)
                    acc[mt] = __builtin_amdgcn_mfma_f32_16x16x32_bf16(a3[mt][kc], bb, acc[mt], 0, 0, 0);
            }
            int col = nt*16 + m16;
            #pragma unroll
            for (int mt = 0; mt < 4; mt++)
                #pragma unroll
                for (int r = 0; r < 4; r++) {
                    float val = acc[mt][r] * xe[snArr[mt][r]*64 + col];
                    atomicAdd(&x1a[(size_t)dnArr[mt][r]*768 + oArr[mt][r]*64 + col], val);
                }
        }
    }

    // layer 1: akb1 stored bf16 (packed) at sorted row index
    #pragma unroll
    for (int nt = 0; nt < 4; nt++) {
        f32x4 acc[4];
        #pragma unroll
        for (int mt = 0; mt < 4; mt++) acc[mt] = (f32x4){0.f,0.f,0.f,0.f};
        #pragma unroll
        for (int kc = 0; kc < 2; kc++) {
            bfrag bb = *(const bfrag*)(WkB + 4096 + (nt*16 + m16)*64 + kc*32 + q*8);
            #pragma unroll
            for (int mt = 0; mt < 4; mt++)
                acc[mt] = __builtin_amdgcn_mfma_f32_16x16x32_bf16(a3[mt][kc], bb, acc[mt], 0, 0, 0);
        }
        #pragma unroll
        for (int mt = 0; mt < 4; mt++)
            #pragma unroll
            for (int r = 0; r < 4; r++) {
                int R = blockRow + (w*4 + mt)*16 + q*4 + r;
                store_bf16_packed(akb1, R, nt*16, m16, acc[mt][r]);
            }
    }
}

// ---------------------------------------------------------------------------
// K4a: layer-0 CSR gather: x1[v,o,c] = sum_seg akb0[j,o,c] * xe[srcOf[j],c]
// ---------------------------------------------------------------------------
__global__ __launch_bounds__(256) void gather0(
    const __hip_bfloat16* __restrict__ akb, const int* __restrict__ srcOf,
    const int* __restrict__ rp, const float* __restrict__ xe,
    float* __restrict__ x1)
{
    int w = threadIdx.x >> 6, lane = threadIdx.x & 63;
    int g = blockIdx.x*4 + w;
    int v = g / 12, o = g - v*12;
    int jb = rp[v], je = rp[v+1];
    float acc = 0.f;
    for (int j = jb; j < je; j++) {
        float a  = __bfloat162float(akb[(size_t)j*768 + o*64 + lane]);
        float xs = xe[(size_t)srcOf[j]*64 + lane];
        acc += a * xs;
    }
    x1[(size_t)v*768 + o*64 + lane] = acc;
}

// ---------------------------------------------------------------------------
// K4b: layer-1 CSR gather (unchanged)
// ---------------------------------------------------------------------------
__global__ __launch_bounds__(256) void gather1(
    const __hip_bfloat16* __restrict__ akb, const int* __restrict__ srcOf,
    const int* __restrict__ rp, const float* __restrict__ x_in,
    float* __restrict__ x1)
{
    int w = threadIdx.x >> 6, lane = threadIdx.x & 63;
    int g = blockIdx.x*4 + w;
    int v = g / 12, o = g - v*12;
    int jb = rp[v], je = rp[v+1];
    float acc = 0.f;
    for (int j = jb; j < je; j++) {
        float a  = __bfloat162float(akb[(size_t)j*768 + o*64 + lane]);
        float xs = x_in[(size_t)srcOf[j]*768 + o*64 + lane];
        acc += a * xs;
    }
    x1[(size_t)v*768 + o*64 + lane] = acc;
}

// ---------------------------------------------------------------------------
// K5: MFMA node kernel (unchanged — known good)
// ---------------------------------------------------------------------------
__global__ __launch_bounds__(256, 2) void node_mfma(
    const float* __restrict__ x1, const float* __restrict__ fk,
    const float* __restrict__ conv_b, const float* __restrict__ ln_g,
    const float* __restrict__ ln_b,
    const short* __restrict__ W1B, const float* __restrict__ b1,
    const short* __restrict__ W2B, const float* __restrict__ pb2,
    const float* __restrict__ Wr, const float* __restrict__ br,
    const float* __restrict__ x_old, float* __restrict__ x_new,
    float* __restrict__ racc, int has_res, int write_x)
{
    __shared__ short sA1[128*72];
    __shared__ short sA2[128*136];

    int tid = threadIdx.x;
    int blockRow = blockIdx.x * 128;

    {
        int rl = tid >> 1, hf = tid & 1;
        int row = blockRow + rl;
        int rc = row < N_ROWS ? row : N_ROWS - 1;
        int v = rc / 12, pp = rc % 12;
        float h[32];
        #pragma unroll
        for (int k = 0; k < 32; k++) h[k] = 0.f;
        const float* xv = x1 + (size_t)v*768 + hf*32;
        const float* fp = fk + (size_t)pp*768 + hf*32;
        for (int o = 0; o < 12; o++) {
            const float4* xa = (const float4*)(xv + o*64);
            const float4* fa = (const float4*)(fp + o*64);
            #pragma unroll
            for (int k4 = 0; k4 < 8; k4++) {
                float4 xd = xa[k4]; float4 fd = fa[k4];
                h[4*k4+0] += xd.x*fd.x; h[4*k4+1] += xd.y*fd.y;
                h[4*k4+2] += xd.z*fd.z; h[4*k4+3] += xd.w*fd.w;
            }
        }
        const float inv12 = 1.0f/12.0f;
        float sum = 0.f;
        #pragma unroll
        for (int k = 0; k < 32; k++) { h[k] = h[k]*inv12 + conv_b[hf*32 + k]; sum += h[k]; }
        sum += __shfl_xor(sum, 1);
        float mu = sum * (1.0f/64.0f);
        float var = 0.f;
        #pragma unroll
        for (int k = 0; k < 32; k++) { float xc = h[k] - mu; var += xc*xc; }
        var += __shfl_xor(var, 1);
        float rstd = rsqrtf(var*(1.0f/64.0f) + 1e-5f);
        short* dst = sA1 + rl*72 + hf*32;
        #pragma unroll
        for (int blk = 0; blk < 4; blk++) {
            union { short s[8]; int4 v4; } u;
            #pragma unroll
            for (int jj = 0; jj < 8; jj++) {
                int k = blk*8 + jj, c = hf*32 + k;
                u.s[jj] = f2bf((h[k] - mu)*rstd*ln_g[c] + ln_b[c]);
            }
            *(int4*)(dst + blk*8) = u.v4;
        }
    }
    __syncthreads();

    int w   = tid >> 6;
    int l   = tid & 63;
    int m16 = l & 15, q = l >> 4;

    bfrag a1[2][2];
    #pragma unroll
    for (int i = 0; i < 2; i++) {
        int mt = 2*w + i;
        #pragma unroll
        for (int kc = 0; kc < 2; kc++)
            a1[i][kc] = *(const bfrag*)(sA1 + (mt*16 + m16)*72 + kc*32 + q*8);
    }

    f32x4 acc2[4][2];
    #pragma unroll
    for (int n = 0; n < 4; n++)
        #pragma unroll
        for (int i = 0; i < 2; i++)
            acc2[n][i] = (f32x4){0.f, 0.f, 0.f, 0.f};

    for (int ph = 0; ph < 2; ph++) {
        for (int ntl = 0; ntl < 8; ntl++) {
            int nt = ph*8 + ntl;
            f32x4 c0 = (f32x4){0.f,0.f,0.f,0.f};
            f32x4 c1 = (f32x4){0.f,0.f,0.f,0.f};
            #pragma unroll
            for (int kc = 0; kc < 2; kc++) {
                bfrag bb = *(const bfrag*)(W1B + (nt*16 + m16)*64 + kc*32 + q*8);
                c0 = __builtin_amdgcn_mfma_f32_16x16x32_bf16(a1[0][kc], bb, c0, 0, 0, 0);
                c1 = __builtin_amdgcn_mfma_f32_16x16x32_bf16(a1[1][kc], bb, c1, 0, 0, 0);
            }
            float bias = b1[nt*16 + m16];
            #pragma unroll
            for (int r = 0; r < 4; r++) {
                int r0 = (2*w)*16 + q*4 + r;
                int r1 = (2*w+1)*16 + q*4 + r;
                sA2[r0*136 + ntl*16 + m16] = f2bf(gelu_f(c0[r] + bias));
                sA2[r1*136 + ntl*16 + m16] = f2bf(gelu_f(c1[r] + bias));
            }
        }
        __syncthreads();
        for (int kc2 = 0; kc2 < 4; kc2++) {
            bfrag a2[2];
            #pragma unroll
            for (int i = 0; i < 2; i++)
                a2[i] = *(const bfrag*)(sA2 + ((2*w+i)*16 + m16)*136 + kc2*32 + q*8);
            #pragma unroll
            for (int nc = 0; nc < 4; nc++) {
                bfrag bb = *(const bfrag*)(W2B + (nc*16 + m16)*256 + ph*128 + kc2*32 + q*8);
                acc2[nc][0] = __builtin_amdgcn_mfma_f32_16x16x32_bf16(a2[0], bb, acc2[nc][0], 0, 0, 0);
                acc2[nc][1] = __builtin_amdgcn_mfma_f32_16x16x32_bf16(a2[1], bb, acc2[nc][1], 0, 0, 0);
            }
        }
        __syncthreads();
    }

    float p0[2][4], p1[2][4];
    #pragma unroll
    for (int i = 0; i < 2; i++) {
        #pragma unroll
        for (int r = 0; r < 4; r++) {
            int rowl = (2*w+i)*16 + q*4 + r;
            int row  = blockRow + rowl;
            bool ok  = row < N_ROWS;
            float vals[4];
            #pragma unroll
            for (int nc = 0; nc < 4; nc++) vals[nc] = acc2[nc][i][r] + pb2[nc*16 + m16];
            if (has_res && ok) {
                #pragma unroll
                for (int nc = 0; nc < 4; nc++) vals[nc] += x_old[(size_t)row*64 + nc*16 + m16];
            }
            if (write_x && ok) {
                #pragma unroll
                for (int nc = 0; nc < 4; nc++) x_new[(size_t)row*64 + nc*16 + m16] = vals[nc];
            }
            float q0 = 0.f, q1 = 0.f;
            #pragma unroll
            for (int nc = 0; nc < 4; nc++) {
                int c = nc*16 + m16;
                q0 += vals[nc]*Wr[2*c];
                q1 += vals[nc]*Wr[2*c + 1];
            }
            p0[i][r] = q0; p1[i][r] = q1;
        }
    }
    #pragma unroll
    for (int s = 1; s < 16; s <<= 1) {
        #pragma unroll
        for (int i = 0; i < 2; i++)
            #pragma unroll
            for (int r = 0; r < 4; r++) {
                p0[i][r] += __shfl_xor(p0[i][r], s);
                p1[i][r] += __shfl_xor(p1[i][r], s);
            }
    }
    if (m16 == 0) {
        #pragma unroll
        for (int i = 0; i < 2; i++)
            #pragma unroll
            for (int r = 0; r < 4; r++) {
                int row = blockRow + (2*w+i)*16 + q*4 + r;
                if (row < N_ROWS) {
                    atomicAdd(&racc[row*2 + 0], p0[i][r] + br[0]);
                    atomicAdd(&racc[row*2 + 1], p1[i][r] + br[1]);
                }
            }
    }
}

// ---------------------------------------------------------------------------
// K6: readout
// ---------------------------------------------------------------------------
__global__ __launch_bounds__(256) void final_kernel(
    const float* __restrict__ racc, const float* __restrict__ ori,
    const int* __restrict__ batch, float* __restrict__ out)
{
    int v = blockIdx.x*256 + threadIdx.x;
    if (v >= N_NODES) return;
    float srs = 0.f, vx = 0.f, vy = 0.f, vz = 0.f;
    #pragma unroll
    for (int p = 0; p < 12; p++) {
        float r0 = racc[v*24 + 2*p], r1 = racc[v*24 + 2*p + 1];
        srs += r0;
        vx += r1*ori[3*p]; vy += r1*ori[3*p+1]; vz += r1*ori[3*p+2];
    }
    const float sc = 1.0f/24.0f;
    int g = batch[v];
    atomicAdd(&out[g], srs*sc);
    atomicAdd(&out[16 + g*3 + 0], vx*sc);
    atomicAdd(&out[16 + g*3 + 1], vy*sc);
    atomicAdd(&out[16 + g*3 + 2], vz*sc);
}

extern "C" void kernel_launch(void* const* d_in, const int* in_sizes, int n_in,
                              void* d_out, int out_size, void* d_ws, size_t ws_size,
                              hipStream_t stream) {
    const float* pos    = (const float*)d_in[0];
    const float* f      = (const float*)d_in[1];
    const float* ori    = (const float*)d_in[2];
    const int*   ei     = (const int*)  d_in[3];
    const int*   batch  = (const int*)  d_in[4];
    const float* Wb1    = (const float*)d_in[5];
    const float* bb1    = (const float*)d_in[6];
    const float* Wb2    = (const float*)d_in[7];
    const float* bb2    = (const float*)d_in[8];
    const float* Wo1    = (const float*)d_in[9];
    const float* bo1    = (const float*)d_in[10];
    const float* Wo2    = (const float*)d_in[11];
    const float* bo2    = (const float*)d_in[12];
    const float* We     = (const float*)d_in[13];
    const float* Wk     = (const float*)d_in[14];
    const float* Wf     = (const float*)d_in[15];
    const float* conv_b = (const float*)d_in[16];
    const float* ln_g   = (const float*)d_in[17];
    const float* ln_b   = (const float*)d_in[18];
    const float* W1     = (const float*)d_in[19];
    const float* b1     = (const float*)d_in[20];
    const float* W2     = (const float*)d_in[21];
    const float* b2     = (const float*)d_in[22];
    const float* Wr     = (const float*)d_in[23];
    const float* br     = (const float*)d_in[24];
    float* out = (float*)d_out;

    float* ws   = (float*)d_ws;
    float* xe   = ws;                       //   640,000 f32
    float* xs1  = xe   + 640000;            // 7,680,000
    float* x1a  = xs1  + 7680000;           // 7,680,000
    float* racc = x1a  + 7680000;           //   240,000
    float* fkb  = racc + 240000;            //    18,432
    short* w1b  = (short*)(fkb + 18432);    //    32,768 shorts (2 layers)
    short* w2b  = w1b + 32768;
    short* w1k  = w2b + 32768;
    short* w2k  = w1k + 2048;
    short* wkb  = w2k + 4096;
    int*   deg  = (int*)(wkb + 8192);       //    10,000 ints
    int*   rp   = deg + 10000;              //    10,001 ints
    int*   wp   = rp  + 10001;              //    10,000 ints
    int*   perm = wp  + 10000;              //    80,000 ints
    int*   srcOf= perm+ 80000;              //    80,000 ints
    int*   pad_ = srcOf + 80000;
    __hip_bfloat16* akb1 = (__hip_bfloat16*)(pad_ + 3);     // 61,440,000 bf16
    __hip_bfloat16* akb0 = akb1 + 61440000;                 // 61,440,000 bf16 (full mode)

    size_t need_full = ((char*)(akb0 + 61440000)) - ((char*)d_ws);
    int full = (ws_size >= need_full) ? 1 : 0;

    hipMemsetAsync(out,  0, 64*sizeof(float), stream);
    hipMemsetAsync(racc, 0, 240000*sizeof(float), stream);
    hipMemsetAsync(deg,  0, 10000*sizeof(int), stream);
    if (!full) hipMemsetAsync(x1a, 0, 7680000*sizeof(float), stream);

    // CSR by dst
    csr_count<<<313, 256, 0, stream>>>(ei, deg);
    csr_scan <<<1,   256, 0, stream>>>(deg, rp, wp);
    csr_fill <<<313, 256, 0, stream>>>(ei, wp, perm, srcOf);

    prep_weights<<<4,    256, 0, stream>>>(W1, W2, Wb1, Wb2, Wk,
                                           w1b, w2b, w1k, w2k, wkb);
    ori_kernel  <<<144,  64, 0, stream>>>(ori, Wo1, bo1, Wo2, bo2, Wf, fkb);
    embed_kernel<<<2500, 256, 0, stream>>>(f, We, xe);

    // kb MLP + akb GEMMs (full: store akb0+akb1; fallback: atomic scatter + akb1)
    kb_mfma     <<<3750, 256, 0, stream>>>(pos, ori, w1k, bb1, w2k, bb2,
                                           wkb, ei, perm, xe, x1a, akb0, akb1, full);

    // layer 0 aggregation
    if (full)
        gather0 <<<30000,256, 0, stream>>>(akb0, srcOf, rp, xe, x1a);

    node_mfma   <<<938,  256, 0, stream>>>(x1a, fkb, conv_b, ln_g, ln_b,
                                           w1b, b1, w2b, b2, Wr, br,
                                           xs1, xs1, racc, /*res=*/0, /*write=*/1);
    // layer 1
    gather1     <<<30000,256, 0, stream>>>(akb1, srcOf, rp, xs1, x1a);
    node_mfma   <<<938,  256, 0, stream>>>(x1a, fkb + 9216, conv_b + 64, ln_g + 64, ln_b + 64,
                                           w1b + 16384, b1 + 256, w2b + 16384, b2 + 64,
                                           Wr + 128, br + 2,
                                           xs1, xs1, racc, /*res=*/1, /*write=*/0);

    final_kernel<<<40,   256, 0, stream>>>(racc, ori, batch, out);
}

// Round 9
// 1148.533 us; speedup vs baseline: 1.1050x; 1.1050x over previous
//
#include <hip/hip_runtime.h>
#include <hip/hip_bf16.h>
#include <math.h>

#define N_NODES 10000
#define N_EDGES 80000
#define N_ORI   12
#define N_ROWS  (N_NODES * N_ORI)

typedef __attribute__((ext_vector_type(8))) short bfrag;   // 8 bf16 = 4 VGPRs
typedef __attribute__((ext_vector_type(4))) float f32x4;

__device__ __forceinline__ float gelu_f(float x) {
    return 0.5f * x * (1.0f + erff(x * 0.70710678118654752440f));
}
__device__ __forceinline__ short f2bf(float x) {
    __hip_bfloat16 h = __float2bfloat16(x);
    return *reinterpret_cast<short*>(&h);
}

// ---------------------------------------------------------------------------
// CSR build (dst-sorted edge list for gather1)
// ---------------------------------------------------------------------------
__global__ __launch_bounds__(256) void csr_count(
    const int* __restrict__ ei, int* __restrict__ deg)
{
    int e = blockIdx.x*256 + threadIdx.x;
    if (e < N_EDGES) atomicAdd(&deg[ei[N_EDGES + e]], 1);
}

__global__ __launch_bounds__(256) void csr_scan(
    const int* __restrict__ deg, int* __restrict__ rp, int* __restrict__ wp)
{
    __shared__ int part[256];
    __shared__ int sbase[257];
    int t = threadIdx.x;
    int cs = t*40;
    int sum = 0;
    for (int i = 0; i < 40; i++) { int idx = cs+i; if (idx < N_NODES) sum += deg[idx]; }
    part[t] = sum;
    __syncthreads();
    if (t == 0) {
        int run = 0;
        for (int i = 0; i < 256; i++) { sbase[i] = run; run += part[i]; }
        sbase[256] = run;
    }
    __syncthreads();
    int run = sbase[t];
    for (int i = 0; i < 40; i++) {
        int idx = cs+i;
        if (idx < N_NODES) { rp[idx] = run; wp[idx] = run; run += deg[idx]; }
    }
    if (t == 0) rp[N_NODES] = sbase[256];
}

__global__ __launch_bounds__(256) void csr_fill(
    const int* __restrict__ ei, int* __restrict__ wp,
    int* __restrict__ perm, int* __restrict__ srcOf)
{
    int e = blockIdx.x*256 + threadIdx.x;
    if (e >= N_EDGES) return;
    int dn = ei[N_EDGES + e];
    int j = atomicAdd(&wp[dn], 1);
    perm[j] = e;
    srcOf[j] = ei[e];
}

// ---------------------------------------------------------------------------
// K0: weight prep (unchanged)
// ---------------------------------------------------------------------------
__global__ __launch_bounds__(256) void prep_weights(
    const float* __restrict__ W1, const float* __restrict__ W2,
    const float* __restrict__ Wb1, const float* __restrict__ Wb2,
    const float* __restrict__ Wk,
    short* __restrict__ W1B, short* __restrict__ W2B,
    short* __restrict__ W1K, short* __restrict__ W2K,
    short* __restrict__ WkB)
{
    if (blockIdx.x < 2) {
        int l = blockIdx.x;
        const float* w1 = W1 + l*16384; short* w1b = W1B + l*16384;
        const float* w2 = W2 + l*16384; short* w2b = W2B + l*16384;
        for (int i = threadIdx.x; i < 16384; i += 256) {
            int k = i >> 8, t = i & 255;
            w1b[t*64 + k] = f2bf(w1[i]);
            int t2 = i >> 6, c = i & 63;
            w2b[c*256 + t2] = f2bf(w2[i]);
        }
    } else if (blockIdx.x == 2) {
        for (int i = threadIdx.x; i < 2048; i += 256) {
            int t = i >> 5, k = i & 31;
            W1K[i] = (k < 30) ? f2bf(Wb1[k*64 + t]) : (short)0;
        }
        for (int i = threadIdx.x; i < 4096; i += 256) {
            int c = i >> 6, t = i & 63;
            W2K[i] = f2bf(Wb2[t*64 + c]);
        }
    } else {
        for (int i = threadIdx.x; i < 8192; i += 256) {
            int l = i >> 12, rem = i & 4095, k = rem >> 6, c = rem & 63;
            WkB[l*4096 + c*64 + k] = f2bf(Wk[l*4096 + k*64 + c]);
        }
    }
}

// ---------------------------------------------------------------------------
// K1: kb_ori MLP + fk (unchanged)
// ---------------------------------------------------------------------------
__global__ __launch_bounds__(64) void ori_kernel(
    const float* __restrict__ ori, const float* __restrict__ Wo1,
    const float* __restrict__ bo1, const float* __restrict__ Wo2,
    const float* __restrict__ bo2, const float* __restrict__ Wf,
    float* __restrict__ fkb)
{
    __shared__ float sh[64];
    __shared__ float skb[64];
    int i = blockIdx.x / 12, j = blockIdx.x % 12;
    int lane = threadIdx.x;
    float s = ori[3*i]*ori[3*j] + ori[3*i+1]*ori[3*j+1] + ori[3*i+2]*ori[3*j+2];
    float p1 = s, p2 = s*s, p3 = p2*s, p4 = p3*s;
    float acc = bo1[lane] + p1*Wo1[lane] + p2*Wo1[64+lane] + p3*Wo1[128+lane] + p4*Wo1[192+lane];
    sh[lane] = gelu_f(acc);
    __syncthreads();
    float acc2 = bo2[lane];
    #pragma unroll
    for (int k = 0; k < 64; k++) acc2 += sh[k] * Wo2[k*64 + lane];
    skb[lane] = gelu_f(acc2);
    __syncthreads();
    for (int l = 0; l < 2; l++) {
        float a = 0.f;
        #pragma unroll
        for (int k = 0; k < 64; k++) a += skb[k] * Wf[l*4096 + k*64 + lane];
        fkb[l*9216 + i*768 + j*64 + lane] = a;
    }
}

// ---------------------------------------------------------------------------
// K2: x = f @ We (unchanged)
// ---------------------------------------------------------------------------
__global__ __launch_bounds__(256) void embed_kernel(
    const float* __restrict__ f, const float* __restrict__ We, float* __restrict__ xe)
{
    int v = blockIdx.x*4 + (threadIdx.x >> 6);
    int lane = threadIdx.x & 63;
    if (v >= N_NODES) return;
    float acc = 0.f;
    #pragma unroll
    for (int k = 0; k < 16; k++) acc += f[v*16 + k] * We[k*64 + lane];
    xe[v*64 + lane] = acc;
}

// ---------------------------------------------------------------------------
// K3 (v5): kb MLP via MFMA, UNSORTED rows (r6-proven atomic path), wave-local
// LDS union (sF stride-40 / sH stride-72 aliased per-wave, +sEnv) = 37,888 B
// -> 4 blocks/CU, ZERO __syncthreads (fully wave-synchronous).
// Layer 0: fused atomic scatter. Layer 1: coalesced akb1 bf16 store.
// ---------------------------------------------------------------------------
#define KB_WREG 4736   // shorts per wave region: 64*72 (sH) + 128 (sEnv f32[64])
__global__ __launch_bounds__(256, 4) void kb_mfma(
    const float* __restrict__ pos, const float* __restrict__ ori,
    const short* __restrict__ W1K, const float* __restrict__ bb1,
    const short* __restrict__ W2K, const float* __restrict__ bb2,
    const short* __restrict__ WkB, const int* __restrict__ ei,
    const float* __restrict__ xe, float* __restrict__ x1a,
    __hip_bfloat16* __restrict__ akb1)
{
    __shared__ short sU[4*KB_WREG];

    int tid = threadIdx.x;
    int w = tid >> 6, l = tid & 63;
    short* reg  = sU + w*KB_WREG;            // this wave's region
    float* envp = (float*)(reg + 64*72);     // 64 floats
    int blockRow = blockIdx.x * 256;

    // ---- Phase A: features (wave-local rows 64w..64w+63; local row = l) ----
    {
        int row = blockRow + tid;
        int e = row / 12, o = row - e*12;
        int sn = ei[e], dn = ei[N_EDGES + e];
        float rx = pos[sn*3+0] - pos[dn*3+0];
        float ry = pos[sn*3+1] - pos[dn*3+1];
        float rz = pos[sn*3+2] - pos[dn*3+2];
        float d  = sqrtf(rx*rx + ry*ry + rz*rz);
        float u2 = d*d, u4 = u2*u2, u6 = u4*u2;
        float env = (d < 1.0f) ? (1.0f - 28.0f*u6 + 48.0f*u6*d - 21.0f*u6*u2) : 0.0f;
        envp[l] = env;

        float ox = ori[3*o], oy = ori[3*o+1], oz = ori[3*o+2];
        float a  = rx*ox + ry*oy + rz*oz;
        float qx = rx - a*ox, qy = ry - a*oy, qz = rz - a*oz;
        float b  = sqrtf(qx*qx + qy*qy + qz*qz);

        float fv[32];
        fv[0] = a; fv[1] = b;
        fv[2] = a*a; fv[3] = a*b; fv[4] = b*a; fv[5] = b*b;
        #pragma unroll
        for (int i = 0; i < 4; i++) { fv[6+2*i] = fv[2+i]*a; fv[7+2*i] = fv[2+i]*b; }
        #pragma unroll
        for (int i = 0; i < 8; i++) { fv[14+2*i] = fv[6+i]*a; fv[15+2*i] = fv[6+i]*b; }
        fv[30] = 0.f; fv[31] = 0.f;

        short* dst = reg + l*40;             // sF view: stride 40
        #pragma unroll
        for (int blk = 0; blk < 4; blk++) {
            union { short s[8]; int4 v4; } u;
            #pragma unroll
            for (int jj = 0; jj < 8; jj++) u.s[jj] = f2bf(fv[blk*8 + jj]);
            *(int4*)(dst + blk*8) = u.v4;
        }
    }
    __builtin_amdgcn_wave_barrier();

    int m16 = l & 15, q = l >> 4;

    // ---- hoist A1 frags (consume sF fully before sH writes alias it) ----
    bfrag a1[4];
    #pragma unroll
    for (int mt = 0; mt < 4; mt++)
        a1[mt] = *(const bfrag*)(reg + (mt*16 + m16)*40 + q*8);
    __builtin_amdgcn_wave_barrier();

    // ---- FFN1: K=32 -> gelu -> sH (stride 72, wave-local) ----
    #pragma unroll
    for (int nt = 0; nt < 4; nt++) {
        bfrag bb = *(const bfrag*)(W1K + (nt*16 + m16)*32 + q*8);
        float bias = bb1[nt*16 + m16];
        #pragma unroll
        for (int mt = 0; mt < 4; mt++) {
            f32x4 acc = (f32x4){0.f,0.f,0.f,0.f};
            acc = __builtin_amdgcn_mfma_f32_16x16x32_bf16(a1[mt], bb, acc, 0, 0, 0);
            #pragma unroll
            for (int r = 0; r < 4; r++) {
                int rl = mt*16 + q*4 + r;            // local row
                reg[rl*72 + nt*16 + m16] = f2bf(gelu_f(acc[r] + bias));
            }
        }
    }
    __builtin_amdgcn_wave_barrier();

    // ---- FFN2: K=64 -> kb = gelu(.)*env back into sH ----
    bfrag a2[4][2];
    #pragma unroll
    for (int mt = 0; mt < 4; mt++)
        #pragma unroll
        for (int kc = 0; kc < 2; kc++)
            a2[mt][kc] = *(const bfrag*)(reg + (mt*16 + m16)*72 + kc*32 + q*8);
    __builtin_amdgcn_wave_barrier();

    #pragma unroll
    for (int nt = 0; nt < 4; nt++) {
        f32x4 acc[4];
        #pragma unroll
        for (int mt = 0; mt < 4; mt++) acc[mt] = (f32x4){0.f,0.f,0.f,0.f};
        #pragma unroll
        for (int kc = 0; kc < 2; kc++) {
            bfrag bb = *(const bfrag*)(W2K + (nt*16 + m16)*64 + kc*32 + q*8);
            #pragma unroll
            for (int mt = 0; mt < 4; mt++)
                acc[mt] = __builtin_amdgcn_mfma_f32_16x16x32_bf16(a2[mt][kc], bb, acc[mt], 0, 0, 0);
        }
        float bias = bb2[nt*16 + m16];
        #pragma unroll
        for (int mt = 0; mt < 4; mt++) {
            #pragma unroll
            for (int r = 0; r < 4; r++) {
                int rl = mt*16 + q*4 + r;
                reg[rl*72 + nt*16 + m16] = f2bf(gelu_f(acc[mt][r] + bias) * envp[rl]);
            }
        }
    }
    __builtin_amdgcn_wave_barrier();

    // ---- akb GEMMs: kb @ Wk[l] ----
    bfrag a3[4][2];
    #pragma unroll
    for (int mt = 0; mt < 4; mt++)
        #pragma unroll
        for (int kc = 0; kc < 2; kc++)
            a3[mt][kc] = *(const bfrag*)(reg + (mt*16 + m16)*72 + kc*32 + q*8);

    int oArr[4][4], snArr[4][4], dnArr[4][4];
    #pragma unroll
    for (int mt = 0; mt < 4; mt++)
        #pragma unroll
        for (int r = 0; r < 4; r++) {
            int R = blockRow + w*64 + mt*16 + q*4 + r;
            int e = R / 12;
            oArr[mt][r] = R - e*12;
            snArr[mt][r] = ei[e]; dnArr[mt][r] = ei[N_EDGES + e];
        }

    // layer 0: akb0 in regs -> fused atomic scatter (unsorted = low contention)
    #pragma unroll
    for (int nt = 0; nt < 4; nt++) {
        f32x4 acc[4];
        #pragma unroll
        for (int mt = 0; mt < 4; mt++) acc[mt] = (f32x4){0.f,0.f,0.f,0.f};
        #pragma unroll
        for (int kc = 0; kc < 2; kc++) {
            bfrag bb = *(const bfrag*)(WkB + (nt*16 + m16)*64 + kc*32 + q*8);
            #pragma unroll
            for (int mt = 0; mt < 4; mt++)
                acc[mt] = __builtin_amdgcn_mfma_f32_16x16x32_bf16(a3[mt][kc], bb, acc[mt], 0, 0, 0);
        }
        int col = nt*16 + m16;
        #pragma unroll
        for (int mt = 0; mt < 4; mt++)
            #pragma unroll
            for (int r = 0; r < 4; r++) {
                float val = acc[mt][r] * xe[snArr[mt][r]*64 + col];
                atomicAdd(&x1a[(size_t)dnArr[mt][r]*768 + oArr[mt][r]*64 + col], val);
            }
    }
    // layer 1: akb1 coalesced bf16 store at unsorted row index
    #pragma unroll
    for (int nt = 0; nt < 4; nt++) {
        f32x4 acc[4];
        #pragma unroll
        for (int mt = 0; mt < 4; mt++) acc[mt] = (f32x4){0.f,0.f,0.f,0.f};
        #pragma unroll
        for (int kc = 0; kc < 2; kc++) {
            bfrag bb = *(const bfrag*)(WkB + 4096 + (nt*16 + m16)*64 + kc*32 + q*8);
            #pragma unroll
            for (int mt = 0; mt < 4; mt++)
                acc[mt] = __builtin_amdgcn_mfma_f32_16x16x32_bf16(a3[mt][kc], bb, acc[mt], 0, 0, 0);
        }
        int col = nt*16 + m16;
        #pragma unroll
        for (int mt = 0; mt < 4; mt++)
            #pragma unroll
            for (int r = 0; r < 4; r++) {
                int R = blockRow + w*64 + mt*16 + q*4 + r;
                akb1[(size_t)R*64 + col] = __float2bfloat16(acc[mt][r]);
            }
    }
}

// ---------------------------------------------------------------------------
// K4: layer-1 CSR gather, perm-indirect akb1 reads (akb1 in edge order).
// ---------------------------------------------------------------------------
__global__ __launch_bounds__(256) void gather1(
    const __hip_bfloat16* __restrict__ akb, const int* __restrict__ perm,
    const int* __restrict__ srcOf, const int* __restrict__ rp,
    const float* __restrict__ x_in, float* __restrict__ x1)
{
    int w = threadIdx.x >> 6, lane = threadIdx.x & 63;
    int g = blockIdx.x*4 + w;
    int v = g / 12, o = g - v*12;
    int jb = rp[v], je = rp[v+1];
    float acc = 0.f;
    for (int j = jb; j < je; j++) {
        int e = perm[j];                        // wave-uniform -> s_load
        float a  = __bfloat162float(akb[(size_t)e*12*64 + o*64 + lane]);
        float xs = x_in[(size_t)srcOf[j]*768 + o*64 + lane];
        acc += a * xs;
    }
    x1[(size_t)v*768 + o*64 + lane] = acc;
}

// ---------------------------------------------------------------------------
// K5 (v2): node kernel, wave-blocked union LDS (sA1 stride-72 / sA2 stride-136
// aliased; 8704 B/wave, 34,816 B total) -> 4 blocks/CU, ZERO __syncthreads.
// Wave w owns rows 32w..32w+31 in every phase.
// ---------------------------------------------------------------------------
#define ND_WREG 4352   // shorts per wave region: 32*136 (sA2 view)
__global__ __launch_bounds__(256, 4) void node_mfma(
    const float* __restrict__ x1, const float* __restrict__ fk,
    const float* __restrict__ conv_b, const float* __restrict__ ln_g,
    const float* __restrict__ ln_b,
    const short* __restrict__ W1B, const float* __restrict__ b1,
    const short* __restrict__ W2B, const float* __restrict__ pb2,
    const float* __restrict__ Wr, const float* __restrict__ br,
    const float* __restrict__ x_old, float* __restrict__ x_new,
    float* __restrict__ racc, int has_res, int write_x)
{
    __shared__ short sU[4*ND_WREG];

    int tid = threadIdx.x;
    int w   = tid >> 6;
    int blockRow = blockIdx.x * 128;
    short* reg = sU + w*ND_WREG;

    // ---- Phase A: conv + LN -> sA1 view (stride 72, local rows 0..31) ----
    {
        int rl = tid >> 1, hf = tid & 1;       // rl in [32w, 32w+32)
        int lr = rl - 32*w;                    // local row
        int row = blockRow + rl;
        int rc = row < N_ROWS ? row : N_ROWS - 1;
        int v = rc / 12, pp = rc % 12;
        float h[32];
        #pragma unroll
        for (int k = 0; k < 32; k++) h[k] = 0.f;
        const float* xv = x1 + (size_t)v*768 + hf*32;
        const float* fp = fk + (size_t)pp*768 + hf*32;
        for (int o = 0; o < 12; o++) {
            const float4* xa = (const float4*)(xv + o*64);
            const float4* fa = (const float4*)(fp + o*64);
            #pragma unroll
            for (int k4 = 0; k4 < 8; k4++) {
                float4 xd = xa[k4]; float4 fd = fa[k4];
                h[4*k4+0] += xd.x*fd.x; h[4*k4+1] += xd.y*fd.y;
                h[4*k4+2] += xd.z*fd.z; h[4*k4+3] += xd.w*fd.w;
            }
        }
        const float inv12 = 1.0f/12.0f;
        float sum = 0.f;
        #pragma unroll
        for (int k = 0; k < 32; k++) { h[k] = h[k]*inv12 + conv_b[hf*32 + k]; sum += h[k]; }
        sum += __shfl_xor(sum, 1);
        float mu = sum * (1.0f/64.0f);
        float var = 0.f;
        #pragma unroll
        for (int k = 0; k < 32; k++) { float xc = h[k] - mu; var += xc*xc; }
        var += __shfl_xor(var, 1);
        float rstd = rsqrtf(var*(1.0f/64.0f) + 1e-5f);
        short* dst = reg + lr*72 + hf*32;
        #pragma unroll
        for (int blk = 0; blk < 4; blk++) {
            union { short s[8]; int4 v4; } u;
            #pragma unroll
            for (int jj = 0; jj < 8; jj++) {
                int k = blk*8 + jj, c = hf*32 + k;
                u.s[jj] = f2bf((h[k] - mu)*rstd*ln_g[c] + ln_b[c]);
            }
            *(int4*)(dst + blk*8) = u.v4;
        }
    }
    __builtin_amdgcn_wave_barrier();

    int l   = tid & 63;
    int m16 = l & 15, q = l >> 4;

    // hoist A1 frags (local rows i*16+m16, i=0,1) before sA2 writes alias sA1
    bfrag a1[2][2];
    #pragma unroll
    for (int i = 0; i < 2; i++)
        #pragma unroll
        for (int kc = 0; kc < 2; kc++)
            a1[i][kc] = *(const bfrag*)(reg + (i*16 + m16)*72 + kc*32 + q*8);
    __builtin_amdgcn_wave_barrier();

    f32x4 acc2[4][2];
    #pragma unroll
    for (int n = 0; n < 4; n++)
        #pragma unroll
        for (int i = 0; i < 2; i++)
            acc2[n][i] = (f32x4){0.f, 0.f, 0.f, 0.f};

    for (int ph = 0; ph < 2; ph++) {
        // FFN1 -> gelu -> sA2 view (stride 136, local rows)
        for (int ntl = 0; ntl < 8; ntl++) {
            int nt = ph*8 + ntl;
            f32x4 c0 = (f32x4){0.f,0.f,0.f,0.f};
            f32x4 c1 = (f32x4){0.f,0.f,0.f,0.f};
            #pragma unroll
            for (int kc = 0; kc < 2; kc++) {
                bfrag bb = *(const bfrag*)(W1B + (nt*16 + m16)*64 + kc*32 + q*8);
                c0 = __builtin_amdgcn_mfma_f32_16x16x32_bf16(a1[0][kc], bb, c0, 0, 0, 0);
                c1 = __builtin_amdgcn_mfma_f32_16x16x32_bf16(a1[1][kc], bb, c1, 0, 0, 0);
            }
            float bias = b1[nt*16 + m16];
            #pragma unroll
            for (int r = 0; r < 4; r++) {
                int r0 = q*4 + r;                 // local rows: mtile0 = 0..15
                int r1 = 16 + q*4 + r;            // mtile1 = 16..31
                reg[r0*136 + ntl*16 + m16] = f2bf(gelu_f(c0[r] + bias));
                reg[r1*136 + ntl*16 + m16] = f2bf(gelu_f(c1[r] + bias));
            }
        }
        __builtin_amdgcn_wave_barrier();
        // FFN2 partial over this half's K
        for (int kc2 = 0; kc2 < 4; kc2++) {
            bfrag a2[2];
            #pragma unroll
            for (int i = 0; i < 2; i++)
                a2[i] = *(const bfrag*)(reg + (i*16 + m16)*136 + kc2*32 + q*8);
            #pragma unroll
            for (int nc = 0; nc < 4; nc++) {
                bfrag bb = *(const bfrag*)(W2B + (nc*16 + m16)*256 + ph*128 + kc2*32 + q*8);
                acc2[nc][0] = __builtin_amdgcn_mfma_f32_16x16x32_bf16(a2[0], bb, acc2[nc][0], 0, 0, 0);
                acc2[nc][1] = __builtin_amdgcn_mfma_f32_16x16x32_bf16(a2[1], bb, acc2[nc][1], 0, 0, 0);
            }
        }
        __builtin_amdgcn_wave_barrier();
    }

    // ---- Epilogue (unchanged math) ----
    float p0[2][4], p1[2][4];
    #pragma unroll
    for (int i = 0; i < 2; i++) {
        #pragma unroll
        for (int r = 0; r < 4; r++) {
            int rowl = 32*w + i*16 + q*4 + r;
            int row  = blockRow + rowl;
            bool ok  = row < N_ROWS;
            float vals[4];
            #pragma unroll
            for (int nc = 0; nc < 4; nc++) vals[nc] = acc2[nc][i][r] + pb2[nc*16 + m16];
            if (has_res && ok) {
                #pragma unroll
                for (int nc = 0; nc < 4; nc++) vals[nc] += x_old[(size_t)row*64 + nc*16 + m16];
            }
            if (write_x && ok) {
                #pragma unroll
                for (int nc = 0; nc < 4; nc++) x_new[(size_t)row*64 + nc*16 + m16] = vals[nc];
            }
            float q0 = 0.f, q1 = 0.f;
            #pragma unroll
            for (int nc = 0; nc < 4; nc++) {
                int c = nc*16 + m16;
                q0 += vals[nc]*Wr[2*c];
                q1 += vals[nc]*Wr[2*c + 1];
            }
            p0[i][r] = q0; p1[i][r] = q1;
        }
    }
    #pragma unroll
    for (int s = 1; s < 16; s <<= 1) {
        #pragma unroll
        for (int i = 0; i < 2; i++)
            #pragma unroll
            for (int r = 0; r < 4; r++) {
                p0[i][r] += __shfl_xor(p0[i][r], s);
                p1[i][r] += __shfl_xor(p1[i][r], s);
            }
    }
    if (m16 == 0) {
        #pragma unroll
        for (int i = 0; i < 2; i++)
            #pragma unroll
            for (int r = 0; r < 4; r++) {
                int row = blockRow + 32*w + i*16 + q*4 + r;
                if (row < N_ROWS) {
                    atomicAdd(&racc[row*2 + 0], p0[i][r] + br[0]);
                    atomicAdd(&racc[row*2 + 1], p1[i][r] + br[1]);
                }
            }
    }
}

// ---------------------------------------------------------------------------
// K6: readout (unchanged)
// ---------------------------------------------------------------------------
__global__ __launch_bounds__(256) void final_kernel(
    const float* __restrict__ racc, const float* __restrict__ ori,
    const int* __restrict__ batch, float* __restrict__ out)
{
    int v = blockIdx.x*256 + threadIdx.x;
    if (v >= N_NODES) return;
    float srs = 0.f, vx = 0.f, vy = 0.f, vz = 0.f;
    #pragma unroll
    for (int p = 0; p < 12; p++) {
        float r0 = racc[v*24 + 2*p], r1 = racc[v*24 + 2*p + 1];
        srs += r0;
        vx += r1*ori[3*p]; vy += r1*ori[3*p+1]; vz += r1*ori[3*p+2];
    }
    const float sc = 1.0f/24.0f;
    int g = batch[v];
    atomicAdd(&out[g], srs*sc);
    atomicAdd(&out[16 + g*3 + 0], vx*sc);
    atomicAdd(&out[16 + g*3 + 1], vy*sc);
    atomicAdd(&out[16 + g*3 + 2], vz*sc);
}

extern "C" void kernel_launch(void* const* d_in, const int* in_sizes, int n_in,
                              void* d_out, int out_size, void* d_ws, size_t ws_size,
                              hipStream_t stream) {
    const float* pos    = (const float*)d_in[0];
    const float* f      = (const float*)d_in[1];
    const float* ori    = (const float*)d_in[2];
    const int*   ei     = (const int*)  d_in[3];
    const int*   batch  = (const int*)  d_in[4];
    const float* Wb1    = (const float*)d_in[5];
    const float* bb1    = (const float*)d_in[6];
    const float* Wb2    = (const float*)d_in[7];
    const float* bb2    = (const float*)d_in[8];
    const float* Wo1    = (const float*)d_in[9];
    const float* bo1    = (const float*)d_in[10];
    const float* Wo2    = (const float*)d_in[11];
    const float* bo2    = (const float*)d_in[12];
    const float* We     = (const float*)d_in[13];
    const float* Wk     = (const float*)d_in[14];
    const float* Wf     = (const float*)d_in[15];
    const float* conv_b = (const float*)d_in[16];
    const float* ln_g   = (const float*)d_in[17];
    const float* ln_b   = (const float*)d_in[18];
    const float* W1     = (const float*)d_in[19];
    const float* b1     = (const float*)d_in[20];
    const float* W2     = (const float*)d_in[21];
    const float* b2     = (const float*)d_in[22];
    const float* Wr     = (const float*)d_in[23];
    const float* br     = (const float*)d_in[24];
    float* out = (float*)d_out;

    float* ws   = (float*)d_ws;
    float* xe   = ws;                       //   640,000 f32
    float* xs1  = xe   + 640000;            // 7,680,000
    float* x1a  = xs1  + 7680000;           // 7,680,000
    float* racc = x1a  + 7680000;           //   240,000
    float* fkb  = racc + 240000;            //    18,432
    short* w1b  = (short*)(fkb + 18432);    //    32,768 shorts (2 layers)
    short* w2b  = w1b + 32768;
    short* w1k  = w2b + 32768;
    short* w2k  = w1k + 2048;
    short* wkb  = w2k + 4096;
    int*   deg  = (int*)(wkb + 8192);       //    10,000 ints
    int*   rp   = deg + 10000;              //    10,001 ints
    int*   wp   = rp  + 10001;              //    10,000 ints
    int*   perm = wp  + 10000;              //    80,000 ints
    int*   srcOf= perm+ 80000;              //    80,000 ints
    int*   pad_ = srcOf + 80000;
    __hip_bfloat16* akb1 = (__hip_bfloat16*)(pad_ + 3);     // 61,440,000 bf16 (~123 MB)

    hipMemsetAsync(out,  0, 64*sizeof(float), stream);
    hipMemsetAsync(racc, 0, 240000*sizeof(float), stream);
    hipMemsetAsync(x1a,  0, 7680000*sizeof(float), stream);
    hipMemsetAsync(deg,  0, 10000*sizeof(int), stream);

    csr_count<<<313, 256, 0, stream>>>(ei, deg);
    csr_scan <<<1,   256, 0, stream>>>(deg, rp, wp);
    csr_fill <<<313, 256, 0, stream>>>(ei, wp, perm, srcOf);

    prep_weights<<<4,    256, 0, stream>>>(W1, W2, Wb1, Wb2, Wk,
                                           w1b, w2b, w1k, w2k, wkb);
    ori_kernel  <<<144,  64, 0, stream>>>(ori, Wo1, bo1, Wo2, bo2, Wf, fkb);
    embed_kernel<<<2500, 256, 0, stream>>>(f, We, xe);

    // kb MLP + akb GEMMs + fused layer-0 atomic scatter + akb1 store
    kb_mfma     <<<3750, 256, 0, stream>>>(pos, ori, w1k, bb1, w2k, bb2,
                                           wkb, ei, xe, x1a, akb1);

    node_mfma   <<<938,  256, 0, stream>>>(x1a, fkb, conv_b, ln_g, ln_b,
                                           w1b, b1, w2b, b2, Wr, br,
                                           xs1, xs1, racc, /*res=*/0, /*write=*/1);

    gather1     <<<30000,256, 0, stream>>>(akb1, perm, srcOf, rp, xs1, x1a);

    node_mfma   <<<938,  256, 0, stream>>>(x1a, fkb + 9216, conv_b + 64, ln_g + 64, ln_b + 64,
                                           w1b + 16384, b1 + 256, w2b + 16384, b2 + 64,
                                           Wr + 128, br + 2,
                                           xs1, xs1, racc, /*res=*/1, /*write=*/0);

    final_kernel<<<40,   256, 0, stream>>>(racc, ori, batch, out);
}

// Round 10
// 1094.256 us; speedup vs baseline: 1.1599x; 1.0496x over previous
//
#include <hip/hip_runtime.h>
#include <hip/hip_bf16.h>
#include <math.h>

#define N_NODES 10000
#define N_EDGES 80000
#define N_ORI   12
#define N_ROWS  (N_NODES * N_ORI)

typedef __attribute__((ext_vector_type(8))) short bfrag;   // 8 bf16 = 4 VGPRs
typedef __attribute__((ext_vector_type(4))) float f32x4;

__device__ __forceinline__ float gelu_f(float x) {
    return 0.5f * x * (1.0f + erff(x * 0.70710678118654752440f));
}
__device__ __forceinline__ short f2bf(float x) {
    __hip_bfloat16 h = __float2bfloat16(x);
    return *reinterpret_cast<short*>(&h);
}
__device__ __forceinline__ float bflo(unsigned u) { return __uint_as_float(u << 16); }
__device__ __forceinline__ float bfhi(unsigned u) { return __uint_as_float(u & 0xffff0000u); }

// packed bf16 atomic add (2 cols / 4 B) — inline asm, header-independent
__device__ __forceinline__ void atomic_pk_add_bf16(void* p, unsigned v) {
    unsigned long long a = (unsigned long long)p;
    asm volatile("global_atomic_pk_add_bf16 %0, %1, off" :: "v"(a), "v"(v) : "memory");
}

// ---------------------------------------------------------------------------
// CSR build (dst-sorted edge list for gather1)
// ---------------------------------------------------------------------------
__global__ __launch_bounds__(256) void csr_count(
    const int* __restrict__ ei, int* __restrict__ deg)
{
    int e = blockIdx.x*256 + threadIdx.x;
    if (e < N_EDGES) atomicAdd(&deg[ei[N_EDGES + e]], 1);
}

__global__ __launch_bounds__(256) void csr_scan(
    const int* __restrict__ deg, int* __restrict__ rp, int* __restrict__ wp)
{
    __shared__ int part[256];
    __shared__ int sbase[257];
    int t = threadIdx.x;
    int cs = t*40;
    int sum = 0;
    for (int i = 0; i < 40; i++) { int idx = cs+i; if (idx < N_NODES) sum += deg[idx]; }
    part[t] = sum;
    __syncthreads();
    if (t == 0) {
        int run = 0;
        for (int i = 0; i < 256; i++) { sbase[i] = run; run += part[i]; }
        sbase[256] = run;
    }
    __syncthreads();
    int run = sbase[t];
    for (int i = 0; i < 40; i++) {
        int idx = cs+i;
        if (idx < N_NODES) { rp[idx] = run; wp[idx] = run; run += deg[idx]; }
    }
    if (t == 0) rp[N_NODES] = sbase[256];
}

__global__ __launch_bounds__(256) void csr_fill(
    const int* __restrict__ ei, int* __restrict__ wp,
    int* __restrict__ perm, int* __restrict__ srcOf)
{
    int e = blockIdx.x*256 + threadIdx.x;
    if (e >= N_EDGES) return;
    int dn = ei[N_EDGES + e];
    int j = atomicAdd(&wp[dn], 1);
    perm[j] = e;
    srcOf[j] = ei[e];
}

// ---------------------------------------------------------------------------
// K0: weight prep (unchanged)
// ---------------------------------------------------------------------------
__global__ __launch_bounds__(256) void prep_weights(
    const float* __restrict__ W1, const float* __restrict__ W2,
    const float* __restrict__ Wb1, const float* __restrict__ Wb2,
    const float* __restrict__ Wk,
    short* __restrict__ W1B, short* __restrict__ W2B,
    short* __restrict__ W1K, short* __restrict__ W2K,
    short* __restrict__ WkB)
{
    if (blockIdx.x < 2) {
        int l = blockIdx.x;
        const float* w1 = W1 + l*16384; short* w1b = W1B + l*16384;
        const float* w2 = W2 + l*16384; short* w2b = W2B + l*16384;
        for (int i = threadIdx.x; i < 16384; i += 256) {
            int k = i >> 8, t = i & 255;
            w1b[t*64 + k] = f2bf(w1[i]);
            int t2 = i >> 6, c = i & 63;
            w2b[c*256 + t2] = f2bf(w2[i]);
        }
    } else if (blockIdx.x == 2) {
        for (int i = threadIdx.x; i < 2048; i += 256) {
            int t = i >> 5, k = i & 31;
            W1K[i] = (k < 30) ? f2bf(Wb1[k*64 + t]) : (short)0;
        }
        for (int i = threadIdx.x; i < 4096; i += 256) {
            int c = i >> 6, t = i & 63;
            W2K[i] = f2bf(Wb2[t*64 + c]);
        }
    } else {
        for (int i = threadIdx.x; i < 8192; i += 256) {
            int l = i >> 12, rem = i & 4095, k = rem >> 6, c = rem & 63;
            WkB[l*4096 + c*64 + k] = f2bf(Wk[l*4096 + k*64 + c]);
        }
    }
}

// ---------------------------------------------------------------------------
// K1: kb_ori MLP + fk (unchanged)
// ---------------------------------------------------------------------------
__global__ __launch_bounds__(64) void ori_kernel(
    const float* __restrict__ ori, const float* __restrict__ Wo1,
    const float* __restrict__ bo1, const float* __restrict__ Wo2,
    const float* __restrict__ bo2, const float* __restrict__ Wf,
    float* __restrict__ fkb)
{
    __shared__ float sh[64];
    __shared__ float skb[64];
    int i = blockIdx.x / 12, j = blockIdx.x % 12;
    int lane = threadIdx.x;
    float s = ori[3*i]*ori[3*j] + ori[3*i+1]*ori[3*j+1] + ori[3*i+2]*ori[3*j+2];
    float p1 = s, p2 = s*s, p3 = p2*s, p4 = p3*s;
    float acc = bo1[lane] + p1*Wo1[lane] + p2*Wo1[64+lane] + p3*Wo1[128+lane] + p4*Wo1[192+lane];
    sh[lane] = gelu_f(acc);
    __syncthreads();
    float acc2 = bo2[lane];
    #pragma unroll
    for (int k = 0; k < 64; k++) acc2 += sh[k] * Wo2[k*64 + lane];
    skb[lane] = gelu_f(acc2);
    __syncthreads();
    for (int l = 0; l < 2; l++) {
        float a = 0.f;
        #pragma unroll
        for (int k = 0; k < 64; k++) a += skb[k] * Wf[l*4096 + k*64 + lane];
        fkb[l*9216 + i*768 + j*64 + lane] = a;
    }
}

// ---------------------------------------------------------------------------
// K2: x = f @ We (unchanged, f32 out: xe is small and L2-hot)
// ---------------------------------------------------------------------------
__global__ __launch_bounds__(256) void embed_kernel(
    const float* __restrict__ f, const float* __restrict__ We, float* __restrict__ xe)
{
    int v = blockIdx.x*4 + (threadIdx.x >> 6);
    int lane = threadIdx.x & 63;
    if (v >= N_NODES) return;
    float acc = 0.f;
    #pragma unroll
    for (int k = 0; k < 16; k++) acc += f[v*16 + k] * We[k*64 + lane];
    xe[v*64 + lane] = acc;
}

// ---------------------------------------------------------------------------
// K3 (v6): kb MLP via MFMA, unsorted rows, wave-local LDS union (r9-proven).
// Layer 0: fused scatter via PACKED-BF16 atomics into bf16 x1 (half ops, half
// bytes). Layer 1: coalesced akb1 bf16 store.
// ---------------------------------------------------------------------------
#define KB_WREG 4736
__global__ __launch_bounds__(256, 4) void kb_mfma(
    const float* __restrict__ pos, const float* __restrict__ ori,
    const short* __restrict__ W1K, const float* __restrict__ bb1,
    const short* __restrict__ W2K, const float* __restrict__ bb2,
    const short* __restrict__ WkB, const int* __restrict__ ei,
    const float* __restrict__ xe, __hip_bfloat16* __restrict__ x1b,
    __hip_bfloat16* __restrict__ akb1)
{
    __shared__ short sU[4*KB_WREG];

    int tid = threadIdx.x;
    int w = tid >> 6, l = tid & 63;
    short* reg  = sU + w*KB_WREG;
    float* envp = (float*)(reg + 64*72);
    int blockRow = blockIdx.x * 256;

    // ---- Phase A: features ----
    {
        int row = blockRow + tid;
        int e = row / 12, o = row - e*12;
        int sn = ei[e], dn = ei[N_EDGES + e];
        float rx = pos[sn*3+0] - pos[dn*3+0];
        float ry = pos[sn*3+1] - pos[dn*3+1];
        float rz = pos[sn*3+2] - pos[dn*3+2];
        float d  = sqrtf(rx*rx + ry*ry + rz*rz);
        float u2 = d*d, u4 = u2*u2, u6 = u4*u2;
        float env = (d < 1.0f) ? (1.0f - 28.0f*u6 + 48.0f*u6*d - 21.0f*u6*u2) : 0.0f;
        envp[l] = env;

        float ox = ori[3*o], oy = ori[3*o+1], oz = ori[3*o+2];
        float a  = rx*ox + ry*oy + rz*oz;
        float qx = rx - a*ox, qy = ry - a*oy, qz = rz - a*oz;
        float b  = sqrtf(qx*qx + qy*qy + qz*qz);

        float fv[32];
        fv[0] = a; fv[1] = b;
        fv[2] = a*a; fv[3] = a*b; fv[4] = b*a; fv[5] = b*b;
        #pragma unroll
        for (int i = 0; i < 4; i++) { fv[6+2*i] = fv[2+i]*a; fv[7+2*i] = fv[2+i]*b; }
        #pragma unroll
        for (int i = 0; i < 8; i++) { fv[14+2*i] = fv[6+i]*a; fv[15+2*i] = fv[6+i]*b; }
        fv[30] = 0.f; fv[31] = 0.f;

        short* dst = reg + l*40;
        #pragma unroll
        for (int blk = 0; blk < 4; blk++) {
            union { short s[8]; int4 v4; } u;
            #pragma unroll
            for (int jj = 0; jj < 8; jj++) u.s[jj] = f2bf(fv[blk*8 + jj]);
            *(int4*)(dst + blk*8) = u.v4;
        }
    }
    __builtin_amdgcn_wave_barrier();

    int m16 = l & 15, q = l >> 4;

    bfrag a1[4];
    #pragma unroll
    for (int mt = 0; mt < 4; mt++)
        a1[mt] = *(const bfrag*)(reg + (mt*16 + m16)*40 + q*8);
    __builtin_amdgcn_wave_barrier();

    // ---- FFN1: K=32 ----
    #pragma unroll
    for (int nt = 0; nt < 4; nt++) {
        bfrag bb = *(const bfrag*)(W1K + (nt*16 + m16)*32 + q*8);
        float bias = bb1[nt*16 + m16];
        #pragma unroll
        for (int mt = 0; mt < 4; mt++) {
            f32x4 acc = (f32x4){0.f,0.f,0.f,0.f};
            acc = __builtin_amdgcn_mfma_f32_16x16x32_bf16(a1[mt], bb, acc, 0, 0, 0);
            #pragma unroll
            for (int r = 0; r < 4; r++) {
                int rl = mt*16 + q*4 + r;
                reg[rl*72 + nt*16 + m16] = f2bf(gelu_f(acc[r] + bias));
            }
        }
    }
    __builtin_amdgcn_wave_barrier();

    // ---- FFN2: K=64 ----
    bfrag a2[4][2];
    #pragma unroll
    for (int mt = 0; mt < 4; mt++)
        #pragma unroll
        for (int kc = 0; kc < 2; kc++)
            a2[mt][kc] = *(const bfrag*)(reg + (mt*16 + m16)*72 + kc*32 + q*8);
    __builtin_amdgcn_wave_barrier();

    #pragma unroll
    for (int nt = 0; nt < 4; nt++) {
        f32x4 acc[4];
        #pragma unroll
        for (int mt = 0; mt < 4; mt++) acc[mt] = (f32x4){0.f,0.f,0.f,0.f};
        #pragma unroll
        for (int kc = 0; kc < 2; kc++) {
            bfrag bb = *(const bfrag*)(W2K + (nt*16 + m16)*64 + kc*32 + q*8);
            #pragma unroll
            for (int mt = 0; mt < 4; mt++)
                acc[mt] = __builtin_amdgcn_mfma_f32_16x16x32_bf16(a2[mt][kc], bb, acc[mt], 0, 0, 0);
        }
        float bias = bb2[nt*16 + m16];
        #pragma unroll
        for (int mt = 0; mt < 4; mt++) {
            #pragma unroll
            for (int r = 0; r < 4; r++) {
                int rl = mt*16 + q*4 + r;
                reg[rl*72 + nt*16 + m16] = f2bf(gelu_f(acc[mt][r] + bias) * envp[rl]);
            }
        }
    }
    __builtin_amdgcn_wave_barrier();

    // ---- akb GEMMs ----
    bfrag a3[4][2];
    #pragma unroll
    for (int mt = 0; mt < 4; mt++)
        #pragma unroll
        for (int kc = 0; kc < 2; kc++)
            a3[mt][kc] = *(const bfrag*)(reg + (mt*16 + m16)*72 + kc*32 + q*8);

    int oArr[4][4], snArr[4][4], dnArr[4][4];
    #pragma unroll
    for (int mt = 0; mt < 4; mt++)
        #pragma unroll
        for (int r = 0; r < 4; r++) {
            int R = blockRow + w*64 + mt*16 + q*4 + r;
            int e = R / 12;
            oArr[mt][r] = R - e*12;
            snArr[mt][r] = ei[e]; dnArr[mt][r] = ei[N_EDGES + e];
        }

    // layer 0: fused scatter via packed-bf16 atomics (pairs of cols)
    #pragma unroll
    for (int nt = 0; nt < 4; nt++) {
        f32x4 acc[4];
        #pragma unroll
        for (int mt = 0; mt < 4; mt++) acc[mt] = (f32x4){0.f,0.f,0.f,0.f};
        #pragma unroll
        for (int kc = 0; kc < 2; kc++) {
            bfrag bb = *(const bfrag*)(WkB + (nt*16 + m16)*64 + kc*32 + q*8);
            #pragma unroll
            for (int mt = 0; mt < 4; mt++)
                acc[mt] = __builtin_amdgcn_mfma_f32_16x16x32_bf16(a3[mt][kc], bb, acc[mt], 0, 0, 0);
        }
        int col = nt*16 + m16;
        #pragma unroll
        for (int mt = 0; mt < 4; mt++)
            #pragma unroll
            for (int r = 0; r < 4; r++) {
                float val = acc[mt][r] * xe[snArr[mt][r]*64 + col];
                unsigned my = (unsigned short)f2bf(val);
                unsigned nb = (unsigned)__shfl_xor((int)my, 1);
                unsigned packed = my | (nb << 16);
                if ((m16 & 1) == 0) {
                    size_t off = (size_t)dnArr[mt][r]*768 + oArr[mt][r]*64 + (col & ~1);
                    atomic_pk_add_bf16((char*)x1b + off*2, packed);
                }
            }
    }
    // layer 1: akb1 coalesced bf16 store
    #pragma unroll
    for (int nt = 0; nt < 4; nt++) {
        f32x4 acc[4];
        #pragma unroll
        for (int mt = 0; mt < 4; mt++) acc[mt] = (f32x4){0.f,0.f,0.f,0.f};
        #pragma unroll
        for (int kc = 0; kc < 2; kc++) {
            bfrag bb = *(const bfrag*)(WkB + 4096 + (nt*16 + m16)*64 + kc*32 + q*8);
            #pragma unroll
            for (int mt = 0; mt < 4; mt++)
                acc[mt] = __builtin_amdgcn_mfma_f32_16x16x32_bf16(a3[mt][kc], bb, acc[mt], 0, 0, 0);
        }
        int col = nt*16 + m16;
        #pragma unroll
        for (int mt = 0; mt < 4; mt++)
            #pragma unroll
            for (int r = 0; r < 4; r++) {
                int R = blockRow + w*64 + mt*16 + q*4 + r;
                akb1[(size_t)R*64 + col] = __float2bfloat16(acc[mt][r]);
            }
    }
}

// ---------------------------------------------------------------------------
// K4: layer-1 CSR gather (bf16 in, bf16 out)
// ---------------------------------------------------------------------------
__global__ __launch_bounds__(256) void gather1(
    const __hip_bfloat16* __restrict__ akb, const int* __restrict__ perm,
    const int* __restrict__ srcOf, const int* __restrict__ rp,
    const __hip_bfloat16* __restrict__ x_in, __hip_bfloat16* __restrict__ x1)
{
    int w = threadIdx.x >> 6, lane = threadIdx.x & 63;
    int g = blockIdx.x*4 + w;
    int v = g / 12, o = g - v*12;
    int jb = rp[v], je = rp[v+1];
    float acc = 0.f;
    for (int j = jb; j < je; j++) {
        int e = perm[j];
        float a  = __bfloat162float(akb[(size_t)e*768 + o*64 + lane]);
        float xs = __bfloat162float(x_in[(size_t)srcOf[j]*768 + o*64 + lane]);
        acc += a * xs;
    }
    x1[(size_t)v*768 + o*64 + lane] = __float2bfloat16(acc);
}

// ---------------------------------------------------------------------------
// packed bf16 epilogue store (quad shuffles -> 8B per 4 lanes)
// ---------------------------------------------------------------------------
__device__ __forceinline__ void store_bf16_packed(
    __hip_bfloat16* base, int row64, int colBase, int m16, float val)
{
    int my = (int)(unsigned short)f2bf(val);
    int p1 = __shfl_xor(my, 1);
    int packed01 = my | (p1 << 16);
    int p2 = __shfl_xor(packed01, 2);
    if ((m16 & 3) == 0) {
        int2 st; st.x = packed01; st.y = p2;
        *(int2*)((short*)base + (size_t)row64*64 + colBase + m16) = st;
    }
}

// ---------------------------------------------------------------------------
// K5 (v3): node kernel, wave-blocked union LDS, bf16 x1 input, bf16 x state.
// ---------------------------------------------------------------------------
#define ND_WREG 4352
__global__ __launch_bounds__(256, 4) void node_mfma(
    const short* __restrict__ x1, const float* __restrict__ fk,
    const float* __restrict__ conv_b, const float* __restrict__ ln_g,
    const float* __restrict__ ln_b,
    const short* __restrict__ W1B, const float* __restrict__ b1,
    const short* __restrict__ W2B, const float* __restrict__ pb2,
    const float* __restrict__ Wr, const float* __restrict__ br,
    const __hip_bfloat16* __restrict__ x_old, __hip_bfloat16* __restrict__ x_new,
    float* __restrict__ racc, int has_res, int write_x)
{
    __shared__ short sU[4*ND_WREG];

    int tid = threadIdx.x;
    int w   = tid >> 6;
    int blockRow = blockIdx.x * 128;
    short* reg = sU + w*ND_WREG;

    // ---- Phase A: conv + LN (x1 bf16 unpacked via shifts) ----
    {
        int rl = tid >> 1, hf = tid & 1;
        int lr = rl - 32*w;
        int row = blockRow + rl;
        int rc = row < N_ROWS ? row : N_ROWS - 1;
        int v = rc / 12, pp = rc % 12;
        float h[32];
        #pragma unroll
        for (int k = 0; k < 32; k++) h[k] = 0.f;
        const short* xv = x1 + (size_t)v*768 + hf*32;
        const float* fp = fk + (size_t)pp*768 + hf*32;
        for (int o = 0; o < 12; o++) {
            const int4*  xa = (const int4*)(xv + o*64);     // 4 int4 = 32 bf16
            const float4* fa = (const float4*)(fp + o*64);
            #pragma unroll
            for (int k4 = 0; k4 < 4; k4++) {
                int4 xi = xa[k4];
                float4 f0 = fa[2*k4], f1 = fa[2*k4+1];
                h[8*k4+0] += bflo((unsigned)xi.x)*f0.x; h[8*k4+1] += bfhi((unsigned)xi.x)*f0.y;
                h[8*k4+2] += bflo((unsigned)xi.y)*f0.z; h[8*k4+3] += bfhi((unsigned)xi.y)*f0.w;
                h[8*k4+4] += bflo((unsigned)xi.z)*f1.x; h[8*k4+5] += bfhi((unsigned)xi.z)*f1.y;
                h[8*k4+6] += bflo((unsigned)xi.w)*f1.z; h[8*k4+7] += bfhi((unsigned)xi.w)*f1.w;
            }
        }
        const float inv12 = 1.0f/12.0f;
        float sum = 0.f;
        #pragma unroll
        for (int k = 0; k < 32; k++) { h[k] = h[k]*inv12 + conv_b[hf*32 + k]; sum += h[k]; }
        sum += __shfl_xor(sum, 1);
        float mu = sum * (1.0f/64.0f);
        float var = 0.f;
        #pragma unroll
        for (int k = 0; k < 32; k++) { float xc = h[k] - mu; var += xc*xc; }
        var += __shfl_xor(var, 1);
        float rstd = rsqrtf(var*(1.0f/64.0f) + 1e-5f);
        short* dst = reg + lr*72 + hf*32;
        #pragma unroll
        for (int blk = 0; blk < 4; blk++) {
            union { short s[8]; int4 v4; } u;
            #pragma unroll
            for (int jj = 0; jj < 8; jj++) {
                int k = blk*8 + jj, c = hf*32 + k;
                u.s[jj] = f2bf((h[k] - mu)*rstd*ln_g[c] + ln_b[c]);
            }
            *(int4*)(dst + blk*8) = u.v4;
        }
    }
    __builtin_amdgcn_wave_barrier();

    int l   = tid & 63;
    int m16 = l & 15, q = l >> 4;

    bfrag a1[2][2];
    #pragma unroll
    for (int i = 0; i < 2; i++)
        #pragma unroll
        for (int kc = 0; kc < 2; kc++)
            a1[i][kc] = *(const bfrag*)(reg + (i*16 + m16)*72 + kc*32 + q*8);
    __builtin_amdgcn_wave_barrier();

    f32x4 acc2[4][2];
    #pragma unroll
    for (int n = 0; n < 4; n++)
        #pragma unroll
        for (int i = 0; i < 2; i++)
            acc2[n][i] = (f32x4){0.f, 0.f, 0.f, 0.f};

    for (int ph = 0; ph < 2; ph++) {
        for (int ntl = 0; ntl < 8; ntl++) {
            int nt = ph*8 + ntl;
            f32x4 c0 = (f32x4){0.f,0.f,0.f,0.f};
            f32x4 c1 = (f32x4){0.f,0.f,0.f,0.f};
            #pragma unroll
            for (int kc = 0; kc < 2; kc++) {
                bfrag bb = *(const bfrag*)(W1B + (nt*16 + m16)*64 + kc*32 + q*8);
                c0 = __builtin_amdgcn_mfma_f32_16x16x32_bf16(a1[0][kc], bb, c0, 0, 0, 0);
                c1 = __builtin_amdgcn_mfma_f32_16x16x32_bf16(a1[1][kc], bb, c1, 0, 0, 0);
            }
            float bias = b1[nt*16 + m16];
            #pragma unroll
            for (int r = 0; r < 4; r++) {
                int r0 = q*4 + r;
                int r1 = 16 + q*4 + r;
                reg[r0*136 + ntl*16 + m16] = f2bf(gelu_f(c0[r] + bias));
                reg[r1*136 + ntl*16 + m16] = f2bf(gelu_f(c1[r] + bias));
            }
        }
        __builtin_amdgcn_wave_barrier();
        for (int kc2 = 0; kc2 < 4; kc2++) {
            bfrag a2[2];
            #pragma unroll
            for (int i = 0; i < 2; i++)
                a2[i] = *(const bfrag*)(reg + (i*16 + m16)*136 + kc2*32 + q*8);
            #pragma unroll
            for (int nc = 0; nc < 4; nc++) {
                bfrag bb = *(const bfrag*)(W2B + (nc*16 + m16)*256 + ph*128 + kc2*32 + q*8);
                acc2[nc][0] = __builtin_amdgcn_mfma_f32_16x16x32_bf16(a2[0], bb, acc2[nc][0], 0, 0, 0);
                acc2[nc][1] = __builtin_amdgcn_mfma_f32_16x16x32_bf16(a2[1], bb, acc2[nc][1], 0, 0, 0);
            }
        }
        __builtin_amdgcn_wave_barrier();
    }

    // ---- Epilogue ----
    float p0[2][4], p1[2][4];
    #pragma unroll
    for (int i = 0; i < 2; i++) {
        #pragma unroll
        for (int r = 0; r < 4; r++) {
            int rowl = 32*w + i*16 + q*4 + r;
            int row  = blockRow + rowl;
            bool ok  = row < N_ROWS;
            float vals[4];
            #pragma unroll
            for (int nc = 0; nc < 4; nc++) vals[nc] = acc2[nc][i][r] + pb2[nc*16 + m16];
            if (has_res && ok) {
                #pragma unroll
                for (int nc = 0; nc < 4; nc++)
                    vals[nc] += __bfloat162float(x_old[(size_t)row*64 + nc*16 + m16]);
            }
            if (write_x && ok) {
                #pragma unroll
                for (int nc = 0; nc < 4; nc++)
                    store_bf16_packed(x_new, row, nc*16, m16, vals[nc]);
            }
            float q0 = 0.f, q1 = 0.f;
            #pragma unroll
            for (int nc = 0; nc < 4; nc++) {
                int c = nc*16 + m16;
                q0 += vals[nc]*Wr[2*c];
                q1 += vals[nc]*Wr[2*c + 1];
            }
            p0[i][r] = q0; p1[i][r] = q1;
        }
    }
    #pragma unroll
    for (int s = 1; s < 16; s <<= 1) {
        #pragma unroll
        for (int i = 0; i < 2; i++)
            #pragma unroll
            for (int r = 0; r < 4; r++) {
                p0[i][r] += __shfl_xor(p0[i][r], s);
                p1[i][r] += __shfl_xor(p1[i][r], s);
            }
    }
    if (m16 == 0) {
        #pragma unroll
        for (int i = 0; i < 2; i++)
            #pragma unroll
            for (int r = 0; r < 4; r++) {
                int row = blockRow + 32*w + i*16 + q*4 + r;
                if (row < N_ROWS) {
                    atomicAdd(&racc[row*2 + 0], p0[i][r] + br[0]);
                    atomicAdd(&racc[row*2 + 1], p1[i][r] + br[1]);
                }
            }
    }
}

// ---------------------------------------------------------------------------
// K6: readout (unchanged)
// ---------------------------------------------------------------------------
__global__ __launch_bounds__(256) void final_kernel(
    const float* __restrict__ racc, const float* __restrict__ ori,
    const int* __restrict__ batch, float* __restrict__ out)
{
    int v = blockIdx.x*256 + threadIdx.x;
    if (v >= N_NODES) return;
    float srs = 0.f, vx = 0.f, vy = 0.f, vz = 0.f;
    #pragma unroll
    for (int p = 0; p < 12; p++) {
        float r0 = racc[v*24 + 2*p], r1 = racc[v*24 + 2*p + 1];
        srs += r0;
        vx += r1*ori[3*p]; vy += r1*ori[3*p+1]; vz += r1*ori[3*p+2];
    }
    const float sc = 1.0f/24.0f;
    int g = batch[v];
    atomicAdd(&out[g], srs*sc);
    atomicAdd(&out[16 + g*3 + 0], vx*sc);
    atomicAdd(&out[16 + g*3 + 1], vy*sc);
    atomicAdd(&out[16 + g*3 + 2], vz*sc);
}

extern "C" void kernel_launch(void* const* d_in, const int* in_sizes, int n_in,
                              void* d_out, int out_size, void* d_ws, size_t ws_size,
                              hipStream_t stream) {
    const float* pos    = (const float*)d_in[0];
    const float* f      = (const float*)d_in[1];
    const float* ori    = (const float*)d_in[2];
    const int*   ei     = (const int*)  d_in[3];
    const int*   batch  = (const int*)  d_in[4];
    const float* Wb1    = (const float*)d_in[5];
    const float* bb1    = (const float*)d_in[6];
    const float* Wb2    = (const float*)d_in[7];
    const float* bb2    = (const float*)d_in[8];
    const float* Wo1    = (const float*)d_in[9];
    const float* bo1    = (const float*)d_in[10];
    const float* Wo2    = (const float*)d_in[11];
    const float* bo2    = (const float*)d_in[12];
    const float* We     = (const float*)d_in[13];
    const float* Wk     = (const float*)d_in[14];
    const float* Wf     = (const float*)d_in[15];
    const float* conv_b = (const float*)d_in[16];
    const float* ln_g   = (const float*)d_in[17];
    const float* ln_b   = (const float*)d_in[18];
    const float* W1     = (const float*)d_in[19];
    const float* b1     = (const float*)d_in[20];
    const float* W2     = (const float*)d_in[21];
    const float* b2     = (const float*)d_in[22];
    const float* Wr     = (const float*)d_in[23];
    const float* br     = (const float*)d_in[24];
    float* out = (float*)d_out;

    float* ws   = (float*)d_ws;
    float* xe   = ws;                               //   640,000 f32
    short* xs1b = (short*)(xe + 640000);            // 7,680,000 bf16
    short* x1b  = xs1b + 7680000;                   // 7,680,000 bf16
    float* racc = (float*)(x1b + 7680000);          //   240,000 f32
    float* fkb  = racc + 240000;                    //    18,432
    short* w1b  = (short*)(fkb + 18432);            //    32,768 shorts
    short* w2b  = w1b + 32768;
    short* w1k  = w2b + 32768;
    short* w2k  = w1k + 2048;
    short* wkb  = w2k + 4096;
    int*   deg  = (int*)(wkb + 8192);               //    10,000 ints
    int*   rp   = deg + 10000;
    int*   wp   = rp  + 10001;
    int*   perm = wp  + 10000;
    int*   srcOf= perm+ 80000;
    int*   pad_ = srcOf + 80000;
    __hip_bfloat16* akb1 = (__hip_bfloat16*)(pad_ + 3);   // 61,440,000 bf16

    hipMemsetAsync(out,  0, 64*sizeof(float), stream);
    hipMemsetAsync(racc, 0, 240000*sizeof(float), stream);
    hipMemsetAsync(x1b,  0, 7680000*sizeof(short), stream);
    hipMemsetAsync(deg,  0, 10000*sizeof(int), stream);

    csr_count<<<313, 256, 0, stream>>>(ei, deg);
    csr_scan <<<1,   256, 0, stream>>>(deg, rp, wp);
    csr_fill <<<313, 256, 0, stream>>>(ei, wp, perm, srcOf);

    prep_weights<<<4,    256, 0, stream>>>(W1, W2, Wb1, Wb2, Wk,
                                           w1b, w2b, w1k, w2k, wkb);
    ori_kernel  <<<144,  64, 0, stream>>>(ori, Wo1, bo1, Wo2, bo2, Wf, fkb);
    embed_kernel<<<2500, 256, 0, stream>>>(f, We, xe);

    // kb MLP + akb GEMMs + fused layer-0 pk-bf16 scatter + akb1 store
    kb_mfma     <<<3750, 256, 0, stream>>>(pos, ori, w1k, bb1, w2k, bb2,
                                           wkb, ei, xe, (__hip_bfloat16*)x1b, akb1);

    node_mfma   <<<938,  256, 0, stream>>>(x1b, fkb, conv_b, ln_g, ln_b,
                                           w1b, b1, w2b, b2, Wr, br,
                                           (const __hip_bfloat16*)xs1b, (__hip_bfloat16*)xs1b,
                                           racc, /*res=*/0, /*write=*/1);

    gather1     <<<30000,256, 0, stream>>>(akb1, perm, srcOf, rp,
                                           (const __hip_bfloat16*)xs1b, (__hip_bfloat16*)x1b);

    node_mfma   <<<938,  256, 0, stream>>>(x1b, fkb + 9216, conv_b + 64, ln_g + 64, ln_b + 64,
                                           w1b + 16384, b1 + 256, w2b + 16384, b2 + 64,
                                           Wr + 128, br + 2,
                                           (const __hip_bfloat16*)xs1b, (__hip_bfloat16*)xs1b,
                                           racc, /*res=*/1, /*write=*/0);

    final_kernel<<<40,   256, 0, stream>>>(racc, ori, batch, out);
}

// Round 11
// 1031.973 us; speedup vs baseline: 1.2299x; 1.0604x over previous
//
#include <hip/hip_runtime.h>
#include <hip/hip_bf16.h>
#include <math.h>

#define N_NODES 10000
#define N_EDGES 80000
#define N_ORI   12
#define N_ROWS  (N_NODES * N_ORI)

typedef __attribute__((ext_vector_type(8))) short bfrag;   // 8 bf16 = 4 VGPRs
typedef __attribute__((ext_vector_type(4))) float f32x4;

__device__ __forceinline__ float gelu_f(float x) {
    return 0.5f * x * (1.0f + erff(x * 0.70710678118654752440f));
}
__device__ __forceinline__ short f2bf(float x) {
    __hip_bfloat16 h = __float2bfloat16(x);
    return *reinterpret_cast<short*>(&h);
}
__device__ __forceinline__ float bflo(unsigned u) { return __uint_as_float(u << 16); }
__device__ __forceinline__ float bfhi(unsigned u) { return __uint_as_float(u & 0xffff0000u); }

// packed bf16 store: 4 cols / 8 B per quad of lanes -> full 128 B lines
__device__ __forceinline__ void store_bf16_packed(
    __hip_bfloat16* base, int row64, int colBase, int m16, float val)
{
    int my = (int)(unsigned short)f2bf(val);
    int p1 = __shfl_xor(my, 1);
    int packed01 = my | (p1 << 16);
    int p2 = __shfl_xor(packed01, 2);
    if ((m16 & 3) == 0) {
        int2 st; st.x = packed01; st.y = p2;
        *(int2*)((short*)base + (size_t)row64*64 + colBase + m16) = st;
    }
}

// ---------------------------------------------------------------------------
// CSR build (dst-sorted edge list for gathers)
// ---------------------------------------------------------------------------
__global__ __launch_bounds__(256) void csr_count(
    const int* __restrict__ ei, int* __restrict__ deg)
{
    int e = blockIdx.x*256 + threadIdx.x;
    if (e < N_EDGES) atomicAdd(&deg[ei[N_EDGES + e]], 1);
}

__global__ __launch_bounds__(256) void csr_scan(
    const int* __restrict__ deg, int* __restrict__ rp, int* __restrict__ wp)
{
    __shared__ int part[256];
    __shared__ int sbase[257];
    int t = threadIdx.x;
    int cs = t*40;
    int sum = 0;
    for (int i = 0; i < 40; i++) { int idx = cs+i; if (idx < N_NODES) sum += deg[idx]; }
    part[t] = sum;
    __syncthreads();
    if (t == 0) {
        int run = 0;
        for (int i = 0; i < 256; i++) { sbase[i] = run; run += part[i]; }
        sbase[256] = run;
    }
    __syncthreads();
    int run = sbase[t];
    for (int i = 0; i < 40; i++) {
        int idx = cs+i;
        if (idx < N_NODES) { rp[idx] = run; wp[idx] = run; run += deg[idx]; }
    }
    if (t == 0) rp[N_NODES] = sbase[256];
}

__global__ __launch_bounds__(256) void csr_fill(
    const int* __restrict__ ei, int* __restrict__ wp,
    int* __restrict__ perm, int* __restrict__ srcOf)
{
    int e = blockIdx.x*256 + threadIdx.x;
    if (e >= N_EDGES) return;
    int dn = ei[N_EDGES + e];
    int j = atomicAdd(&wp[dn], 1);
    perm[j] = e;
    srcOf[j] = ei[e];
}

// ---------------------------------------------------------------------------
// K0: weight prep (unchanged)
// ---------------------------------------------------------------------------
__global__ __launch_bounds__(256) void prep_weights(
    const float* __restrict__ W1, const float* __restrict__ W2,
    const float* __restrict__ Wb1, const float* __restrict__ Wb2,
    const float* __restrict__ Wk,
    short* __restrict__ W1B, short* __restrict__ W2B,
    short* __restrict__ W1K, short* __restrict__ W2K,
    short* __restrict__ WkB)
{
    if (blockIdx.x < 2) {
        int l = blockIdx.x;
        const float* w1 = W1 + l*16384; short* w1b = W1B + l*16384;
        const float* w2 = W2 + l*16384; short* w2b = W2B + l*16384;
        for (int i = threadIdx.x; i < 16384; i += 256) {
            int k = i >> 8, t = i & 255;
            w1b[t*64 + k] = f2bf(w1[i]);
            int t2 = i >> 6, c = i & 63;
            w2b[c*256 + t2] = f2bf(w2[i]);
        }
    } else if (blockIdx.x == 2) {
        for (int i = threadIdx.x; i < 2048; i += 256) {
            int t = i >> 5, k = i & 31;
            W1K[i] = (k < 30) ? f2bf(Wb1[k*64 + t]) : (short)0;
        }
        for (int i = threadIdx.x; i < 4096; i += 256) {
            int c = i >> 6, t = i & 63;
            W2K[i] = f2bf(Wb2[t*64 + c]);
        }
    } else {
        for (int i = threadIdx.x; i < 8192; i += 256) {
            int l = i >> 12, rem = i & 4095, k = rem >> 6, c = rem & 63;
            WkB[l*4096 + c*64 + k] = f2bf(Wk[l*4096 + k*64 + c]);
        }
    }
}

// ---------------------------------------------------------------------------
// K1: kb_ori MLP + fk (unchanged)
// ---------------------------------------------------------------------------
__global__ __launch_bounds__(64) void ori_kernel(
    const float* __restrict__ ori, const float* __restrict__ Wo1,
    const float* __restrict__ bo1, const float* __restrict__ Wo2,
    const float* __restrict__ bo2, const float* __restrict__ Wf,
    float* __restrict__ fkb)
{
    __shared__ float sh[64];
    __shared__ float skb[64];
    int i = blockIdx.x / 12, j = blockIdx.x % 12;
    int lane = threadIdx.x;
    float s = ori[3*i]*ori[3*j] + ori[3*i+1]*ori[3*j+1] + ori[3*i+2]*ori[3*j+2];
    float p1 = s, p2 = s*s, p3 = p2*s, p4 = p3*s;
    float acc = bo1[lane] + p1*Wo1[lane] + p2*Wo1[64+lane] + p3*Wo1[128+lane] + p4*Wo1[192+lane];
    sh[lane] = gelu_f(acc);
    __syncthreads();
    float acc2 = bo2[lane];
    #pragma unroll
    for (int k = 0; k < 64; k++) acc2 += sh[k] * Wo2[k*64 + lane];
    skb[lane] = gelu_f(acc2);
    __syncthreads();
    for (int l = 0; l < 2; l++) {
        float a = 0.f;
        #pragma unroll
        for (int k = 0; k < 64; k++) a += skb[k] * Wf[l*4096 + k*64 + lane];
        fkb[l*9216 + i*768 + j*64 + lane] = a;
    }
}

// ---------------------------------------------------------------------------
// K2: x = f @ We (unchanged)
// ---------------------------------------------------------------------------
__global__ __launch_bounds__(256) void embed_kernel(
    const float* __restrict__ f, const float* __restrict__ We, float* __restrict__ xe)
{
    int v = blockIdx.x*4 + (threadIdx.x >> 6);
    int lane = threadIdx.x & 63;
    if (v >= N_NODES) return;
    float acc = 0.f;
    #pragma unroll
    for (int k = 0; k < 16; k++) acc += f[v*16 + k] * We[k*64 + lane];
    xe[v*64 + lane] = acc;
}

// ---------------------------------------------------------------------------
// K3 (v7): kb MLP via MFMA -> akb = kb@Wk, ZERO atomics. Writes akbA (and
// akbB if dual) with packed coalesced bf16 stores. Wave-local LDS union.
// full ws: one launch, dual=1 (both layers). tight ws: two launches, dual=0,
// second launch recomputes the MLP (~90us) but reuses the same 123 MB buffer.
// ---------------------------------------------------------------------------
#define KB_WREG 4736
__global__ __launch_bounds__(256, 4) void kb_mfma(
    const float* __restrict__ pos, const float* __restrict__ ori,
    const short* __restrict__ W1K, const float* __restrict__ bb1,
    const short* __restrict__ W2K, const float* __restrict__ bb2,
    const short* __restrict__ WkA, __hip_bfloat16* __restrict__ akbA,
    const short* __restrict__ WkB2, __hip_bfloat16* __restrict__ akbB,
    int dual, const int* __restrict__ ei)
{
    __shared__ short sU[4*KB_WREG];

    int tid = threadIdx.x;
    int w = tid >> 6, l = tid & 63;
    short* reg  = sU + w*KB_WREG;
    float* envp = (float*)(reg + 64*72);
    int blockRow = blockIdx.x * 256;

    // ---- Phase A: features ----
    {
        int row = blockRow + tid;
        int e = row / 12, o = row - e*12;
        int sn = ei[e], dn = ei[N_EDGES + e];
        float rx = pos[sn*3+0] - pos[dn*3+0];
        float ry = pos[sn*3+1] - pos[dn*3+1];
        float rz = pos[sn*3+2] - pos[dn*3+2];
        float d  = sqrtf(rx*rx + ry*ry + rz*rz);
        float u2 = d*d, u4 = u2*u2, u6 = u4*u2;
        float env = (d < 1.0f) ? (1.0f - 28.0f*u6 + 48.0f*u6*d - 21.0f*u6*u2) : 0.0f;
        envp[l] = env;

        float ox = ori[3*o], oy = ori[3*o+1], oz = ori[3*o+2];
        float a  = rx*ox + ry*oy + rz*oz;
        float qx = rx - a*ox, qy = ry - a*oy, qz = rz - a*oz;
        float b  = sqrtf(qx*qx + qy*qy + qz*qz);

        float fv[32];
        fv[0] = a; fv[1] = b;
        fv[2] = a*a; fv[3] = a*b; fv[4] = b*a; fv[5] = b*b;
        #pragma unroll
        for (int i = 0; i < 4; i++) { fv[6+2*i] = fv[2+i]*a; fv[7+2*i] = fv[2+i]*b; }
        #pragma unroll
        for (int i = 0; i < 8; i++) { fv[14+2*i] = fv[6+i]*a; fv[15+2*i] = fv[6+i]*b; }
        fv[30] = 0.f; fv[31] = 0.f;

        short* dst = reg + l*40;
        #pragma unroll
        for (int blk = 0; blk < 4; blk++) {
            union { short s[8]; int4 v4; } u;
            #pragma unroll
            for (int jj = 0; jj < 8; jj++) u.s[jj] = f2bf(fv[blk*8 + jj]);
            *(int4*)(dst + blk*8) = u.v4;
        }
    }
    __builtin_amdgcn_wave_barrier();

    int m16 = l & 15, q = l >> 4;

    bfrag a1[4];
    #pragma unroll
    for (int mt = 0; mt < 4; mt++)
        a1[mt] = *(const bfrag*)(reg + (mt*16 + m16)*40 + q*8);
    __builtin_amdgcn_wave_barrier();

    // ---- FFN1: K=32 ----
    #pragma unroll
    for (int nt = 0; nt < 4; nt++) {
        bfrag bb = *(const bfrag*)(W1K + (nt*16 + m16)*32 + q*8);
        float bias = bb1[nt*16 + m16];
        #pragma unroll
        for (int mt = 0; mt < 4; mt++) {
            f32x4 acc = (f32x4){0.f,0.f,0.f,0.f};
            acc = __builtin_amdgcn_mfma_f32_16x16x32_bf16(a1[mt], bb, acc, 0, 0, 0);
            #pragma unroll
            for (int r = 0; r < 4; r++) {
                int rl = mt*16 + q*4 + r;
                reg[rl*72 + nt*16 + m16] = f2bf(gelu_f(acc[r] + bias));
            }
        }
    }
    __builtin_amdgcn_wave_barrier();

    // ---- FFN2: K=64 -> kb back into sH ----
    bfrag a2[4][2];
    #pragma unroll
    for (int mt = 0; mt < 4; mt++)
        #pragma unroll
        for (int kc = 0; kc < 2; kc++)
            a2[mt][kc] = *(const bfrag*)(reg + (mt*16 + m16)*72 + kc*32 + q*8);
    __builtin_amdgcn_wave_barrier();

    #pragma unroll
    for (int nt = 0; nt < 4; nt++) {
        f32x4 acc[4];
        #pragma unroll
        for (int mt = 0; mt < 4; mt++) acc[mt] = (f32x4){0.f,0.f,0.f,0.f};
        #pragma unroll
        for (int kc = 0; kc < 2; kc++) {
            bfrag bb = *(const bfrag*)(W2K + (nt*16 + m16)*64 + kc*32 + q*8);
            #pragma unroll
            for (int mt = 0; mt < 4; mt++)
                acc[mt] = __builtin_amdgcn_mfma_f32_16x16x32_bf16(a2[mt][kc], bb, acc[mt], 0, 0, 0);
        }
        float bias = bb2[nt*16 + m16];
        #pragma unroll
        for (int mt = 0; mt < 4; mt++) {
            #pragma unroll
            for (int r = 0; r < 4; r++) {
                int rl = mt*16 + q*4 + r;
                reg[rl*72 + nt*16 + m16] = f2bf(gelu_f(acc[mt][r] + bias) * envp[rl]);
            }
        }
    }
    __builtin_amdgcn_wave_barrier();

    // ---- akb GEMMs + packed coalesced stores ----
    bfrag a3[4][2];
    #pragma unroll
    for (int mt = 0; mt < 4; mt++)
        #pragma unroll
        for (int kc = 0; kc < 2; kc++)
            a3[mt][kc] = *(const bfrag*)(reg + (mt*16 + m16)*72 + kc*32 + q*8);

    #pragma unroll
    for (int nt = 0; nt < 4; nt++) {
        f32x4 acc[4];
        #pragma unroll
        for (int mt = 0; mt < 4; mt++) acc[mt] = (f32x4){0.f,0.f,0.f,0.f};
        #pragma unroll
        for (int kc = 0; kc < 2; kc++) {
            bfrag bb = *(const bfrag*)(WkA + (nt*16 + m16)*64 + kc*32 + q*8);
            #pragma unroll
            for (int mt = 0; mt < 4; mt++)
                acc[mt] = __builtin_amdgcn_mfma_f32_16x16x32_bf16(a3[mt][kc], bb, acc[mt], 0, 0, 0);
        }
        #pragma unroll
        for (int mt = 0; mt < 4; mt++)
            #pragma unroll
            for (int r = 0; r < 4; r++) {
                int R = blockRow + w*64 + mt*16 + q*4 + r;
                store_bf16_packed(akbA, R, nt*16, m16, acc[mt][r]);
            }
    }
    if (dual) {
        #pragma unroll
        for (int nt = 0; nt < 4; nt++) {
            f32x4 acc[4];
            #pragma unroll
            for (int mt = 0; mt < 4; mt++) acc[mt] = (f32x4){0.f,0.f,0.f,0.f};
            #pragma unroll
            for (int kc = 0; kc < 2; kc++) {
                bfrag bb = *(const bfrag*)(WkB2 + (nt*16 + m16)*64 + kc*32 + q*8);
                #pragma unroll
                for (int mt = 0; mt < 4; mt++)
                    acc[mt] = __builtin_amdgcn_mfma_f32_16x16x32_bf16(a3[mt][kc], bb, acc[mt], 0, 0, 0);
            }
            #pragma unroll
            for (int mt = 0; mt < 4; mt++)
                #pragma unroll
                for (int r = 0; r < 4; r++) {
                    int R = blockRow + w*64 + mt*16 + q*4 + r;
                    store_bf16_packed(akbB, R, nt*16, m16, acc[mt][r]);
                }
        }
    }
}

// ---------------------------------------------------------------------------
// K4a: layer-0 CSR gather: x1[v,o,c] = sum_seg akb0[e,o,c] * xe[src,c]
// ---------------------------------------------------------------------------
__global__ __launch_bounds__(256) void gather0(
    const __hip_bfloat16* __restrict__ akb, const int* __restrict__ perm,
    const int* __restrict__ srcOf, const int* __restrict__ rp,
    const float* __restrict__ xe, __hip_bfloat16* __restrict__ x1)
{
    int w = threadIdx.x >> 6, lane = threadIdx.x & 63;
    int g = blockIdx.x*4 + w;
    int v = g / 12, o = g - v*12;
    int jb = rp[v], je = rp[v+1];
    float acc = 0.f;
    for (int j = jb; j < je; j++) {
        int e = perm[j];
        float a  = __bfloat162float(akb[(size_t)e*768 + o*64 + lane]);
        float xs = xe[(size_t)srcOf[j]*64 + lane];
        acc += a * xs;
    }
    x1[(size_t)v*768 + o*64 + lane] = __float2bfloat16(acc);
}

// ---------------------------------------------------------------------------
// K4b: layer-1 CSR gather (bf16 in, bf16 out)
// ---------------------------------------------------------------------------
__global__ __launch_bounds__(256) void gather1(
    const __hip_bfloat16* __restrict__ akb, const int* __restrict__ perm,
    const int* __restrict__ srcOf, const int* __restrict__ rp,
    const __hip_bfloat16* __restrict__ x_in, __hip_bfloat16* __restrict__ x1)
{
    int w = threadIdx.x >> 6, lane = threadIdx.x & 63;
    int g = blockIdx.x*4 + w;
    int v = g / 12, o = g - v*12;
    int jb = rp[v], je = rp[v+1];
    float acc = 0.f;
    for (int j = jb; j < je; j++) {
        int e = perm[j];
        float a  = __bfloat162float(akb[(size_t)e*768 + o*64 + lane]);
        float xs = __bfloat162float(x_in[(size_t)srcOf[j]*768 + o*64 + lane]);
        acc += a * xs;
    }
    x1[(size_t)v*768 + o*64 + lane] = __float2bfloat16(acc);
}

// ---------------------------------------------------------------------------
// K5 (v3): node kernel (unchanged from r10 — known good)
// ---------------------------------------------------------------------------
#define ND_WREG 4352
__global__ __launch_bounds__(256, 4) void node_mfma(
    const short* __restrict__ x1, const float* __restrict__ fk,
    const float* __restrict__ conv_b, const float* __restrict__ ln_g,
    const float* __restrict__ ln_b,
    const short* __restrict__ W1B, const float* __restrict__ b1,
    const short* __restrict__ W2B, const float* __restrict__ pb2,
    const float* __restrict__ Wr, const float* __restrict__ br,
    const __hip_bfloat16* __restrict__ x_old, __hip_bfloat16* __restrict__ x_new,
    float* __restrict__ racc, int has_res, int write_x)
{
    __shared__ short sU[4*ND_WREG];

    int tid = threadIdx.x;
    int w   = tid >> 6;
    int blockRow = blockIdx.x * 128;
    short* reg = sU + w*ND_WREG;

    {
        int rl = tid >> 1, hf = tid & 1;
        int lr = rl - 32*w;
        int row = blockRow + rl;
        int rc = row < N_ROWS ? row : N_ROWS - 1;
        int v = rc / 12, pp = rc % 12;
        float h[32];
        #pragma unroll
        for (int k = 0; k < 32; k++) h[k] = 0.f;
        const short* xv = x1 + (size_t)v*768 + hf*32;
        const float* fp = fk + (size_t)pp*768 + hf*32;
        for (int o = 0; o < 12; o++) {
            const int4*  xa = (const int4*)(xv + o*64);
            const float4* fa = (const float4*)(fp + o*64);
            #pragma unroll
            for (int k4 = 0; k4 < 4; k4++) {
                int4 xi = xa[k4];
                float4 f0 = fa[2*k4], f1 = fa[2*k4+1];
                h[8*k4+0] += bflo((unsigned)xi.x)*f0.x; h[8*k4+1] += bfhi((unsigned)xi.x)*f0.y;
                h[8*k4+2] += bflo((unsigned)xi.y)*f0.z; h[8*k4+3] += bfhi((unsigned)xi.y)*f0.w;
                h[8*k4+4] += bflo((unsigned)xi.z)*f1.x; h[8*k4+5] += bfhi((unsigned)xi.z)*f1.y;
                h[8*k4+6] += bflo((unsigned)xi.w)*f1.z; h[8*k4+7] += bfhi((unsigned)xi.w)*f1.w;
            }
        }
        const float inv12 = 1.0f/12.0f;
        float sum = 0.f;
        #pragma unroll
        for (int k = 0; k < 32; k++) { h[k] = h[k]*inv12 + conv_b[hf*32 + k]; sum += h[k]; }
        sum += __shfl_xor(sum, 1);
        float mu = sum * (1.0f/64.0f);
        float var = 0.f;
        #pragma unroll
        for (int k = 0; k < 32; k++) { float xc = h[k] - mu; var += xc*xc; }
        var += __shfl_xor(var, 1);
        float rstd = rsqrtf(var*(1.0f/64.0f) + 1e-5f);
        short* dst = reg + lr*72 + hf*32;
        #pragma unroll
        for (int blk = 0; blk < 4; blk++) {
            union { short s[8]; int4 v4; } u;
            #pragma unroll
            for (int jj = 0; jj < 8; jj++) {
                int k = blk*8 + jj, c = hf*32 + k;
                u.s[jj] = f2bf((h[k] - mu)*rstd*ln_g[c] + ln_b[c]);
            }
            *(int4*)(dst + blk*8) = u.v4;
        }
    }
    __builtin_amdgcn_wave_barrier();

    int l   = tid & 63;
    int m16 = l & 15, q = l >> 4;

    bfrag a1[2][2];
    #pragma unroll
    for (int i = 0; i < 2; i++)
        #pragma unroll
        for (int kc = 0; kc < 2; kc++)
            a1[i][kc] = *(const bfrag*)(reg + (i*16 + m16)*72 + kc*32 + q*8);
    __builtin_amdgcn_wave_barrier();

    f32x4 acc2[4][2];
    #pragma unroll
    for (int n = 0; n < 4; n++)
        #pragma unroll
        for (int i = 0; i < 2; i++)
            acc2[n][i] = (f32x4){0.f, 0.f, 0.f, 0.f};

    for (int ph = 0; ph < 2; ph++) {
        for (int ntl = 0; ntl < 8; ntl++) {
            int nt = ph*8 + ntl;
            f32x4 c0 = (f32x4){0.f,0.f,0.f,0.f};
            f32x4 c1 = (f32x4){0.f,0.f,0.f,0.f};
            #pragma unroll
            for (int kc = 0; kc < 2; kc++) {
                bfrag bb = *(const bfrag*)(W1B + (nt*16 + m16)*64 + kc*32 + q*8);
                c0 = __builtin_amdgcn_mfma_f32_16x16x32_bf16(a1[0][kc], bb, c0, 0, 0, 0);
                c1 = __builtin_amdgcn_mfma_f32_16x16x32_bf16(a1[1][kc], bb, c1, 0, 0, 0);
            }
            float bias = b1[nt*16 + m16];
            #pragma unroll
            for (int r = 0; r < 4; r++) {
                int r0 = q*4 + r;
                int r1 = 16 + q*4 + r;
                reg[r0*136 + ntl*16 + m16] = f2bf(gelu_f(c0[r] + bias));
                reg[r1*136 + ntl*16 + m16] = f2bf(gelu_f(c1[r] + bias));
            }
        }
        __builtin_amdgcn_wave_barrier();
        for (int kc2 = 0; kc2 < 4; kc2++) {
            bfrag a2[2];
            #pragma unroll
            for (int i = 0; i < 2; i++)
                a2[i] = *(const bfrag*)(reg + (i*16 + m16)*136 + kc2*32 + q*8);
            #pragma unroll
            for (int nc = 0; nc < 4; nc++) {
                bfrag bb = *(const bfrag*)(W2B + (nc*16 + m16)*256 + ph*128 + kc2*32 + q*8);
                acc2[nc][0] = __builtin_amdgcn_mfma_f32_16x16x32_bf16(a2[0], bb, acc2[nc][0], 0, 0, 0);
                acc2[nc][1] = __builtin_amdgcn_mfma_f32_16x16x32_bf16(a2[1], bb, acc2[nc][1], 0, 0, 0);
            }
        }
        __builtin_amdgcn_wave_barrier();
    }

    float p0[2][4], p1[2][4];
    #pragma unroll
    for (int i = 0; i < 2; i++) {
        #pragma unroll
        for (int r = 0; r < 4; r++) {
            int rowl = 32*w + i*16 + q*4 + r;
            int row  = blockRow + rowl;
            bool ok  = row < N_ROWS;
            float vals[4];
            #pragma unroll
            for (int nc = 0; nc < 4; nc++) vals[nc] = acc2[nc][i][r] + pb2[nc*16 + m16];
            if (has_res && ok) {
                #pragma unroll
                for (int nc = 0; nc < 4; nc++)
                    vals[nc] += __bfloat162float(x_old[(size_t)row*64 + nc*16 + m16]);
            }
            if (write_x && ok) {
                #pragma unroll
                for (int nc = 0; nc < 4; nc++)
                    store_bf16_packed(x_new, row, nc*16, m16, vals[nc]);
            }
            float q0 = 0.f, q1 = 0.f;
            #pragma unroll
            for (int nc = 0; nc < 4; nc++) {
                int c = nc*16 + m16;
                q0 += vals[nc]*Wr[2*c];
                q1 += vals[nc]*Wr[2*c + 1];
            }
            p0[i][r] = q0; p1[i][r] = q1;
        }
    }
    #pragma unroll
    for (int s = 1; s < 16; s <<= 1) {
        #pragma unroll
        for (int i = 0; i < 2; i++)
            #pragma unroll
            for (int r = 0; r < 4; r++) {
                p0[i][r] += __shfl_xor(p0[i][r], s);
                p1[i][r] += __shfl_xor(p1[i][r], s);
            }
    }
    if (m16 == 0) {
        #pragma unroll
        for (int i = 0; i < 2; i++)
            #pragma unroll
            for (int r = 0; r < 4; r++) {
                int row = blockRow + 32*w + i*16 + q*4 + r;
                if (row < N_ROWS) {
                    atomicAdd(&racc[row*2 + 0], p0[i][r] + br[0]);
                    atomicAdd(&racc[row*2 + 1], p1[i][r] + br[1]);
                }
            }
    }
}

// ---------------------------------------------------------------------------
// K6: readout (unchanged)
// ---------------------------------------------------------------------------
__global__ __launch_bounds__(256) void final_kernel(
    const float* __restrict__ racc, const float* __restrict__ ori,
    const int* __restrict__ batch, float* __restrict__ out)
{
    int v = blockIdx.x*256 + threadIdx.x;
    if (v >= N_NODES) return;
    float srs = 0.f, vx = 0.f, vy = 0.f, vz = 0.f;
    #pragma unroll
    for (int p = 0; p < 12; p++) {
        float r0 = racc[v*24 + 2*p], r1 = racc[v*24 + 2*p + 1];
        srs += r0;
        vx += r1*ori[3*p]; vy += r1*ori[3*p+1]; vz += r1*ori[3*p+2];
    }
    const float sc = 1.0f/24.0f;
    int g = batch[v];
    atomicAdd(&out[g], srs*sc);
    atomicAdd(&out[16 + g*3 + 0], vx*sc);
    atomicAdd(&out[16 + g*3 + 1], vy*sc);
    atomicAdd(&out[16 + g*3 + 2], vz*sc);
}

extern "C" void kernel_launch(void* const* d_in, const int* in_sizes, int n_in,
                              void* d_out, int out_size, void* d_ws, size_t ws_size,
                              hipStream_t stream) {
    const float* pos    = (const float*)d_in[0];
    const float* f      = (const float*)d_in[1];
    const float* ori    = (const float*)d_in[2];
    const int*   ei     = (const int*)  d_in[3];
    const int*   batch  = (const int*)  d_in[4];
    const float* Wb1    = (const float*)d_in[5];
    const float* bb1    = (const float*)d_in[6];
    const float* Wb2    = (const float*)d_in[7];
    const float* bb2    = (const float*)d_in[8];
    const float* Wo1    = (const float*)d_in[9];
    const float* bo1    = (const float*)d_in[10];
    const float* Wo2    = (const float*)d_in[11];
    const float* bo2    = (const float*)d_in[12];
    const float* We     = (const float*)d_in[13];
    const float* Wk     = (const float*)d_in[14];
    const float* Wf     = (const float*)d_in[15];
    const float* conv_b = (const float*)d_in[16];
    const float* ln_g   = (const float*)d_in[17];
    const float* ln_b   = (const float*)d_in[18];
    const float* W1     = (const float*)d_in[19];
    const float* b1     = (const float*)d_in[20];
    const float* W2     = (const float*)d_in[21];
    const float* b2     = (const float*)d_in[22];
    const float* Wr     = (const float*)d_in[23];
    const float* br     = (const float*)d_in[24];
    float* out = (float*)d_out;

    float* ws   = (float*)d_ws;
    float* xe   = ws;                               //   640,000 f32
    short* xs1b = (short*)(xe + 640000);            // 7,680,000 bf16
    short* x1b  = xs1b + 7680000;                   // 7,680,000 bf16
    float* racc = (float*)(x1b + 7680000);          //   240,000 f32
    float* fkb  = racc + 240000;                    //    18,432
    short* w1b  = (short*)(fkb + 18432);            //    32,768 shorts
    short* w2b  = w1b + 32768;
    short* w1k  = w2b + 32768;
    short* w2k  = w1k + 2048;
    short* wkb  = w2k + 4096;
    int*   deg  = (int*)(wkb + 8192);               //    10,000 ints
    int*   rp   = deg + 10000;
    int*   wp   = rp  + 10001;
    int*   perm = wp  + 10000;
    int*   srcOf= perm+ 80000;
    int*   pad_ = srcOf + 80000;
    __hip_bfloat16* akbA = (__hip_bfloat16*)(pad_ + 3);   // 61,440,000 bf16 (~123 MB)
    __hip_bfloat16* akbB = akbA + 61440000;               // second buffer (full mode)

    size_t need_full = ((char*)(akbB + 61440000)) - ((char*)d_ws);
    int full = (ws_size >= need_full) ? 1 : 0;

    hipMemsetAsync(out,  0, 64*sizeof(float), stream);
    hipMemsetAsync(racc, 0, 240000*sizeof(float), stream);
    hipMemsetAsync(deg,  0, 10000*sizeof(int), stream);

    csr_count<<<313, 256, 0, stream>>>(ei, deg);
    csr_scan <<<1,   256, 0, stream>>>(deg, rp, wp);
    csr_fill <<<313, 256, 0, stream>>>(ei, wp, perm, srcOf);

    prep_weights<<<4,    256, 0, stream>>>(W1, W2, Wb1, Wb2, Wk,
                                           w1b, w2b, w1k, w2k, wkb);
    ori_kernel  <<<144,  64, 0, stream>>>(ori, Wo1, bo1, Wo2, bo2, Wf, fkb);
    embed_kernel<<<2500, 256, 0, stream>>>(f, We, xe);

    if (full) {
        // one MLP pass, both akb outputs
        kb_mfma <<<3750, 256, 0, stream>>>(pos, ori, w1k, bb1, w2k, bb2,
                                           wkb, akbA, wkb + 4096, akbB, /*dual=*/1, ei);
        gather0 <<<30000,256, 0, stream>>>(akbA, perm, srcOf, rp, xe, (__hip_bfloat16*)x1b);
        node_mfma<<<938, 256, 0, stream>>>(x1b, fkb, conv_b, ln_g, ln_b,
                                           w1b, b1, w2b, b2, Wr, br,
                                           (const __hip_bfloat16*)xs1b, (__hip_bfloat16*)xs1b,
                                           racc, /*res=*/0, /*write=*/1);
        gather1 <<<30000,256, 0, stream>>>(akbB, perm, srcOf, rp,
                                           (const __hip_bfloat16*)xs1b, (__hip_bfloat16*)x1b);
    } else {
        // two MLP passes reusing one 123 MB akb buffer (atomic-free either way)
        kb_mfma <<<3750, 256, 0, stream>>>(pos, ori, w1k, bb1, w2k, bb2,
                                           wkb, akbA, wkb, akbA, /*dual=*/0, ei);
        gather0 <<<30000,256, 0, stream>>>(akbA, perm, srcOf, rp, xe, (__hip_bfloat16*)x1b);
        node_mfma<<<938, 256, 0, stream>>>(x1b, fkb, conv_b, ln_g, ln_b,
                                           w1b, b1, w2b, b2, Wr, br,
                                           (const __hip_bfloat16*)xs1b, (__hip_bfloat16*)xs1b,
                                           racc, /*res=*/0, /*write=*/1);
        kb_mfma <<<3750, 256, 0, stream>>>(pos, ori, w1k, bb1, w2k, bb2,
                                           wkb + 4096, akbA, wkb + 4096, akbA, /*dual=*/0, ei);
        gather1 <<<30000,256, 0, stream>>>(akbA, perm, srcOf, rp,
                                           (const __hip_bfloat16*)xs1b, (__hip_bfloat16*)x1b);
    }

    node_mfma   <<<938,  256, 0, stream>>>(x1b, fkb + 9216, conv_b + 64, ln_g + 64, ln_b + 64,
                                           w1b + 16384, b1 + 256, w2b + 16384, b2 + 64,
                                           Wr + 128, br + 2,
                                           (const __hip_bfloat16*)xs1b, (__hip_bfloat16*)xs1b,
                                           racc, /*res=*/1, /*write=*/0);

    final_kernel<<<40,   256, 0, stream>>>(racc, ori, batch, out);
}

// Round 12
// 851.104 us; speedup vs baseline: 1.4912x; 1.2125x over previous
//
#include <hip/hip_runtime.h>
#include <hip/hip_bf16.h>
#include <math.h>

#define N_NODES 10000
#define N_EDGES 80000
#define N_ORI   12
#define N_ROWS  (N_NODES * N_ORI)

typedef __attribute__((ext_vector_type(8))) short bfrag;   // 8 bf16 = 4 VGPRs
typedef __attribute__((ext_vector_type(4))) float f32x4;

__device__ __forceinline__ float gelu_f(float x) {
    return 0.5f * x * (1.0f + erff(x * 0.70710678118654752440f));
}
__device__ __forceinline__ short f2bf(float x) {
    __hip_bfloat16 h = __float2bfloat16(x);
    return *reinterpret_cast<short*>(&h);
}
__device__ __forceinline__ float bflo(unsigned u) { return __uint_as_float(u << 16); }
__device__ __forceinline__ float bfhi(unsigned u) { return __uint_as_float(u & 0xffff0000u); }

// packed bf16 store: 4 cols / 8 B per quad of lanes -> full 128 B lines
__device__ __forceinline__ void store_bf16_packed(
    __hip_bfloat16* base, int row64, int colBase, int m16, float val)
{
    int my = (int)(unsigned short)f2bf(val);
    int p1 = __shfl_xor(my, 1);
    int packed01 = my | (p1 << 16);
    int p2 = __shfl_xor(packed01, 2);
    if ((m16 & 3) == 0) {
        int2 st; st.x = packed01; st.y = p2;
        *(int2*)((short*)base + (size_t)row64*64 + colBase + m16) = st;
    }
}

// ---------------------------------------------------------------------------
// CSR build (dst-sorted edge list for gathers)
// ---------------------------------------------------------------------------
__global__ __launch_bounds__(256) void csr_count(
    const int* __restrict__ ei, int* __restrict__ deg)
{
    int e = blockIdx.x*256 + threadIdx.x;
    if (e < N_EDGES) atomicAdd(&deg[ei[N_EDGES + e]], 1);
}

__global__ __launch_bounds__(256) void csr_scan(
    const int* __restrict__ deg, int* __restrict__ rp, int* __restrict__ wp)
{
    __shared__ int part[256];
    __shared__ int sbase[257];
    int t = threadIdx.x;
    int cs = t*40;
    int sum = 0;
    for (int i = 0; i < 40; i++) { int idx = cs+i; if (idx < N_NODES) sum += deg[idx]; }
    part[t] = sum;
    __syncthreads();
    if (t == 0) {
        int run = 0;
        for (int i = 0; i < 256; i++) { sbase[i] = run; run += part[i]; }
        sbase[256] = run;
    }
    __syncthreads();
    int run = sbase[t];
    for (int i = 0; i < 40; i++) {
        int idx = cs+i;
        if (idx < N_NODES) { rp[idx] = run; wp[idx] = run; run += deg[idx]; }
    }
    if (t == 0) rp[N_NODES] = sbase[256];
}

__global__ __launch_bounds__(256) void csr_fill(
    const int* __restrict__ ei, int* __restrict__ wp,
    int* __restrict__ perm, int* __restrict__ srcOf)
{
    int e = blockIdx.x*256 + threadIdx.x;
    if (e >= N_EDGES) return;
    int dn = ei[N_EDGES + e];
    int j = atomicAdd(&wp[dn], 1);
    perm[j] = e;
    srcOf[j] = ei[e];
}

// ---------------------------------------------------------------------------
// K0: weight prep (unchanged)
// ---------------------------------------------------------------------------
__global__ __launch_bounds__(256) void prep_weights(
    const float* __restrict__ W1, const float* __restrict__ W2,
    const float* __restrict__ Wb1, const float* __restrict__ Wb2,
    const float* __restrict__ Wk,
    short* __restrict__ W1B, short* __restrict__ W2B,
    short* __restrict__ W1K, short* __restrict__ W2K,
    short* __restrict__ WkB)
{
    if (blockIdx.x < 2) {
        int l = blockIdx.x;
        const float* w1 = W1 + l*16384; short* w1b = W1B + l*16384;
        const float* w2 = W2 + l*16384; short* w2b = W2B + l*16384;
        for (int i = threadIdx.x; i < 16384; i += 256) {
            int k = i >> 8, t = i & 255;
            w1b[t*64 + k] = f2bf(w1[i]);
            int t2 = i >> 6, c = i & 63;
            w2b[c*256 + t2] = f2bf(w2[i]);
        }
    } else if (blockIdx.x == 2) {
        for (int i = threadIdx.x; i < 2048; i += 256) {
            int t = i >> 5, k = i & 31;
            W1K[i] = (k < 30) ? f2bf(Wb1[k*64 + t]) : (short)0;
        }
        for (int i = threadIdx.x; i < 4096; i += 256) {
            int c = i >> 6, t = i & 63;
            W2K[i] = f2bf(Wb2[t*64 + c]);
        }
    } else {
        for (int i = threadIdx.x; i < 8192; i += 256) {
            int l = i >> 12, rem = i & 4095, k = rem >> 6, c = rem & 63;
            WkB[l*4096 + c*64 + k] = f2bf(Wk[l*4096 + k*64 + c]);
        }
    }
}

// ---------------------------------------------------------------------------
// K1: kb_ori MLP + fk (unchanged)
// ---------------------------------------------------------------------------
__global__ __launch_bounds__(64) void ori_kernel(
    const float* __restrict__ ori, const float* __restrict__ Wo1,
    const float* __restrict__ bo1, const float* __restrict__ Wo2,
    const float* __restrict__ bo2, const float* __restrict__ Wf,
    float* __restrict__ fkb)
{
    __shared__ float sh[64];
    __shared__ float skb[64];
    int i = blockIdx.x / 12, j = blockIdx.x % 12;
    int lane = threadIdx.x;
    float s = ori[3*i]*ori[3*j] + ori[3*i+1]*ori[3*j+1] + ori[3*i+2]*ori[3*j+2];
    float p1 = s, p2 = s*s, p3 = p2*s, p4 = p3*s;
    float acc = bo1[lane] + p1*Wo1[lane] + p2*Wo1[64+lane] + p3*Wo1[128+lane] + p4*Wo1[192+lane];
    sh[lane] = gelu_f(acc);
    __syncthreads();
    float acc2 = bo2[lane];
    #pragma unroll
    for (int k = 0; k < 64; k++) acc2 += sh[k] * Wo2[k*64 + lane];
    skb[lane] = gelu_f(acc2);
    __syncthreads();
    for (int l = 0; l < 2; l++) {
        float a = 0.f;
        #pragma unroll
        for (int k = 0; k < 64; k++) a += skb[k] * Wf[l*4096 + k*64 + lane];
        fkb[l*9216 + i*768 + j*64 + lane] = a;
    }
}

// ---------------------------------------------------------------------------
// K2: x = f @ We (unchanged)
// ---------------------------------------------------------------------------
__global__ __launch_bounds__(256) void embed_kernel(
    const float* __restrict__ f, const float* __restrict__ We, float* __restrict__ xe)
{
    int v = blockIdx.x*4 + (threadIdx.x >> 6);
    int lane = threadIdx.x & 63;
    if (v >= N_NODES) return;
    float acc = 0.f;
    #pragma unroll
    for (int k = 0; k < 16; k++) acc += f[v*16 + k] * We[k*64 + lane];
    xe[v*64 + lane] = acc;
}

// ---------------------------------------------------------------------------
// K3 (v7): kb MLP via MFMA -> akb = kb@Wk, ZERO atomics. (unchanged r11)
// ---------------------------------------------------------------------------
#define KB_WREG 4736
__global__ __launch_bounds__(256, 4) void kb_mfma(
    const float* __restrict__ pos, const float* __restrict__ ori,
    const short* __restrict__ W1K, const float* __restrict__ bb1,
    const short* __restrict__ W2K, const float* __restrict__ bb2,
    const short* __restrict__ WkA, __hip_bfloat16* __restrict__ akbA,
    const short* __restrict__ WkB2, __hip_bfloat16* __restrict__ akbB,
    int dual, const int* __restrict__ ei)
{
    __shared__ short sU[4*KB_WREG];

    int tid = threadIdx.x;
    int w = tid >> 6, l = tid & 63;
    short* reg  = sU + w*KB_WREG;
    float* envp = (float*)(reg + 64*72);
    int blockRow = blockIdx.x * 256;

    // ---- Phase A: features ----
    {
        int row = blockRow + tid;
        int e = row / 12, o = row - e*12;
        int sn = ei[e], dn = ei[N_EDGES + e];
        float rx = pos[sn*3+0] - pos[dn*3+0];
        float ry = pos[sn*3+1] - pos[dn*3+1];
        float rz = pos[sn*3+2] - pos[dn*3+2];
        float d  = sqrtf(rx*rx + ry*ry + rz*rz);
        float u2 = d*d, u4 = u2*u2, u6 = u4*u2;
        float env = (d < 1.0f) ? (1.0f - 28.0f*u6 + 48.0f*u6*d - 21.0f*u6*u2) : 0.0f;
        envp[l] = env;

        float ox = ori[3*o], oy = ori[3*o+1], oz = ori[3*o+2];
        float a  = rx*ox + ry*oy + rz*oz;
        float qx = rx - a*ox, qy = ry - a*oy, qz = rz - a*oz;
        float b  = sqrtf(qx*qx + qy*qy + qz*qz);

        float fv[32];
        fv[0] = a; fv[1] = b;
        fv[2] = a*a; fv[3] = a*b; fv[4] = b*a; fv[5] = b*b;
        #pragma unroll
        for (int i = 0; i < 4; i++) { fv[6+2*i] = fv[2+i]*a; fv[7+2*i] = fv[2+i]*b; }
        #pragma unroll
        for (int i = 0; i < 8; i++) { fv[14+2*i] = fv[6+i]*a; fv[15+2*i] = fv[6+i]*b; }
        fv[30] = 0.f; fv[31] = 0.f;

        short* dst = reg + l*40;
        #pragma unroll
        for (int blk = 0; blk < 4; blk++) {
            union { short s[8]; int4 v4; } u;
            #pragma unroll
            for (int jj = 0; jj < 8; jj++) u.s[jj] = f2bf(fv[blk*8 + jj]);
            *(int4*)(dst + blk*8) = u.v4;
        }
    }
    __builtin_amdgcn_wave_barrier();

    int m16 = l & 15, q = l >> 4;

    bfrag a1[4];
    #pragma unroll
    for (int mt = 0; mt < 4; mt++)
        a1[mt] = *(const bfrag*)(reg + (mt*16 + m16)*40 + q*8);
    __builtin_amdgcn_wave_barrier();

    // ---- FFN1: K=32 ----
    #pragma unroll
    for (int nt = 0; nt < 4; nt++) {
        bfrag bb = *(const bfrag*)(W1K + (nt*16 + m16)*32 + q*8);
        float bias = bb1[nt*16 + m16];
        #pragma unroll
        for (int mt = 0; mt < 4; mt++) {
            f32x4 acc = (f32x4){0.f,0.f,0.f,0.f};
            acc = __builtin_amdgcn_mfma_f32_16x16x32_bf16(a1[mt], bb, acc, 0, 0, 0);
            #pragma unroll
            for (int r = 0; r < 4; r++) {
                int rl = mt*16 + q*4 + r;
                reg[rl*72 + nt*16 + m16] = f2bf(gelu_f(acc[r] + bias));
            }
        }
    }
    __builtin_amdgcn_wave_barrier();

    // ---- FFN2: K=64 -> kb back into sH ----
    bfrag a2[4][2];
    #pragma unroll
    for (int mt = 0; mt < 4; mt++)
        #pragma unroll
        for (int kc = 0; kc < 2; kc++)
            a2[mt][kc] = *(const bfrag*)(reg + (mt*16 + m16)*72 + kc*32 + q*8);
    __builtin_amdgcn_wave_barrier();

    #pragma unroll
    for (int nt = 0; nt < 4; nt++) {
        f32x4 acc[4];
        #pragma unroll
        for (int mt = 0; mt < 4; mt++) acc[mt] = (f32x4){0.f,0.f,0.f,0.f};
        #pragma unroll
        for (int kc = 0; kc < 2; kc++) {
            bfrag bb = *(const bfrag*)(W2K + (nt*16 + m16)*64 + kc*32 + q*8);
            #pragma unroll
            for (int mt = 0; mt < 4; mt++)
                acc[mt] = __builtin_amdgcn_mfma_f32_16x16x32_bf16(a2[mt][kc], bb, acc[mt], 0, 0, 0);
        }
        float bias = bb2[nt*16 + m16];
        #pragma unroll
        for (int mt = 0; mt < 4; mt++) {
            #pragma unroll
            for (int r = 0; r < 4; r++) {
                int rl = mt*16 + q*4 + r;
                reg[rl*72 + nt*16 + m16] = f2bf(gelu_f(acc[mt][r] + bias) * envp[rl]);
            }
        }
    }
    __builtin_amdgcn_wave_barrier();

    // ---- akb GEMMs + packed coalesced stores ----
    bfrag a3[4][2];
    #pragma unroll
    for (int mt = 0; mt < 4; mt++)
        #pragma unroll
        for (int kc = 0; kc < 2; kc++)
            a3[mt][kc] = *(const bfrag*)(reg + (mt*16 + m16)*72 + kc*32 + q*8);

    #pragma unroll
    for (int nt = 0; nt < 4; nt++) {
        f32x4 acc[4];
        #pragma unroll
        for (int mt = 0; mt < 4; mt++) acc[mt] = (f32x4){0.f,0.f,0.f,0.f};
        #pragma unroll
        for (int kc = 0; kc < 2; kc++) {
            bfrag bb = *(const bfrag*)(WkA + (nt*16 + m16)*64 + kc*32 + q*8);
            #pragma unroll
            for (int mt = 0; mt < 4; mt++)
                acc[mt] = __builtin_amdgcn_mfma_f32_16x16x32_bf16(a3[mt][kc], bb, acc[mt], 0, 0, 0);
        }
        #pragma unroll
        for (int mt = 0; mt < 4; mt++)
            #pragma unroll
            for (int r = 0; r < 4; r++) {
                int R = blockRow + w*64 + mt*16 + q*4 + r;
                store_bf16_packed(akbA, R, nt*16, m16, acc[mt][r]);
            }
    }
    if (dual) {
        #pragma unroll
        for (int nt = 0; nt < 4; nt++) {
            f32x4 acc[4];
            #pragma unroll
            for (int mt = 0; mt < 4; mt++) acc[mt] = (f32x4){0.f,0.f,0.f,0.f};
            #pragma unroll
            for (int kc = 0; kc < 2; kc++) {
                bfrag bb = *(const bfrag*)(WkB2 + (nt*16 + m16)*64 + kc*32 + q*8);
                #pragma unroll
                for (int mt = 0; mt < 4; mt++)
                    acc[mt] = __builtin_amdgcn_mfma_f32_16x16x32_bf16(a3[mt][kc], bb, acc[mt], 0, 0, 0);
            }
            #pragma unroll
            for (int mt = 0; mt < 4; mt++)
                #pragma unroll
                for (int r = 0; r < 4; r++) {
                    int R = blockRow + w*64 + mt*16 + q*4 + r;
                    store_bf16_packed(akbB, R, nt*16, m16, acc[mt][r]);
                }
        }
    }
}

// ---------------------------------------------------------------------------
// K4a: layer-0 CSR gather (unchanged)
// ---------------------------------------------------------------------------
__global__ __launch_bounds__(256) void gather0(
    const __hip_bfloat16* __restrict__ akb, const int* __restrict__ perm,
    const int* __restrict__ srcOf, const int* __restrict__ rp,
    const float* __restrict__ xe, __hip_bfloat16* __restrict__ x1)
{
    int w = threadIdx.x >> 6, lane = threadIdx.x & 63;
    int g = blockIdx.x*4 + w;
    int v = g / 12, o = g - v*12;
    int jb = rp[v], je = rp[v+1];
    float acc = 0.f;
    for (int j = jb; j < je; j++) {
        int e = perm[j];
        float a  = __bfloat162float(akb[(size_t)e*768 + o*64 + lane]);
        float xs = xe[(size_t)srcOf[j]*64 + lane];
        acc += a * xs;
    }
    x1[(size_t)v*768 + o*64 + lane] = __float2bfloat16(acc);
}

// ---------------------------------------------------------------------------
// K4b: layer-1 CSR gather (unchanged)
// ---------------------------------------------------------------------------
__global__ __launch_bounds__(256) void gather1(
    const __hip_bfloat16* __restrict__ akb, const int* __restrict__ perm,
    const int* __restrict__ srcOf, const int* __restrict__ rp,
    const __hip_bfloat16* __restrict__ x_in, __hip_bfloat16* __restrict__ x1)
{
    int w = threadIdx.x >> 6, lane = threadIdx.x & 63;
    int g = blockIdx.x*4 + w;
    int v = g / 12, o = g - v*12;
    int jb = rp[v], je = rp[v+1];
    float acc = 0.f;
    for (int j = jb; j < je; j++) {
        int e = perm[j];
        float a  = __bfloat162float(akb[(size_t)e*768 + o*64 + lane]);
        float xs = __bfloat162float(x_in[(size_t)srcOf[j]*768 + o*64 + lane]);
        acc += a * xs;
    }
    x1[(size_t)v*768 + o*64 + lane] = __float2bfloat16(acc);
}

// ---------------------------------------------------------------------------
// K5 (v3): node kernel (unchanged from r10/r11 — known good)
// ---------------------------------------------------------------------------
#define ND_WREG 4352
__global__ __launch_bounds__(256, 4) void node_mfma(
    const short* __restrict__ x1, const float* __restrict__ fk,
    const float* __restrict__ conv_b, const float* __restrict__ ln_g,
    const float* __restrict__ ln_b,
    const short* __restrict__ W1B, const float* __restrict__ b1,
    const short* __restrict__ W2B, const float* __restrict__ pb2,
    const float* __restrict__ Wr, const float* __restrict__ br,
    const __hip_bfloat16* __restrict__ x_old, __hip_bfloat16* __restrict__ x_new,
    float* __restrict__ racc, int has_res, int write_x)
{
    __shared__ short sU[4*ND_WREG];

    int tid = threadIdx.x;
    int w   = tid >> 6;
    int blockRow = blockIdx.x * 128;
    short* reg = sU + w*ND_WREG;

    {
        int rl = tid >> 1, hf = tid & 1;
        int lr = rl - 32*w;
        int row = blockRow + rl;
        int rc = row < N_ROWS ? row : N_ROWS - 1;
        int v = rc / 12, pp = rc % 12;
        float h[32];
        #pragma unroll
        for (int k = 0; k < 32; k++) h[k] = 0.f;
        const short* xv = x1 + (size_t)v*768 + hf*32;
        const float* fp = fk + (size_t)pp*768 + hf*32;
        for (int o = 0; o < 12; o++) {
            const int4*  xa = (const int4*)(xv + o*64);
            const float4* fa = (const float4*)(fp + o*64);
            #pragma unroll
            for (int k4 = 0; k4 < 4; k4++) {
                int4 xi = xa[k4];
                float4 f0 = fa[2*k4], f1 = fa[2*k4+1];
                h[8*k4+0] += bflo((unsigned)xi.x)*f0.x; h[8*k4+1] += bfhi((unsigned)xi.x)*f0.y;
                h[8*k4+2] += bflo((unsigned)xi.y)*f0.z; h[8*k4+3] += bfhi((unsigned)xi.y)*f0.w;
                h[8*k4+4] += bflo((unsigned)xi.z)*f1.x; h[8*k4+5] += bfhi((unsigned)xi.z)*f1.y;
                h[8*k4+6] += bflo((unsigned)xi.w)*f1.z; h[8*k4+7] += bfhi((unsigned)xi.w)*f1.w;
            }
        }
        const float inv12 = 1.0f/12.0f;
        float sum = 0.f;
        #pragma unroll
        for (int k = 0; k < 32; k++) { h[k] = h[k]*inv12 + conv_b[hf*32 + k]; sum += h[k]; }
        sum += __shfl_xor(sum, 1);
        float mu = sum * (1.0f/64.0f);
        float var = 0.f;
        #pragma unroll
        for (int k = 0; k < 32; k++) { float xc = h[k] - mu; var += xc*xc; }
        var += __shfl_xor(var, 1);
        float rstd = rsqrtf(var*(1.0f/64.0f) + 1e-5f);
        short* dst = reg + lr*72 + hf*32;
        #pragma unroll
        for (int blk = 0; blk < 4; blk++) {
            union { short s[8]; int4 v4; } u;
            #pragma unroll
            for (int jj = 0; jj < 8; jj++) {
                int k = blk*8 + jj, c = hf*32 + k;
                u.s[jj] = f2bf((h[k] - mu)*rstd*ln_g[c] + ln_b[c]);
            }
            *(int4*)(dst + blk*8) = u.v4;
        }
    }
    __builtin_amdgcn_wave_barrier();

    int l   = tid & 63;
    int m16 = l & 15, q = l >> 4;

    bfrag a1[2][2];
    #pragma unroll
    for (int i = 0; i < 2; i++)
        #pragma unroll
        for (int kc = 0; kc < 2; kc++)
            a1[i][kc] = *(const bfrag*)(reg + (i*16 + m16)*72 + kc*32 + q*8);
    __builtin_amdgcn_wave_barrier();

    f32x4 acc2[4][2];
    #pragma unroll
    for (int n = 0; n < 4; n++)
        #pragma unroll
        for (int i = 0; i < 2; i++)
            acc2[n][i] = (f32x4){0.f, 0.f, 0.f, 0.f};

    for (int ph = 0; ph < 2; ph++) {
        for (int ntl = 0; ntl < 8; ntl++) {
            int nt = ph*8 + ntl;
            f32x4 c0 = (f32x4){0.f,0.f,0.f,0.f};
            f32x4 c1 = (f32x4){0.f,0.f,0.f,0.f};
            #pragma unroll
            for (int kc = 0; kc < 2; kc++) {
                bfrag bb = *(const bfrag*)(W1B + (nt*16 + m16)*64 + kc*32 + q*8);
                c0 = __builtin_amdgcn_mfma_f32_16x16x32_bf16(a1[0][kc], bb, c0, 0, 0, 0);
                c1 = __builtin_amdgcn_mfma_f32_16x16x32_bf16(a1[1][kc], bb, c1, 0, 0, 0);
            }
            float bias = b1[nt*16 + m16];
            #pragma unroll
            for (int r = 0; r < 4; r++) {
                int r0 = q*4 + r;
                int r1 = 16 + q*4 + r;
                reg[r0*136 + ntl*16 + m16] = f2bf(gelu_f(c0[r] + bias));
                reg[r1*136 + ntl*16 + m16] = f2bf(gelu_f(c1[r] + bias));
            }
        }
        __builtin_amdgcn_wave_barrier();
        for (int kc2 = 0; kc2 < 4; kc2++) {
            bfrag a2[2];
            #pragma unroll
            for (int i = 0; i < 2; i++)
                a2[i] = *(const bfrag*)(reg + (i*16 + m16)*136 + kc2*32 + q*8);
            #pragma unroll
            for (int nc = 0; nc < 4; nc++) {
                bfrag bb = *(const bfrag*)(W2B + (nc*16 + m16)*256 + ph*128 + kc2*32 + q*8);
                acc2[nc][0] = __builtin_amdgcn_mfma_f32_16x16x32_bf16(a2[0], bb, acc2[nc][0], 0, 0, 0);
                acc2[nc][1] = __builtin_amdgcn_mfma_f32_16x16x32_bf16(a2[1], bb, acc2[nc][1], 0, 0, 0);
            }
        }
        __builtin_amdgcn_wave_barrier();
    }

    float p0[2][4], p1[2][4];
    #pragma unroll
    for (int i = 0; i < 2; i++) {
        #pragma unroll
        for (int r = 0; r < 4; r++) {
            int rowl = 32*w + i*16 + q*4 + r;
            int row  = blockRow + rowl;
            bool ok  = row < N_ROWS;
            float vals[4];
            #pragma unroll
            for (int nc = 0; nc < 4; nc++) vals[nc] = acc2[nc][i][r] + pb2[nc*16 + m16];
            if (has_res && ok) {
                #pragma unroll
                for (int nc = 0; nc < 4; nc++)
                    vals[nc] += __bfloat162float(x_old[(size_t)row*64 + nc*16 + m16]);
            }
            if (write_x && ok) {
                #pragma unroll
                for (int nc = 0; nc < 4; nc++)
                    store_bf16_packed(x_new, row, nc*16, m16, vals[nc]);
            }
            float q0 = 0.f, q1 = 0.f;
            #pragma unroll
            for (int nc = 0; nc < 4; nc++) {
                int c = nc*16 + m16;
                q0 += vals[nc]*Wr[2*c];
                q1 += vals[nc]*Wr[2*c + 1];
            }
            p0[i][r] = q0; p1[i][r] = q1;
        }
    }
    #pragma unroll
    for (int s = 1; s < 16; s <<= 1) {
        #pragma unroll
        for (int i = 0; i < 2; i++)
            #pragma unroll
            for (int r = 0; r < 4; r++) {
                p0[i][r] += __shfl_xor(p0[i][r], s);
                p1[i][r] += __shfl_xor(p1[i][r], s);
            }
    }
    if (m16 == 0) {
        #pragma unroll
        for (int i = 0; i < 2; i++)
            #pragma unroll
            for (int r = 0; r < 4; r++) {
                int row = blockRow + 32*w + i*16 + q*4 + r;
                if (row < N_ROWS) {
                    atomicAdd(&racc[row*2 + 0], p0[i][r] + br[0]);
                    atomicAdd(&racc[row*2 + 1], p1[i][r] + br[1]);
                }
            }
    }
}

// ---------------------------------------------------------------------------
// K6 (v2): readout — two-stage reduction. Stage 1: per-block LDS accumulation
// (ds_add atomics; same-address serialization at LDS speed). Stage 2: 64
// global atomics per block (40/address total — no contention).
// Math identical to v1 (f32 sum re-association only).
// ---------------------------------------------------------------------------
__global__ __launch_bounds__(256) void final_kernel(
    const float* __restrict__ racc, const float* __restrict__ ori,
    const int* __restrict__ batch, float* __restrict__ out)
{
    __shared__ float sAcc[64];
    int tid = threadIdx.x;
    if (tid < 64) sAcc[tid] = 0.f;
    __syncthreads();

    int v = blockIdx.x*256 + tid;
    if (v < N_NODES) {
        float srs = 0.f, vx = 0.f, vy = 0.f, vz = 0.f;
        #pragma unroll
        for (int p = 0; p < 12; p++) {
            float r0 = racc[v*24 + 2*p], r1 = racc[v*24 + 2*p + 1];
            srs += r0;
            vx += r1*ori[3*p]; vy += r1*ori[3*p+1]; vz += r1*ori[3*p+2];
        }
        const float sc = 1.0f/24.0f;   // /2 layers, /12 orientations
        int g = batch[v];
        atomicAdd(&sAcc[g],            srs*sc);
        atomicAdd(&sAcc[16 + g*3 + 0], vx*sc);
        atomicAdd(&sAcc[16 + g*3 + 1], vy*sc);
        atomicAdd(&sAcc[16 + g*3 + 2], vz*sc);
    }
    __syncthreads();
    if (tid < 64) atomicAdd(&out[tid], sAcc[tid]);
}

extern "C" void kernel_launch(void* const* d_in, const int* in_sizes, int n_in,
                              void* d_out, int out_size, void* d_ws, size_t ws_size,
                              hipStream_t stream) {
    const float* pos    = (const float*)d_in[0];
    const float* f      = (const float*)d_in[1];
    const float* ori    = (const float*)d_in[2];
    const int*   ei     = (const int*)  d_in[3];
    const int*   batch  = (const int*)  d_in[4];
    const float* Wb1    = (const float*)d_in[5];
    const float* bb1    = (const float*)d_in[6];
    const float* Wb2    = (const float*)d_in[7];
    const float* bb2    = (const float*)d_in[8];
    const float* Wo1    = (const float*)d_in[9];
    const float* bo1    = (const float*)d_in[10];
    const float* Wo2    = (const float*)d_in[11];
    const float* bo2    = (const float*)d_in[12];
    const float* We     = (const float*)d_in[13];
    const float* Wk     = (const float*)d_in[14];
    const float* Wf     = (const float*)d_in[15];
    const float* conv_b = (const float*)d_in[16];
    const float* ln_g   = (const float*)d_in[17];
    const float* ln_b   = (const float*)d_in[18];
    const float* W1     = (const float*)d_in[19];
    const float* b1     = (const float*)d_in[20];
    const float* W2     = (const float*)d_in[21];
    const float* b2     = (const float*)d_in[22];
    const float* Wr     = (const float*)d_in[23];
    const float* br     = (const float*)d_in[24];
    float* out = (float*)d_out;

    float* ws   = (float*)d_ws;
    float* xe   = ws;                               //   640,000 f32
    short* xs1b = (short*)(xe + 640000);            // 7,680,000 bf16
    short* x1b  = xs1b + 7680000;                   // 7,680,000 bf16
    float* racc = (float*)(x1b + 7680000);          //   240,000 f32
    float* fkb  = racc + 240000;                    //    18,432
    short* w1b  = (short*)(fkb + 18432);            //    32,768 shorts
    short* w2b  = w1b + 32768;
    short* w1k  = w2b + 32768;
    short* w2k  = w1k + 2048;
    short* wkb  = w2k + 4096;
    int*   deg  = (int*)(wkb + 8192);               //    10,000 ints
    int*   rp   = deg + 10000;
    int*   wp   = rp  + 10001;
    int*   perm = wp  + 10000;
    int*   srcOf= perm+ 80000;
    int*   pad_ = srcOf + 80000;
    __hip_bfloat16* akbA = (__hip_bfloat16*)(pad_ + 3);   // 61,440,000 bf16 (~123 MB)
    __hip_bfloat16* akbB = akbA + 61440000;               // second buffer (full mode)

    size_t need_full = ((char*)(akbB + 61440000)) - ((char*)d_ws);
    int full = (ws_size >= need_full) ? 1 : 0;

    hipMemsetAsync(out,  0, 64*sizeof(float), stream);
    hipMemsetAsync(racc, 0, 240000*sizeof(float), stream);
    hipMemsetAsync(deg,  0, 10000*sizeof(int), stream);

    csr_count<<<313, 256, 0, stream>>>(ei, deg);
    csr_scan <<<1,   256, 0, stream>>>(deg, rp, wp);
    csr_fill <<<313, 256, 0, stream>>>(ei, wp, perm, srcOf);

    prep_weights<<<4,    256, 0, stream>>>(W1, W2, Wb1, Wb2, Wk,
                                           w1b, w2b, w1k, w2k, wkb);
    ori_kernel  <<<144,  64, 0, stream>>>(ori, Wo1, bo1, Wo2, bo2, Wf, fkb);
    embed_kernel<<<2500, 256, 0, stream>>>(f, We, xe);

    if (full) {
        kb_mfma <<<3750, 256, 0, stream>>>(pos, ori, w1k, bb1, w2k, bb2,
                                           wkb, akbA, wkb + 4096, akbB, /*dual=*/1, ei);
        gather0 <<<30000,256, 0, stream>>>(akbA, perm, srcOf, rp, xe, (__hip_bfloat16*)x1b);
        node_mfma<<<938, 256, 0, stream>>>(x1b, fkb, conv_b, ln_g, ln_b,
                                           w1b, b1, w2b, b2, Wr, br,
                                           (const __hip_bfloat16*)xs1b, (__hip_bfloat16*)xs1b,
                                           racc, /*res=*/0, /*write=*/1);
        gather1 <<<30000,256, 0, stream>>>(akbB, perm, srcOf, rp,
                                           (const __hip_bfloat16*)xs1b, (__hip_bfloat16*)x1b);
    } else {
        kb_mfma <<<3750, 256, 0, stream>>>(pos, ori, w1k, bb1, w2k, bb2,
                                           wkb, akbA, wkb, akbA, /*dual=*/0, ei);
        gather0 <<<30000,256, 0, stream>>>(akbA, perm, srcOf, rp, xe, (__hip_bfloat16*)x1b);
        node_mfma<<<938, 256, 0, stream>>>(x1b, fkb, conv_b, ln_g, ln_b,
                                           w1b, b1, w2b, b2, Wr, br,
                                           (const __hip_bfloat16*)xs1b, (__hip_bfloat16*)xs1b,
                                           racc, /*res=*/0, /*write=*/1);
        kb_mfma <<<3750, 256, 0, stream>>>(pos, ori, w1k, bb1, w2k, bb2,
                                           wkb + 4096, akbA, wkb + 4096, akbA, /*dual=*/0, ei);
        gather1 <<<30000,256, 0, stream>>>(akbA, perm, srcOf, rp,
                                           (const __hip_bfloat16*)xs1b, (__hip_bfloat16*)x1b);
    }

    node_mfma   <<<938,  256, 0, stream>>>(x1b, fkb + 9216, conv_b + 64, ln_g + 64, ln_b + 64,
                                           w1b + 16384, b1 + 256, w2b + 16384, b2 + 64,
                                           Wr + 128, br + 2,
                                           (const __hip_bfloat16*)xs1b, (__hip_bfloat16*)xs1b,
                                           racc, /*res=*/1, /*write=*/0);

    final_kernel<<<40,   256, 0, stream>>>(racc, ori, batch, out);
}

// Round 13
// 784.401 us; speedup vs baseline: 1.6180x; 1.0850x over previous
//
#include <hip/hip_runtime.h>
#include <hip/hip_bf16.h>
#include <math.h>

#define N_NODES 10000
#define N_EDGES 80000
#define N_ORI   12
#define N_ROWS  (N_NODES * N_ORI)

typedef __attribute__((ext_vector_type(8))) short bfrag;   // 8 bf16 = 4 VGPRs
typedef __attribute__((ext_vector_type(4))) float f32x4;

// fast gelu: x * sigmoid(1.5957845*x*(1+0.044715x^2)) — tanh-approx gelu.
// |err| vs exact-erf gelu <= ~3e-3 absolute, below bf16 ulp of the rounded
// outputs it feeds. exp(-u) form is overflow-safe at both tails.
__device__ __forceinline__ float gelu_f(float x) {
    float u = 1.5957691216057308f * x * (1.0f + 0.044715f * x * x);
    float e = __expf(-u);
    return x * __builtin_amdgcn_rcpf(1.0f + e);
}
// exact gelu for the tiny f32-precision ori path
__device__ __forceinline__ float gelu_exact(float x) {
    return 0.5f * x * (1.0f + erff(x * 0.70710678118654752440f));
}
__device__ __forceinline__ short f2bf(float x) {
    __hip_bfloat16 h = __float2bfloat16(x);
    return *reinterpret_cast<short*>(&h);
}
__device__ __forceinline__ float bflo(unsigned u) { return __uint_as_float(u << 16); }
__device__ __forceinline__ float bfhi(unsigned u) { return __uint_as_float(u & 0xffff0000u); }

// packed bf16 store: 4 cols / 8 B per quad of lanes -> full 128 B lines
__device__ __forceinline__ void store_bf16_packed(
    __hip_bfloat16* base, int row64, int colBase, int m16, float val)
{
    int my = (int)(unsigned short)f2bf(val);
    int p1 = __shfl_xor(my, 1);
    int packed01 = my | (p1 << 16);
    int p2 = __shfl_xor(packed01, 2);
    if ((m16 & 3) == 0) {
        int2 st; st.x = packed01; st.y = p2;
        *(int2*)((short*)base + (size_t)row64*64 + colBase + m16) = st;
    }
}

// ---------------------------------------------------------------------------
// CSR build (dst-sorted edge list for gathers)
// ---------------------------------------------------------------------------
__global__ __launch_bounds__(256) void csr_count(
    const int* __restrict__ ei, int* __restrict__ deg)
{
    int e = blockIdx.x*256 + threadIdx.x;
    if (e < N_EDGES) atomicAdd(&deg[ei[N_EDGES + e]], 1);
}

__global__ __launch_bounds__(256) void csr_scan(
    const int* __restrict__ deg, int* __restrict__ rp, int* __restrict__ wp)
{
    __shared__ int part[256];
    __shared__ int sbase[257];
    int t = threadIdx.x;
    int cs = t*40;
    int sum = 0;
    for (int i = 0; i < 40; i++) { int idx = cs+i; if (idx < N_NODES) sum += deg[idx]; }
    part[t] = sum;
    __syncthreads();
    if (t == 0) {
        int run = 0;
        for (int i = 0; i < 256; i++) { sbase[i] = run; run += part[i]; }
        sbase[256] = run;
    }
    __syncthreads();
    int run = sbase[t];
    for (int i = 0; i < 40; i++) {
        int idx = cs+i;
        if (idx < N_NODES) { rp[idx] = run; wp[idx] = run; run += deg[idx]; }
    }
    if (t == 0) rp[N_NODES] = sbase[256];
}

__global__ __launch_bounds__(256) void csr_fill(
    const int* __restrict__ ei, int* __restrict__ wp,
    int* __restrict__ perm, int* __restrict__ srcOf)
{
    int e = blockIdx.x*256 + threadIdx.x;
    if (e >= N_EDGES) return;
    int dn = ei[N_EDGES + e];
    int j = atomicAdd(&wp[dn], 1);
    perm[j] = e;
    srcOf[j] = ei[e];
}

// ---------------------------------------------------------------------------
// K0: weight prep (unchanged)
// ---------------------------------------------------------------------------
__global__ __launch_bounds__(256) void prep_weights(
    const float* __restrict__ W1, const float* __restrict__ W2,
    const float* __restrict__ Wb1, const float* __restrict__ Wb2,
    const float* __restrict__ Wk,
    short* __restrict__ W1B, short* __restrict__ W2B,
    short* __restrict__ W1K, short* __restrict__ W2K,
    short* __restrict__ WkB)
{
    if (blockIdx.x < 2) {
        int l = blockIdx.x;
        const float* w1 = W1 + l*16384; short* w1b = W1B + l*16384;
        const float* w2 = W2 + l*16384; short* w2b = W2B + l*16384;
        for (int i = threadIdx.x; i < 16384; i += 256) {
            int k = i >> 8, t = i & 255;
            w1b[t*64 + k] = f2bf(w1[i]);
            int t2 = i >> 6, c = i & 63;
            w2b[c*256 + t2] = f2bf(w2[i]);
        }
    } else if (blockIdx.x == 2) {
        for (int i = threadIdx.x; i < 2048; i += 256) {
            int t = i >> 5, k = i & 31;
            W1K[i] = (k < 30) ? f2bf(Wb1[k*64 + t]) : (short)0;
        }
        for (int i = threadIdx.x; i < 4096; i += 256) {
            int c = i >> 6, t = i & 63;
            W2K[i] = f2bf(Wb2[t*64 + c]);
        }
    } else {
        for (int i = threadIdx.x; i < 8192; i += 256) {
            int l = i >> 12, rem = i & 4095, k = rem >> 6, c = rem & 63;
            WkB[l*4096 + c*64 + k] = f2bf(Wk[l*4096 + k*64 + c]);
        }
    }
}

// ---------------------------------------------------------------------------
// K1: kb_ori MLP + fk (exact gelu — f32 path, tiny kernel)
// ---------------------------------------------------------------------------
__global__ __launch_bounds__(64) void ori_kernel(
    const float* __restrict__ ori, const float* __restrict__ Wo1,
    const float* __restrict__ bo1, const float* __restrict__ Wo2,
    const float* __restrict__ bo2, const float* __restrict__ Wf,
    float* __restrict__ fkb)
{
    __shared__ float sh[64];
    __shared__ float skb[64];
    int i = blockIdx.x / 12, j = blockIdx.x % 12;
    int lane = threadIdx.x;
    float s = ori[3*i]*ori[3*j] + ori[3*i+1]*ori[3*j+1] + ori[3*i+2]*ori[3*j+2];
    float p1 = s, p2 = s*s, p3 = p2*s, p4 = p3*s;
    float acc = bo1[lane] + p1*Wo1[lane] + p2*Wo1[64+lane] + p3*Wo1[128+lane] + p4*Wo1[192+lane];
    sh[lane] = gelu_exact(acc);
    __syncthreads();
    float acc2 = bo2[lane];
    #pragma unroll
    for (int k = 0; k < 64; k++) acc2 += sh[k] * Wo2[k*64 + lane];
    skb[lane] = gelu_exact(acc2);
    __syncthreads();
    for (int l = 0; l < 2; l++) {
        float a = 0.f;
        #pragma unroll
        for (int k = 0; k < 64; k++) a += skb[k] * Wf[l*4096 + k*64 + lane];
        fkb[l*9216 + i*768 + j*64 + lane] = a;
    }
}

// ---------------------------------------------------------------------------
// K2: x = f @ We (unchanged)
// ---------------------------------------------------------------------------
__global__ __launch_bounds__(256) void embed_kernel(
    const float* __restrict__ f, const float* __restrict__ We, float* __restrict__ xe)
{
    int v = blockIdx.x*4 + (threadIdx.x >> 6);
    int lane = threadIdx.x & 63;
    if (v >= N_NODES) return;
    float acc = 0.f;
    #pragma unroll
    for (int k = 0; k < 16; k++) acc += f[v*16 + k] * We[k*64 + lane];
    xe[v*64 + lane] = acc;
}

// ---------------------------------------------------------------------------
// K3 (v8): kb MLP via MFMA -> akb = kb@Wk, zero atomics, fast gelu.
// ---------------------------------------------------------------------------
#define KB_WREG 4736
__global__ __launch_bounds__(256, 4) void kb_mfma(
    const float* __restrict__ pos, const float* __restrict__ ori,
    const short* __restrict__ W1K, const float* __restrict__ bb1,
    const short* __restrict__ W2K, const float* __restrict__ bb2,
    const short* __restrict__ WkA, __hip_bfloat16* __restrict__ akbA,
    const short* __restrict__ WkB2, __hip_bfloat16* __restrict__ akbB,
    int dual, const int* __restrict__ ei)
{
    __shared__ short sU[4*KB_WREG];

    int tid = threadIdx.x;
    int w = tid >> 6, l = tid & 63;
    short* reg  = sU + w*KB_WREG;
    float* envp = (float*)(reg + 64*72);
    int blockRow = blockIdx.x * 256;

    // ---- Phase A: features ----
    {
        int row = blockRow + tid;
        int e = row / 12, o = row - e*12;
        int sn = ei[e], dn = ei[N_EDGES + e];
        float rx = pos[sn*3+0] - pos[dn*3+0];
        float ry = pos[sn*3+1] - pos[dn*3+1];
        float rz = pos[sn*3+2] - pos[dn*3+2];
        float d  = sqrtf(rx*rx + ry*ry + rz*rz);
        float u2 = d*d, u4 = u2*u2, u6 = u4*u2;
        float env = (d < 1.0f) ? (1.0f - 28.0f*u6 + 48.0f*u6*d - 21.0f*u6*u2) : 0.0f;
        envp[l] = env;

        float ox = ori[3*o], oy = ori[3*o+1], oz = ori[3*o+2];
        float a  = rx*ox + ry*oy + rz*oz;
        float qx = rx - a*ox, qy = ry - a*oy, qz = rz - a*oz;
        float b  = sqrtf(qx*qx + qy*qy + qz*qz);

        float fv[32];
        fv[0] = a; fv[1] = b;
        fv[2] = a*a; fv[3] = a*b; fv[4] = b*a; fv[5] = b*b;
        #pragma unroll
        for (int i = 0; i < 4; i++) { fv[6+2*i] = fv[2+i]*a; fv[7+2*i] = fv[2+i]*b; }
        #pragma unroll
        for (int i = 0; i < 8; i++) { fv[14+2*i] = fv[6+i]*a; fv[15+2*i] = fv[6+i]*b; }
        fv[30] = 0.f; fv[31] = 0.f;

        short* dst = reg + l*40;
        #pragma unroll
        for (int blk = 0; blk < 4; blk++) {
            union { short s[8]; int4 v4; } u;
            #pragma unroll
            for (int jj = 0; jj < 8; jj++) u.s[jj] = f2bf(fv[blk*8 + jj]);
            *(int4*)(dst + blk*8) = u.v4;
        }
    }
    __builtin_amdgcn_wave_barrier();

    int m16 = l & 15, q = l >> 4;

    bfrag a1[4];
    #pragma unroll
    for (int mt = 0; mt < 4; mt++)
        a1[mt] = *(const bfrag*)(reg + (mt*16 + m16)*40 + q*8);
    __builtin_amdgcn_wave_barrier();

    // ---- FFN1: K=32 ----
    #pragma unroll
    for (int nt = 0; nt < 4; nt++) {
        bfrag bb = *(const bfrag*)(W1K + (nt*16 + m16)*32 + q*8);
        float bias = bb1[nt*16 + m16];
        #pragma unroll
        for (int mt = 0; mt < 4; mt++) {
            f32x4 acc = (f32x4){0.f,0.f,0.f,0.f};
            acc = __builtin_amdgcn_mfma_f32_16x16x32_bf16(a1[mt], bb, acc, 0, 0, 0);
            #pragma unroll
            for (int r = 0; r < 4; r++) {
                int rl = mt*16 + q*4 + r;
                reg[rl*72 + nt*16 + m16] = f2bf(gelu_f(acc[r] + bias));
            }
        }
    }
    __builtin_amdgcn_wave_barrier();

    // ---- FFN2: K=64 -> kb back into sH ----
    bfrag a2[4][2];
    #pragma unroll
    for (int mt = 0; mt < 4; mt++)
        #pragma unroll
        for (int kc = 0; kc < 2; kc++)
            a2[mt][kc] = *(const bfrag*)(reg + (mt*16 + m16)*72 + kc*32 + q*8);
    __builtin_amdgcn_wave_barrier();

    #pragma unroll
    for (int nt = 0; nt < 4; nt++) {
        f32x4 acc[4];
        #pragma unroll
        for (int mt = 0; mt < 4; mt++) acc[mt] = (f32x4){0.f,0.f,0.f,0.f};
        #pragma unroll
        for (int kc = 0; kc < 2; kc++) {
            bfrag bb = *(const bfrag*)(W2K + (nt*16 + m16)*64 + kc*32 + q*8);
            #pragma unroll
            for (int mt = 0; mt < 4; mt++)
                acc[mt] = __builtin_amdgcn_mfma_f32_16x16x32_bf16(a2[mt][kc], bb, acc[mt], 0, 0, 0);
        }
        float bias = bb2[nt*16 + m16];
        #pragma unroll
        for (int mt = 0; mt < 4; mt++) {
            #pragma unroll
            for (int r = 0; r < 4; r++) {
                int rl = mt*16 + q*4 + r;
                reg[rl*72 + nt*16 + m16] = f2bf(gelu_f(acc[mt][r] + bias) * envp[rl]);
            }
        }
    }
    __builtin_amdgcn_wave_barrier();

    // ---- akb GEMMs + packed coalesced stores ----
    bfrag a3[4][2];
    #pragma unroll
    for (int mt = 0; mt < 4; mt++)
        #pragma unroll
        for (int kc = 0; kc < 2; kc++)
            a3[mt][kc] = *(const bfrag*)(reg + (mt*16 + m16)*72 + kc*32 + q*8);

    #pragma unroll
    for (int nt = 0; nt < 4; nt++) {
        f32x4 acc[4];
        #pragma unroll
        for (int mt = 0; mt < 4; mt++) acc[mt] = (f32x4){0.f,0.f,0.f,0.f};
        #pragma unroll
        for (int kc = 0; kc < 2; kc++) {
            bfrag bb = *(const bfrag*)(WkA + (nt*16 + m16)*64 + kc*32 + q*8);
            #pragma unroll
            for (int mt = 0; mt < 4; mt++)
                acc[mt] = __builtin_amdgcn_mfma_f32_16x16x32_bf16(a3[mt][kc], bb, acc[mt], 0, 0, 0);
        }
        #pragma unroll
        for (int mt = 0; mt < 4; mt++)
            #pragma unroll
            for (int r = 0; r < 4; r++) {
                int R = blockRow + w*64 + mt*16 + q*4 + r;
                store_bf16_packed(akbA, R, nt*16, m16, acc[mt][r]);
            }
    }
    if (dual) {
        #pragma unroll
        for (int nt = 0; nt < 4; nt++) {
            f32x4 acc[4];
            #pragma unroll
            for (int mt = 0; mt < 4; mt++) acc[mt] = (f32x4){0.f,0.f,0.f,0.f};
            #pragma unroll
            for (int kc = 0; kc < 2; kc++) {
                bfrag bb = *(const bfrag*)(WkB2 + (nt*16 + m16)*64 + kc*32 + q*8);
                #pragma unroll
                for (int mt = 0; mt < 4; mt++)
                    acc[mt] = __builtin_amdgcn_mfma_f32_16x16x32_bf16(a3[mt][kc], bb, acc[mt], 0, 0, 0);
            }
            #pragma unroll
            for (int mt = 0; mt < 4; mt++)
                #pragma unroll
                for (int r = 0; r < 4; r++) {
                    int R = blockRow + w*64 + mt*16 + q*4 + r;
                    store_bf16_packed(akbB, R, nt*16, m16, acc[mt][r]);
                }
        }
    }
}

// ---------------------------------------------------------------------------
// K4a: layer-0 CSR gather (unchanged)
// ---------------------------------------------------------------------------
__global__ __launch_bounds__(256) void gather0(
    const __hip_bfloat16* __restrict__ akb, const int* __restrict__ perm,
    const int* __restrict__ srcOf, const int* __restrict__ rp,
    const float* __restrict__ xe, __hip_bfloat16* __restrict__ x1)
{
    int w = threadIdx.x >> 6, lane = threadIdx.x & 63;
    int g = blockIdx.x*4 + w;
    int v = g / 12, o = g - v*12;
    int jb = rp[v], je = rp[v+1];
    float acc = 0.f;
    for (int j = jb; j < je; j++) {
        int e = perm[j];
        float a  = __bfloat162float(akb[(size_t)e*768 + o*64 + lane]);
        float xs = xe[(size_t)srcOf[j]*64 + lane];
        acc += a * xs;
    }
    x1[(size_t)v*768 + o*64 + lane] = __float2bfloat16(acc);
}

// ---------------------------------------------------------------------------
// K4b: layer-1 CSR gather (unchanged)
// ---------------------------------------------------------------------------
__global__ __launch_bounds__(256) void gather1(
    const __hip_bfloat16* __restrict__ akb, const int* __restrict__ perm,
    const int* __restrict__ srcOf, const int* __restrict__ rp,
    const __hip_bfloat16* __restrict__ x_in, __hip_bfloat16* __restrict__ x1)
{
    int w = threadIdx.x >> 6, lane = threadIdx.x & 63;
    int g = blockIdx.x*4 + w;
    int v = g / 12, o = g - v*12;
    int jb = rp[v], je = rp[v+1];
    float acc = 0.f;
    for (int j = jb; j < je; j++) {
        int e = perm[j];
        float a  = __bfloat162float(akb[(size_t)e*768 + o*64 + lane]);
        float xs = __bfloat162float(x_in[(size_t)srcOf[j]*768 + o*64 + lane]);
        acc += a * xs;
    }
    x1[(size_t)v*768 + o*64 + lane] = __float2bfloat16(acc);
}

// ---------------------------------------------------------------------------
// K5 (v4): node kernel — fast gelu; otherwise unchanged.
// ---------------------------------------------------------------------------
#define ND_WREG 4352
__global__ __launch_bounds__(256, 4) void node_mfma(
    const short* __restrict__ x1, const float* __restrict__ fk,
    const float* __restrict__ conv_b, const float* __restrict__ ln_g,
    const float* __restrict__ ln_b,
    const short* __restrict__ W1B, const float* __restrict__ b1,
    const short* __restrict__ W2B, const float* __restrict__ pb2,
    const float* __restrict__ Wr, const float* __restrict__ br,
    const __hip_bfloat16* __restrict__ x_old, __hip_bfloat16* __restrict__ x_new,
    float* __restrict__ racc, int has_res, int write_x)
{
    __shared__ short sU[4*ND_WREG];

    int tid = threadIdx.x;
    int w   = tid >> 6;
    int blockRow = blockIdx.x * 128;
    short* reg = sU + w*ND_WREG;

    {
        int rl = tid >> 1, hf = tid & 1;
        int lr = rl - 32*w;
        int row = blockRow + rl;
        int rc = row < N_ROWS ? row : N_ROWS - 1;
        int v = rc / 12, pp = rc % 12;
        float h[32];
        #pragma unroll
        for (int k = 0; k < 32; k++) h[k] = 0.f;
        const short* xv = x1 + (size_t)v*768 + hf*32;
        const float* fp = fk + (size_t)pp*768 + hf*32;
        for (int o = 0; o < 12; o++) {
            const int4*  xa = (const int4*)(xv + o*64);
            const float4* fa = (const float4*)(fp + o*64);
            #pragma unroll
            for (int k4 = 0; k4 < 4; k4++) {
                int4 xi = xa[k4];
                float4 f0 = fa[2*k4], f1 = fa[2*k4+1];
                h[8*k4+0] += bflo((unsigned)xi.x)*f0.x; h[8*k4+1] += bfhi((unsigned)xi.x)*f0.y;
                h[8*k4+2] += bflo((unsigned)xi.y)*f0.z; h[8*k4+3] += bfhi((unsigned)xi.y)*f0.w;
                h[8*k4+4] += bflo((unsigned)xi.z)*f1.x; h[8*k4+5] += bfhi((unsigned)xi.z)*f1.y;
                h[8*k4+6] += bflo((unsigned)xi.w)*f1.z; h[8*k4+7] += bfhi((unsigned)xi.w)*f1.w;
            }
        }
        const float inv12 = 1.0f/12.0f;
        float sum = 0.f;
        #pragma unroll
        for (int k = 0; k < 32; k++) { h[k] = h[k]*inv12 + conv_b[hf*32 + k]; sum += h[k]; }
        sum += __shfl_xor(sum, 1);
        float mu = sum * (1.0f/64.0f);
        float var = 0.f;
        #pragma unroll
        for (int k = 0; k < 32; k++) { float xc = h[k] - mu; var += xc*xc; }
        var += __shfl_xor(var, 1);
        float rstd = rsqrtf(var*(1.0f/64.0f) + 1e-5f);
        short* dst = reg + lr*72 + hf*32;
        #pragma unroll
        for (int blk = 0; blk < 4; blk++) {
            union { short s[8]; int4 v4; } u;
            #pragma unroll
            for (int jj = 0; jj < 8; jj++) {
                int k = blk*8 + jj, c = hf*32 + k;
                u.s[jj] = f2bf((h[k] - mu)*rstd*ln_g[c] + ln_b[c]);
            }
            *(int4*)(dst + blk*8) = u.v4;
        }
    }
    __builtin_amdgcn_wave_barrier();

    int l   = tid & 63;
    int m16 = l & 15, q = l >> 4;

    bfrag a1[2][2];
    #pragma unroll
    for (int i = 0; i < 2; i++)
        #pragma unroll
        for (int kc = 0; kc < 2; kc++)
            a1[i][kc] = *(const bfrag*)(reg + (i*16 + m16)*72 + kc*32 + q*8);
    __builtin_amdgcn_wave_barrier();

    f32x4 acc2[4][2];
    #pragma unroll
    for (int n = 0; n < 4; n++)
        #pragma unroll
        for (int i = 0; i < 2; i++)
            acc2[n][i] = (f32x4){0.f, 0.f, 0.f, 0.f};

    for (int ph = 0; ph < 2; ph++) {
        for (int ntl = 0; ntl < 8; ntl++) {
            int nt = ph*8 + ntl;
            f32x4 c0 = (f32x4){0.f,0.f,0.f,0.f};
            f32x4 c1 = (f32x4){0.f,0.f,0.f,0.f};
            #pragma unroll
            for (int kc = 0; kc < 2; kc++) {
                bfrag bb = *(const bfrag*)(W1B + (nt*16 + m16)*64 + kc*32 + q*8);
                c0 = __builtin_amdgcn_mfma_f32_16x16x32_bf16(a1[0][kc], bb, c0, 0, 0, 0);
                c1 = __builtin_amdgcn_mfma_f32_16x16x32_bf16(a1[1][kc], bb, c1, 0, 0, 0);
            }
            float bias = b1[nt*16 + m16];
            #pragma unroll
            for (int r = 0; r < 4; r++) {
                int r0 = q*4 + r;
                int r1 = 16 + q*4 + r;
                reg[r0*136 + ntl*16 + m16] = f2bf(gelu_f(c0[r] + bias));
                reg[r1*136 + ntl*16 + m16] = f2bf(gelu_f(c1[r] + bias));
            }
        }
        __builtin_amdgcn_wave_barrier();
        for (int kc2 = 0; kc2 < 4; kc2++) {
            bfrag a2[2];
            #pragma unroll
            for (int i = 0; i < 2; i++)
                a2[i] = *(const bfrag*)(reg + (i*16 + m16)*136 + kc2*32 + q*8);
            #pragma unroll
            for (int nc = 0; nc < 4; nc++) {
                bfrag bb = *(const bfrag*)(W2B + (nc*16 + m16)*256 + ph*128 + kc2*32 + q*8);
                acc2[nc][0] = __builtin_amdgcn_mfma_f32_16x16x32_bf16(a2[0], bb, acc2[nc][0], 0, 0, 0);
                acc2[nc][1] = __builtin_amdgcn_mfma_f32_16x16x32_bf16(a2[1], bb, acc2[nc][1], 0, 0, 0);
            }
        }
        __builtin_amdgcn_wave_barrier();
    }

    float p0[2][4], p1[2][4];
    #pragma unroll
    for (int i = 0; i < 2; i++) {
        #pragma unroll
        for (int r = 0; r < 4; r++) {
            int rowl = 32*w + i*16 + q*4 + r;
            int row  = blockRow + rowl;
            bool ok  = row < N_ROWS;
            float vals[4];
            #pragma unroll
            for (int nc = 0; nc < 4; nc++) vals[nc] = acc2[nc][i][r] + pb2[nc*16 + m16];
            if (has_res && ok) {
                #pragma unroll
                for (int nc = 0; nc < 4; nc++)
                    vals[nc] += __bfloat162float(x_old[(size_t)row*64 + nc*16 + m16]);
            }
            if (write_x && ok) {
                #pragma unroll
                for (int nc = 0; nc < 4; nc++)
                    store_bf16_packed(x_new, row, nc*16, m16, vals[nc]);
            }
            float q0 = 0.f, q1 = 0.f;
            #pragma unroll
            for (int nc = 0; nc < 4; nc++) {
                int c = nc*16 + m16;
                q0 += vals[nc]*Wr[2*c];
                q1 += vals[nc]*Wr[2*c + 1];
            }
            p0[i][r] = q0; p1[i][r] = q1;
        }
    }
    #pragma unroll
    for (int s = 1; s < 16; s <<= 1) {
        #pragma unroll
        for (int i = 0; i < 2; i++)
            #pragma unroll
            for (int r = 0; r < 4; r++) {
                p0[i][r] += __shfl_xor(p0[i][r], s);
                p1[i][r] += __shfl_xor(p1[i][r], s);
            }
    }
    if (m16 == 0) {
        #pragma unroll
        for (int i = 0; i < 2; i++)
            #pragma unroll
            for (int r = 0; r < 4; r++) {
                int row = blockRow + 32*w + i*16 + q*4 + r;
                if (row < N_ROWS) {
                    atomicAdd(&racc[row*2 + 0], p0[i][r] + br[0]);
                    atomicAdd(&racc[row*2 + 1], p1[i][r] + br[1]);
                }
            }
    }
}

// ---------------------------------------------------------------------------
// K6 (v2): readout — two-stage reduction (unchanged from r12)
// ---------------------------------------------------------------------------
__global__ __launch_bounds__(256) void final_kernel(
    const float* __restrict__ racc, const float* __restrict__ ori,
    const int* __restrict__ batch, float* __restrict__ out)
{
    __shared__ float sAcc[64];
    int tid = threadIdx.x;
    if (tid < 64) sAcc[tid] = 0.f;
    __syncthreads();

    int v = blockIdx.x*256 + tid;
    if (v < N_NODES) {
        float srs = 0.f, vx = 0.f, vy = 0.f, vz = 0.f;
        #pragma unroll
        for (int p = 0; p < 12; p++) {
            float r0 = racc[v*24 + 2*p], r1 = racc[v*24 + 2*p + 1];
            srs += r0;
            vx += r1*ori[3*p]; vy += r1*ori[3*p+1]; vz += r1*ori[3*p+2];
        }
        const float sc = 1.0f/24.0f;
        int g = batch[v];
        atomicAdd(&sAcc[g],            srs*sc);
        atomicAdd(&sAcc[16 + g*3 + 0], vx*sc);
        atomicAdd(&sAcc[16 + g*3 + 1], vy*sc);
        atomicAdd(&sAcc[16 + g*3 + 2], vz*sc);
    }
    __syncthreads();
    if (tid < 64) atomicAdd(&out[tid], sAcc[tid]);
}

extern "C" void kernel_launch(void* const* d_in, const int* in_sizes, int n_in,
                              void* d_out, int out_size, void* d_ws, size_t ws_size,
                              hipStream_t stream) {
    const float* pos    = (const float*)d_in[0];
    const float* f      = (const float*)d_in[1];
    const float* ori    = (const float*)d_in[2];
    const int*   ei     = (const int*)  d_in[3];
    const int*   batch  = (const int*)  d_in[4];
    const float* Wb1    = (const float*)d_in[5];
    const float* bb1    = (const float*)d_in[6];
    const float* Wb2    = (const float*)d_in[7];
    const float* bb2    = (const float*)d_in[8];
    const float* Wo1    = (const float*)d_in[9];
    const float* bo1    = (const float*)d_in[10];
    const float* Wo2    = (const float*)d_in[11];
    const float* bo2    = (const float*)d_in[12];
    const float* We     = (const float*)d_in[13];
    const float* Wk     = (const float*)d_in[14];
    const float* Wf     = (const float*)d_in[15];
    const float* conv_b = (const float*)d_in[16];
    const float* ln_g   = (const float*)d_in[17];
    const float* ln_b   = (const float*)d_in[18];
    const float* W1     = (const float*)d_in[19];
    const float* b1     = (const float*)d_in[20];
    const float* W2     = (const float*)d_in[21];
    const float* b2     = (const float*)d_in[22];
    const float* Wr     = (const float*)d_in[23];
    const float* br     = (const float*)d_in[24];
    float* out = (float*)d_out;

    float* ws   = (float*)d_ws;
    float* xe   = ws;                               //   640,000 f32
    short* xs1b = (short*)(xe + 640000);            // 7,680,000 bf16
    short* x1b  = xs1b + 7680000;                   // 7,680,000 bf16
    float* racc = (float*)(x1b + 7680000);          //   240,000 f32
    float* fkb  = racc + 240000;                    //    18,432
    short* w1b  = (short*)(fkb + 18432);            //    32,768 shorts
    short* w2b  = w1b + 32768;
    short* w1k  = w2b + 32768;
    short* w2k  = w1k + 2048;
    short* wkb  = w2k + 4096;
    int*   deg  = (int*)(wkb + 8192);               //    10,000 ints
    int*   rp   = deg + 10000;
    int*   wp   = rp  + 10001;
    int*   perm = wp  + 10000;
    int*   srcOf= perm+ 80000;
    int*   pad_ = srcOf + 80000;
    __hip_bfloat16* akbA = (__hip_bfloat16*)(pad_ + 3);   // 61,440,000 bf16 (~123 MB)
    __hip_bfloat16* akbB = akbA + 61440000;               // second buffer (full mode)

    size_t need_full = ((char*)(akbB + 61440000)) - ((char*)d_ws);
    int full = (ws_size >= need_full) ? 1 : 0;

    hipMemsetAsync(out,  0, 64*sizeof(float), stream);
    hipMemsetAsync(racc, 0, 240000*sizeof(float), stream);
    hipMemsetAsync(deg,  0, 10000*sizeof(int), stream);

    csr_count<<<313, 256, 0, stream>>>(ei, deg);
    csr_scan <<<1,   256, 0, stream>>>(deg, rp, wp);
    csr_fill <<<313, 256, 0, stream>>>(ei, wp, perm, srcOf);

    prep_weights<<<4,    256, 0, stream>>>(W1, W2, Wb1, Wb2, Wk,
                                           w1b, w2b, w1k, w2k, wkb);
    ori_kernel  <<<144,  64, 0, stream>>>(ori, Wo1, bo1, Wo2, bo2, Wf, fkb);
    embed_kernel<<<2500, 256, 0, stream>>>(f, We, xe);

    if (full) {
        kb_mfma <<<3750, 256, 0, stream>>>(pos, ori, w1k, bb1, w2k, bb2,
                                           wkb, akbA, wkb + 4096, akbB, /*dual=*/1, ei);
        gather0 <<<30000,256, 0, stream>>>(akbA, perm, srcOf, rp, xe, (__hip_bfloat16*)x1b);
        node_mfma<<<938, 256, 0, stream>>>(x1b, fkb, conv_b, ln_g, ln_b,
                                           w1b, b1, w2b, b2, Wr, br,
                                           (const __hip_bfloat16*)xs1b, (__hip_bfloat16*)xs1b,
                                           racc, /*res=*/0, /*write=*/1);
        gather1 <<<30000,256, 0, stream>>>(akbB, perm, srcOf, rp,
                                           (const __hip_bfloat16*)xs1b, (__hip_bfloat16*)x1b);
    } else {
        kb_mfma <<<3750, 256, 0, stream>>>(pos, ori, w1k, bb1, w2k, bb2,
                                           wkb, akbA, wkb, akbA, /*dual=*/0, ei);
        gather0 <<<30000,256, 0, stream>>>(akbA, perm, srcOf, rp, xe, (__hip_bfloat16*)x1b);
        node_mfma<<<938, 256, 0, stream>>>(x1b, fkb, conv_b, ln_g, ln_b,
                                           w1b, b1, w2b, b2, Wr, br,
                                           (const __hip_bfloat16*)xs1b, (__hip_bfloat16*)xs1b,
                                           racc, /*res=*/0, /*write=*/1);
        kb_mfma <<<3750, 256, 0, stream>>>(pos, ori, w1k, bb1, w2k, bb2,
                                           wkb + 4096, akbA, wkb + 4096, akbA, /*dual=*/0, ei);
        gather1 <<<30000,256, 0, stream>>>(akbA, perm, srcOf, rp,
                                           (const __hip_bfloat16*)xs1b, (__hip_bfloat16*)x1b);
    }

    node_mfma   <<<938,  256, 0, stream>>>(x1b, fkb + 9216, conv_b + 64, ln_g + 64, ln_b + 64,
                                           w1b + 16384, b1 + 256, w2b + 16384, b2 + 64,
                                           Wr + 128, br + 2,
                                           (const __hip_bfloat16*)xs1b, (__hip_bfloat16*)xs1b,
                                           racc, /*res=*/1, /*write=*/0);

    final_kernel<<<40,   256, 0, stream>>>(racc, ori, batch, out);
}

// Round 14
// 718.691 us; speedup vs baseline: 1.7660x; 1.0914x over previous
//
#include <hip/hip_runtime.h>
#include <hip/hip_bf16.h>
#include <math.h>

#define N_NODES 10000
#define N_EDGES 80000
#define N_ORI   12
#define N_ROWS  (N_NODES * N_ORI)

typedef __attribute__((ext_vector_type(8))) short bfrag;   // 8 bf16 = 4 VGPRs
typedef __attribute__((ext_vector_type(4))) float f32x4;

// fast gelu (tanh-approx, overflow-safe); |err| < ~3e-3 < bf16 ulp downstream
__device__ __forceinline__ float gelu_f(float x) {
    float u = 1.5957691216057308f * x * (1.0f + 0.044715f * x * x);
    float e = __expf(-u);
    return x * __builtin_amdgcn_rcpf(1.0f + e);
}
// exact gelu for the tiny f32-precision ori path
__device__ __forceinline__ float gelu_exact(float x) {
    return 0.5f * x * (1.0f + erff(x * 0.70710678118654752440f));
}
__device__ __forceinline__ short f2bf(float x) {
    __hip_bfloat16 h = __float2bfloat16(x);
    return *reinterpret_cast<short*>(&h);
}
__device__ __forceinline__ float bflo(unsigned u) { return __uint_as_float(u << 16); }
__device__ __forceinline__ float bfhi(unsigned u) { return __uint_as_float(u & 0xffff0000u); }

// packed bf16 store: 4 cols / 8 B per quad of lanes -> full 128 B lines
__device__ __forceinline__ void store_bf16_packed(
    __hip_bfloat16* base, int row64, int colBase, int m16, float val)
{
    int my = (int)(unsigned short)f2bf(val);
    int p1 = __shfl_xor(my, 1);
    int packed01 = my | (p1 << 16);
    int p2 = __shfl_xor(packed01, 2);
    if ((m16 & 3) == 0) {
        int2 st; st.x = packed01; st.y = p2;
        *(int2*)((short*)base + (size_t)row64*64 + colBase + m16) = st;
    }
}

// ---------------------------------------------------------------------------
// CSR build (dst-sorted edge list for gathers)
// ---------------------------------------------------------------------------
__global__ __launch_bounds__(256) void csr_count(
    const int* __restrict__ ei, int* __restrict__ deg)
{
    int e = blockIdx.x*256 + threadIdx.x;
    if (e < N_EDGES) atomicAdd(&deg[ei[N_EDGES + e]], 1);
}

__global__ __launch_bounds__(256) void csr_scan(
    const int* __restrict__ deg, int* __restrict__ rp, int* __restrict__ wp)
{
    __shared__ int part[256];
    __shared__ int sbase[257];
    int t = threadIdx.x;
    int cs = t*40;
    int sum = 0;
    for (int i = 0; i < 40; i++) { int idx = cs+i; if (idx < N_NODES) sum += deg[idx]; }
    part[t] = sum;
    __syncthreads();
    if (t == 0) {
        int run = 0;
        for (int i = 0; i < 256; i++) { sbase[i] = run; run += part[i]; }
        sbase[256] = run;
    }
    __syncthreads();
    int run = sbase[t];
    for (int i = 0; i < 40; i++) {
        int idx = cs+i;
        if (idx < N_NODES) { rp[idx] = run; wp[idx] = run; run += deg[idx]; }
    }
    if (t == 0) rp[N_NODES] = sbase[256];
}

__global__ __launch_bounds__(256) void csr_fill(
    const int* __restrict__ ei, int* __restrict__ wp,
    int* __restrict__ perm, int* __restrict__ srcOf)
{
    int e = blockIdx.x*256 + threadIdx.x;
    if (e >= N_EDGES) return;
    int dn = ei[N_EDGES + e];
    int j = atomicAdd(&wp[dn], 1);
    perm[j] = e;
    srcOf[j] = ei[e];
}

// ---------------------------------------------------------------------------
// K0: weight prep (unchanged)
// ---------------------------------------------------------------------------
__global__ __launch_bounds__(256) void prep_weights(
    const float* __restrict__ W1, const float* __restrict__ W2,
    const float* __restrict__ Wb1, const float* __restrict__ Wb2,
    const float* __restrict__ Wk,
    short* __restrict__ W1B, short* __restrict__ W2B,
    short* __restrict__ W1K, short* __restrict__ W2K,
    short* __restrict__ WkB)
{
    if (blockIdx.x < 2) {
        int l = blockIdx.x;
        const float* w1 = W1 + l*16384; short* w1b = W1B + l*16384;
        const float* w2 = W2 + l*16384; short* w2b = W2B + l*16384;
        for (int i = threadIdx.x; i < 16384; i += 256) {
            int k = i >> 8, t = i & 255;
            w1b[t*64 + k] = f2bf(w1[i]);
            int t2 = i >> 6, c = i & 63;
            w2b[c*256 + t2] = f2bf(w2[i]);
        }
    } else if (blockIdx.x == 2) {
        for (int i = threadIdx.x; i < 2048; i += 256) {
            int t = i >> 5, k = i & 31;
            W1K[i] = (k < 30) ? f2bf(Wb1[k*64 + t]) : (short)0;
        }
        for (int i = threadIdx.x; i < 4096; i += 256) {
            int c = i >> 6, t = i & 63;
            W2K[i] = f2bf(Wb2[t*64 + c]);
        }
    } else {
        for (int i = threadIdx.x; i < 8192; i += 256) {
            int l = i >> 12, rem = i & 4095, k = rem >> 6, c = rem & 63;
            WkB[l*4096 + c*64 + k] = f2bf(Wk[l*4096 + k*64 + c]);
        }
    }
}

// ---------------------------------------------------------------------------
// K1: kb_ori MLP + fk (exact gelu — f32 path, tiny kernel)
// ---------------------------------------------------------------------------
__global__ __launch_bounds__(64) void ori_kernel(
    const float* __restrict__ ori, const float* __restrict__ Wo1,
    const float* __restrict__ bo1, const float* __restrict__ Wo2,
    const float* __restrict__ bo2, const float* __restrict__ Wf,
    float* __restrict__ fkb)
{
    __shared__ float sh[64];
    __shared__ float skb[64];
    int i = blockIdx.x / 12, j = blockIdx.x % 12;
    int lane = threadIdx.x;
    float s = ori[3*i]*ori[3*j] + ori[3*i+1]*ori[3*j+1] + ori[3*i+2]*ori[3*j+2];
    float p1 = s, p2 = s*s, p3 = p2*s, p4 = p3*s;
    float acc = bo1[lane] + p1*Wo1[lane] + p2*Wo1[64+lane] + p3*Wo1[128+lane] + p4*Wo1[192+lane];
    sh[lane] = gelu_exact(acc);
    __syncthreads();
    float acc2 = bo2[lane];
    #pragma unroll
    for (int k = 0; k < 64; k++) acc2 += sh[k] * Wo2[k*64 + lane];
    skb[lane] = gelu_exact(acc2);
    __syncthreads();
    for (int l = 0; l < 2; l++) {
        float a = 0.f;
        #pragma unroll
        for (int k = 0; k < 64; k++) a += skb[k] * Wf[l*4096 + k*64 + lane];
        fkb[l*9216 + i*768 + j*64 + lane] = a;
    }
}

// ---------------------------------------------------------------------------
// K2: x = f @ We (unchanged)
// ---------------------------------------------------------------------------
__global__ __launch_bounds__(256) void embed_kernel(
    const float* __restrict__ f, const float* __restrict__ We, float* __restrict__ xe)
{
    int v = blockIdx.x*4 + (threadIdx.x >> 6);
    int lane = threadIdx.x & 63;
    if (v >= N_NODES) return;
    float acc = 0.f;
    #pragma unroll
    for (int k = 0; k < 16; k++) acc += f[v*16 + k] * We[k*64 + lane];
    xe[v*64 + lane] = acc;
}

// ---------------------------------------------------------------------------
// K3 (v9): kb MLP via MFMA -> akb, stored at DST-SORTED index (row -> j;
// e = perm[j] only affects Phase A's input gather). Stores stay coalesced
// (rows relabeled), gathers become sequential streams. Zero atomics.
// ---------------------------------------------------------------------------
#define KB_WREG 4736
__global__ __launch_bounds__(256, 4) void kb_mfma(
    const float* __restrict__ pos, const float* __restrict__ ori,
    const short* __restrict__ W1K, const float* __restrict__ bb1,
    const short* __restrict__ W2K, const float* __restrict__ bb2,
    const short* __restrict__ WkA, __hip_bfloat16* __restrict__ akbA,
    const short* __restrict__ WkB2, __hip_bfloat16* __restrict__ akbB,
    int dual, const int* __restrict__ ei, const int* __restrict__ perm)
{
    __shared__ short sU[4*KB_WREG];

    int tid = threadIdx.x;
    int w = tid >> 6, l = tid & 63;
    short* reg  = sU + w*KB_WREG;
    float* envp = (float*)(reg + 64*72);
    int blockRow = blockIdx.x * 256;

    // ---- Phase A: features (sorted row -> j -> orig edge e = perm[j]) ----
    {
        int row = blockRow + tid;
        int j = row / 12, o = row - j*12;
        int e = perm[j];
        int sn = ei[e], dn = ei[N_EDGES + e];
        float rx = pos[sn*3+0] - pos[dn*3+0];
        float ry = pos[sn*3+1] - pos[dn*3+1];
        float rz = pos[sn*3+2] - pos[dn*3+2];
        float d  = sqrtf(rx*rx + ry*ry + rz*rz);
        float u2 = d*d, u4 = u2*u2, u6 = u4*u2;
        float env = (d < 1.0f) ? (1.0f - 28.0f*u6 + 48.0f*u6*d - 21.0f*u6*u2) : 0.0f;
        envp[l] = env;

        float ox = ori[3*o], oy = ori[3*o+1], oz = ori[3*o+2];
        float a  = rx*ox + ry*oy + rz*oz;
        float qx = rx - a*ox, qy = ry - a*oy, qz = rz - a*oz;
        float b  = sqrtf(qx*qx + qy*qy + qz*qz);

        float fv[32];
        fv[0] = a; fv[1] = b;
        fv[2] = a*a; fv[3] = a*b; fv[4] = b*a; fv[5] = b*b;
        #pragma unroll
        for (int i = 0; i < 4; i++) { fv[6+2*i] = fv[2+i]*a; fv[7+2*i] = fv[2+i]*b; }
        #pragma unroll
        for (int i = 0; i < 8; i++) { fv[14+2*i] = fv[6+i]*a; fv[15+2*i] = fv[6+i]*b; }
        fv[30] = 0.f; fv[31] = 0.f;

        short* dst = reg + l*40;
        #pragma unroll
        for (int blk = 0; blk < 4; blk++) {
            union { short s[8]; int4 v4; } u;
            #pragma unroll
            for (int jj = 0; jj < 8; jj++) u.s[jj] = f2bf(fv[blk*8 + jj]);
            *(int4*)(dst + blk*8) = u.v4;
        }
    }
    __builtin_amdgcn_wave_barrier();

    int m16 = l & 15, q = l >> 4;

    bfrag a1[4];
    #pragma unroll
    for (int mt = 0; mt < 4; mt++)
        a1[mt] = *(const bfrag*)(reg + (mt*16 + m16)*40 + q*8);
    __builtin_amdgcn_wave_barrier();

    // ---- FFN1: K=32 ----
    #pragma unroll
    for (int nt = 0; nt < 4; nt++) {
        bfrag bb = *(const bfrag*)(W1K + (nt*16 + m16)*32 + q*8);
        float bias = bb1[nt*16 + m16];
        #pragma unroll
        for (int mt = 0; mt < 4; mt++) {
            f32x4 acc = (f32x4){0.f,0.f,0.f,0.f};
            acc = __builtin_amdgcn_mfma_f32_16x16x32_bf16(a1[mt], bb, acc, 0, 0, 0);
            #pragma unroll
            for (int r = 0; r < 4; r++) {
                int rl = mt*16 + q*4 + r;
                reg[rl*72 + nt*16 + m16] = f2bf(gelu_f(acc[r] + bias));
            }
        }
    }
    __builtin_amdgcn_wave_barrier();

    // ---- FFN2: K=64 -> kb back into sH ----
    bfrag a2[4][2];
    #pragma unroll
    for (int mt = 0; mt < 4; mt++)
        #pragma unroll
        for (int kc = 0; kc < 2; kc++)
            a2[mt][kc] = *(const bfrag*)(reg + (mt*16 + m16)*72 + kc*32 + q*8);
    __builtin_amdgcn_wave_barrier();

    #pragma unroll
    for (int nt = 0; nt < 4; nt++) {
        f32x4 acc[4];
        #pragma unroll
        for (int mt = 0; mt < 4; mt++) acc[mt] = (f32x4){0.f,0.f,0.f,0.f};
        #pragma unroll
        for (int kc = 0; kc < 2; kc++) {
            bfrag bb = *(const bfrag*)(W2K + (nt*16 + m16)*64 + kc*32 + q*8);
            #pragma unroll
            for (int mt = 0; mt < 4; mt++)
                acc[mt] = __builtin_amdgcn_mfma_f32_16x16x32_bf16(a2[mt][kc], bb, acc[mt], 0, 0, 0);
        }
        float bias = bb2[nt*16 + m16];
        #pragma unroll
        for (int mt = 0; mt < 4; mt++) {
            #pragma unroll
            for (int r = 0; r < 4; r++) {
                int rl = mt*16 + q*4 + r;
                reg[rl*72 + nt*16 + m16] = f2bf(gelu_f(acc[mt][r] + bias) * envp[rl]);
            }
        }
    }
    __builtin_amdgcn_wave_barrier();

    // ---- akb GEMMs + packed coalesced stores (sorted row index) ----
    bfrag a3[4][2];
    #pragma unroll
    for (int mt = 0; mt < 4; mt++)
        #pragma unroll
        for (int kc = 0; kc < 2; kc++)
            a3[mt][kc] = *(const bfrag*)(reg + (mt*16 + m16)*72 + kc*32 + q*8);

    #pragma unroll
    for (int nt = 0; nt < 4; nt++) {
        f32x4 acc[4];
        #pragma unroll
        for (int mt = 0; mt < 4; mt++) acc[mt] = (f32x4){0.f,0.f,0.f,0.f};
        #pragma unroll
        for (int kc = 0; kc < 2; kc++) {
            bfrag bb = *(const bfrag*)(WkA + (nt*16 + m16)*64 + kc*32 + q*8);
            #pragma unroll
            for (int mt = 0; mt < 4; mt++)
                acc[mt] = __builtin_amdgcn_mfma_f32_16x16x32_bf16(a3[mt][kc], bb, acc[mt], 0, 0, 0);
        }
        #pragma unroll
        for (int mt = 0; mt < 4; mt++)
            #pragma unroll
            for (int r = 0; r < 4; r++) {
                int R = blockRow + w*64 + mt*16 + q*4 + r;
                store_bf16_packed(akbA, R, nt*16, m16, acc[mt][r]);
            }
    }
    if (dual) {
        #pragma unroll
        for (int nt = 0; nt < 4; nt++) {
            f32x4 acc[4];
            #pragma unroll
            for (int mt = 0; mt < 4; mt++) acc[mt] = (f32x4){0.f,0.f,0.f,0.f};
            #pragma unroll
            for (int kc = 0; kc < 2; kc++) {
                bfrag bb = *(const bfrag*)(WkB2 + (nt*16 + m16)*64 + kc*32 + q*8);
                #pragma unroll
                for (int mt = 0; mt < 4; mt++)
                    acc[mt] = __builtin_amdgcn_mfma_f32_16x16x32_bf16(a3[mt][kc], bb, acc[mt], 0, 0, 0);
            }
            #pragma unroll
            for (int mt = 0; mt < 4; mt++)
                #pragma unroll
                for (int r = 0; r < 4; r++) {
                    int R = blockRow + w*64 + mt*16 + q*4 + r;
                    store_bf16_packed(akbB, R, nt*16, m16, acc[mt][r]);
                }
        }
    }
}

// ---------------------------------------------------------------------------
// K4a: layer-0 CSR gather — akb indexed by sorted j (sequential stream),
// 2-way unrolled for load ILP.
// ---------------------------------------------------------------------------
__global__ __launch_bounds__(256) void gather0(
    const __hip_bfloat16* __restrict__ akb,
    const int* __restrict__ srcOf, const int* __restrict__ rp,
    const float* __restrict__ xe, __hip_bfloat16* __restrict__ x1)
{
    int w = threadIdx.x >> 6, lane = threadIdx.x & 63;
    int g = blockIdx.x*4 + w;
    int v = g / 12, o = g - v*12;
    int jb = rp[v], je = rp[v+1];
    float acc = 0.f;
    int j = jb;
    for (; j + 1 < je; j += 2) {
        float a0 = __bfloat162float(akb[(size_t)j*768 + o*64 + lane]);
        float a1 = __bfloat162float(akb[(size_t)(j+1)*768 + o*64 + lane]);
        float x0 = xe[(size_t)srcOf[j]*64 + lane];
        float x1v= xe[(size_t)srcOf[j+1]*64 + lane];
        acc += a0 * x0 + a1 * x1v;
    }
    if (j < je) {
        float a0 = __bfloat162float(akb[(size_t)j*768 + o*64 + lane]);
        acc += a0 * xe[(size_t)srcOf[j]*64 + lane];
    }
    x1[(size_t)v*768 + o*64 + lane] = __float2bfloat16(acc);
}

// ---------------------------------------------------------------------------
// K4b: layer-1 CSR gather — same treatment.
// ---------------------------------------------------------------------------
__global__ __launch_bounds__(256) void gather1(
    const __hip_bfloat16* __restrict__ akb,
    const int* __restrict__ srcOf, const int* __restrict__ rp,
    const __hip_bfloat16* __restrict__ x_in, __hip_bfloat16* __restrict__ x1)
{
    int w = threadIdx.x >> 6, lane = threadIdx.x & 63;
    int g = blockIdx.x*4 + w;
    int v = g / 12, o = g - v*12;
    int jb = rp[v], je = rp[v+1];
    float acc = 0.f;
    int j = jb;
    for (; j + 1 < je; j += 2) {
        float a0 = __bfloat162float(akb[(size_t)j*768 + o*64 + lane]);
        float a1 = __bfloat162float(akb[(size_t)(j+1)*768 + o*64 + lane]);
        float x0 = __bfloat162float(x_in[(size_t)srcOf[j]*768 + o*64 + lane]);
        float x1v= __bfloat162float(x_in[(size_t)srcOf[j+1]*768 + o*64 + lane]);
        acc += a0 * x0 + a1 * x1v;
    }
    if (j < je) {
        float a0 = __bfloat162float(akb[(size_t)j*768 + o*64 + lane]);
        acc += a0 * __bfloat162float(x_in[(size_t)srcOf[j]*768 + o*64 + lane]);
    }
    x1[(size_t)v*768 + o*64 + lane] = __float2bfloat16(acc);
}

// ---------------------------------------------------------------------------
// K5 (v4): node kernel (unchanged from r13)
// ---------------------------------------------------------------------------
#define ND_WREG 4352
__global__ __launch_bounds__(256, 4) void node_mfma(
    const short* __restrict__ x1, const float* __restrict__ fk,
    const float* __restrict__ conv_b, const float* __restrict__ ln_g,
    const float* __restrict__ ln_b,
    const short* __restrict__ W1B, const float* __restrict__ b1,
    const short* __restrict__ W2B, const float* __restrict__ pb2,
    const float* __restrict__ Wr, const float* __restrict__ br,
    const __hip_bfloat16* __restrict__ x_old, __hip_bfloat16* __restrict__ x_new,
    float* __restrict__ racc, int has_res, int write_x)
{
    __shared__ short sU[4*ND_WREG];

    int tid = threadIdx.x;
    int w   = tid >> 6;
    int blockRow = blockIdx.x * 128;
    short* reg = sU + w*ND_WREG;

    {
        int rl = tid >> 1, hf = tid & 1;
        int lr = rl - 32*w;
        int row = blockRow + rl;
        int rc = row < N_ROWS ? row : N_ROWS - 1;
        int v = rc / 12, pp = rc % 12;
        float h[32];
        #pragma unroll
        for (int k = 0; k < 32; k++) h[k] = 0.f;
        const short* xv = x1 + (size_t)v*768 + hf*32;
        const float* fp = fk + (size_t)pp*768 + hf*32;
        for (int o = 0; o < 12; o++) {
            const int4*  xa = (const int4*)(xv + o*64);
            const float4* fa = (const float4*)(fp + o*64);
            #pragma unroll
            for (int k4 = 0; k4 < 4; k4++) {
                int4 xi = xa[k4];
                float4 f0 = fa[2*k4], f1 = fa[2*k4+1];
                h[8*k4+0] += bflo((unsigned)xi.x)*f0.x; h[8*k4+1] += bfhi((unsigned)xi.x)*f0.y;
                h[8*k4+2] += bflo((unsigned)xi.y)*f0.z; h[8*k4+3] += bfhi((unsigned)xi.y)*f0.w;
                h[8*k4+4] += bflo((unsigned)xi.z)*f1.x; h[8*k4+5] += bfhi((unsigned)xi.z)*f1.y;
                h[8*k4+6] += bflo((unsigned)xi.w)*f1.z; h[8*k4+7] += bfhi((unsigned)xi.w)*f1.w;
            }
        }
        const float inv12 = 1.0f/12.0f;
        float sum = 0.f;
        #pragma unroll
        for (int k = 0; k < 32; k++) { h[k] = h[k]*inv12 + conv_b[hf*32 + k]; sum += h[k]; }
        sum += __shfl_xor(sum, 1);
        float mu = sum * (1.0f/64.0f);
        float var = 0.f;
        #pragma unroll
        for (int k = 0; k < 32; k++) { float xc = h[k] - mu; var += xc*xc; }
        var += __shfl_xor(var, 1);
        float rstd = rsqrtf(var*(1.0f/64.0f) + 1e-5f);
        short* dst = reg + lr*72 + hf*32;
        #pragma unroll
        for (int blk = 0; blk < 4; blk++) {
            union { short s[8]; int4 v4; } u;
            #pragma unroll
            for (int jj = 0; jj < 8; jj++) {
                int k = blk*8 + jj, c = hf*32 + k;
                u.s[jj] = f2bf((h[k] - mu)*rstd*ln_g[c] + ln_b[c]);
            }
            *(int4*)(dst + blk*8) = u.v4;
        }
    }
    __builtin_amdgcn_wave_barrier();

    int l   = tid & 63;
    int m16 = l & 15, q = l >> 4;

    bfrag a1[2][2];
    #pragma unroll
    for (int i = 0; i < 2; i++)
        #pragma unroll
        for (int kc = 0; kc < 2; kc++)
            a1[i][kc] = *(const bfrag*)(reg + (i*16 + m16)*72 + kc*32 + q*8);
    __builtin_amdgcn_wave_barrier();

    f32x4 acc2[4][2];
    #pragma unroll
    for (int n = 0; n < 4; n++)
        #pragma unroll
        for (int i = 0; i < 2; i++)
            acc2[n][i] = (f32x4){0.f, 0.f, 0.f, 0.f};

    for (int ph = 0; ph < 2; ph++) {
        for (int ntl = 0; ntl < 8; ntl++) {
            int nt = ph*8 + ntl;
            f32x4 c0 = (f32x4){0.f,0.f,0.f,0.f};
            f32x4 c1 = (f32x4){0.f,0.f,0.f,0.f};
            #pragma unroll
            for (int kc = 0; kc < 2; kc++) {
                bfrag bb = *(const bfrag*)(W1B + (nt*16 + m16)*64 + kc*32 + q*8);
                c0 = __builtin_amdgcn_mfma_f32_16x16x32_bf16(a1[0][kc], bb, c0, 0, 0, 0);
                c1 = __builtin_amdgcn_mfma_f32_16x16x32_bf16(a1[1][kc], bb, c1, 0, 0, 0);
            }
            float bias = b1[nt*16 + m16];
            #pragma unroll
            for (int r = 0; r < 4; r++) {
                int r0 = q*4 + r;
                int r1 = 16 + q*4 + r;
                reg[r0*136 + ntl*16 + m16] = f2bf(gelu_f(c0[r] + bias));
                reg[r1*136 + ntl*16 + m16] = f2bf(gelu_f(c1[r] + bias));
            }
        }
        __builtin_amdgcn_wave_barrier();
        for (int kc2 = 0; kc2 < 4; kc2++) {
            bfrag a2[2];
            #pragma unroll
            for (int i = 0; i < 2; i++)
                a2[i] = *(const bfrag*)(reg + (i*16 + m16)*136 + kc2*32 + q*8);
            #pragma unroll
            for (int nc = 0; nc < 4; nc++) {
                bfrag bb = *(const bfrag*)(W2B + (nc*16 + m16)*256 + ph*128 + kc2*32 + q*8);
                acc2[nc][0] = __builtin_amdgcn_mfma_f32_16x16x32_bf16(a2[0], bb, acc2[nc][0], 0, 0, 0);
                acc2[nc][1] = __builtin_amdgcn_mfma_f32_16x16x32_bf16(a2[1], bb, acc2[nc][1], 0, 0, 0);
            }
        }
        __builtin_amdgcn_wave_barrier();
    }

    float p0[2][4], p1[2][4];
    #pragma unroll
    for (int i = 0; i < 2; i++) {
        #pragma unroll
        for (int r = 0; r < 4; r++) {
            int rowl = 32*w + i*16 + q*4 + r;
            int row  = blockRow + rowl;
            bool ok  = row < N_ROWS;
            float vals[4];
            #pragma unroll
            for (int nc = 0; nc < 4; nc++) vals[nc] = acc2[nc][i][r] + pb2[nc*16 + m16];
            if (has_res && ok) {
                #pragma unroll
                for (int nc = 0; nc < 4; nc++)
                    vals[nc] += __bfloat162float(x_old[(size_t)row*64 + nc*16 + m16]);
            }
            if (write_x && ok) {
                #pragma unroll
                for (int nc = 0; nc < 4; nc++)
                    store_bf16_packed(x_new, row, nc*16, m16, vals[nc]);
            }
            float q0 = 0.f, q1 = 0.f;
            #pragma unroll
            for (int nc = 0; nc < 4; nc++) {
                int c = nc*16 + m16;
                q0 += vals[nc]*Wr[2*c];
                q1 += vals[nc]*Wr[2*c + 1];
            }
            p0[i][r] = q0; p1[i][r] = q1;
        }
    }
    #pragma unroll
    for (int s = 1; s < 16; s <<= 1) {
        #pragma unroll
        for (int i = 0; i < 2; i++)
            #pragma unroll
            for (int r = 0; r < 4; r++) {
                p0[i][r] += __shfl_xor(p0[i][r], s);
                p1[i][r] += __shfl_xor(p1[i][r], s);
            }
    }
    if (m16 == 0) {
        #pragma unroll
        for (int i = 0; i < 2; i++)
            #pragma unroll
            for (int r = 0; r < 4; r++) {
                int row = blockRow + 32*w + i*16 + q*4 + r;
                if (row < N_ROWS) {
                    atomicAdd(&racc[row*2 + 0], p0[i][r] + br[0]);
                    atomicAdd(&racc[row*2 + 1], p1[i][r] + br[1]);
                }
            }
    }
}

// ---------------------------------------------------------------------------
// K6 (v2): readout — two-stage reduction (unchanged)
// ---------------------------------------------------------------------------
__global__ __launch_bounds__(256) void final_kernel(
    const float* __restrict__ racc, const float* __restrict__ ori,
    const int* __restrict__ batch, float* __restrict__ out)
{
    __shared__ float sAcc[64];
    int tid = threadIdx.x;
    if (tid < 64) sAcc[tid] = 0.f;
    __syncthreads();

    int v = blockIdx.x*256 + tid;
    if (v < N_NODES) {
        float srs = 0.f, vx = 0.f, vy = 0.f, vz = 0.f;
        #pragma unroll
        for (int p = 0; p < 12; p++) {
            float r0 = racc[v*24 + 2*p], r1 = racc[v*24 + 2*p + 1];
            srs += r0;
            vx += r1*ori[3*p]; vy += r1*ori[3*p+1]; vz += r1*ori[3*p+2];
        }
        const float sc = 1.0f/24.0f;
        int g = batch[v];
        atomicAdd(&sAcc[g],            srs*sc);
        atomicAdd(&sAcc[16 + g*3 + 0], vx*sc);
        atomicAdd(&sAcc[16 + g*3 + 1], vy*sc);
        atomicAdd(&sAcc[16 + g*3 + 2], vz*sc);
    }
    __syncthreads();
    if (tid < 64) atomicAdd(&out[tid], sAcc[tid]);
}

extern "C" void kernel_launch(void* const* d_in, const int* in_sizes, int n_in,
                              void* d_out, int out_size, void* d_ws, size_t ws_size,
                              hipStream_t stream) {
    const float* pos    = (const float*)d_in[0];
    const float* f      = (const float*)d_in[1];
    const float* ori    = (const float*)d_in[2];
    const int*   ei     = (const int*)  d_in[3];
    const int*   batch  = (const int*)  d_in[4];
    const float* Wb1    = (const float*)d_in[5];
    const float* bb1    = (const float*)d_in[6];
    const float* Wb2    = (const float*)d_in[7];
    const float* bb2    = (const float*)d_in[8];
    const float* Wo1    = (const float*)d_in[9];
    const float* bo1    = (const float*)d_in[10];
    const float* Wo2    = (const float*)d_in[11];
    const float* bo2    = (const float*)d_in[12];
    const float* We     = (const float*)d_in[13];
    const float* Wk     = (const float*)d_in[14];
    const float* Wf     = (const float*)d_in[15];
    const float* conv_b = (const float*)d_in[16];
    const float* ln_g   = (const float*)d_in[17];
    const float* ln_b   = (const float*)d_in[18];
    const float* W1     = (const float*)d_in[19];
    const float* b1     = (const float*)d_in[20];
    const float* W2     = (const float*)d_in[21];
    const float* b2     = (const float*)d_in[22];
    const float* Wr     = (const float*)d_in[23];
    const float* br     = (const float*)d_in[24];
    float* out = (float*)d_out;

    float* ws   = (float*)d_ws;
    float* xe   = ws;                               //   640,000 f32
    short* xs1b = (short*)(xe + 640000);            // 7,680,000 bf16
    short* x1b  = xs1b + 7680000;                   // 7,680,000 bf16
    float* racc = (float*)(x1b + 7680000);          //   240,000 f32
    float* fkb  = racc + 240000;                    //    18,432
    short* w1b  = (short*)(fkb + 18432);            //    32,768 shorts
    short* w2b  = w1b + 32768;
    short* w1k  = w2b + 32768;
    short* w2k  = w1k + 2048;
    short* wkb  = w2k + 4096;
    int*   deg  = (int*)(wkb + 8192);               //    10,000 ints
    int*   rp   = deg + 10000;
    int*   wp   = rp  + 10001;
    int*   perm = wp  + 10000;
    int*   srcOf= perm+ 80000;
    int*   pad_ = srcOf + 80000;
    __hip_bfloat16* akbA = (__hip_bfloat16*)(pad_ + 3);   // 61,440,000 bf16 (~123 MB)
    __hip_bfloat16* akbB = akbA + 61440000;               // second buffer (full mode)

    size_t need_full = ((char*)(akbB + 61440000)) - ((char*)d_ws);
    int full = (ws_size >= need_full) ? 1 : 0;

    hipMemsetAsync(out,  0, 64*sizeof(float), stream);
    hipMemsetAsync(racc, 0, 240000*sizeof(float), stream);
    hipMemsetAsync(deg,  0, 10000*sizeof(int), stream);

    csr_count<<<313, 256, 0, stream>>>(ei, deg);
    csr_scan <<<1,   256, 0, stream>>>(deg, rp, wp);
    csr_fill <<<313, 256, 0, stream>>>(ei, wp, perm, srcOf);

    prep_weights<<<4,    256, 0, stream>>>(W1, W2, Wb1, Wb2, Wk,
                                           w1b, w2b, w1k, w2k, wkb);
    ori_kernel  <<<144,  64, 0, stream>>>(ori, Wo1, bo1, Wo2, bo2, Wf, fkb);
    embed_kernel<<<2500, 256, 0, stream>>>(f, We, xe);

    if (full) {
        kb_mfma <<<3750, 256, 0, stream>>>(pos, ori, w1k, bb1, w2k, bb2,
                                           wkb, akbA, wkb + 4096, akbB, /*dual=*/1, ei, perm);
        gather0 <<<30000,256, 0, stream>>>(akbA, srcOf, rp, xe, (__hip_bfloat16*)x1b);
        node_mfma<<<938, 256, 0, stream>>>(x1b, fkb, conv_b, ln_g, ln_b,
                                           w1b, b1, w2b, b2, Wr, br,
                                           (const __hip_bfloat16*)xs1b, (__hip_bfloat16*)xs1b,
                                           racc, /*res=*/0, /*write=*/1);
        gather1 <<<30000,256, 0, stream>>>(akbB, srcOf, rp,
                                           (const __hip_bfloat16*)xs1b, (__hip_bfloat16*)x1b);
    } else {
        kb_mfma <<<3750, 256, 0, stream>>>(pos, ori, w1k, bb1, w2k, bb2,
                                           wkb, akbA, wkb, akbA, /*dual=*/0, ei, perm);
        gather0 <<<30000,256, 0, stream>>>(akbA, srcOf, rp, xe, (__hip_bfloat16*)x1b);
        node_mfma<<<938, 256, 0, stream>>>(x1b, fkb, conv_b, ln_g, ln_b,
                                           w1b, b1, w2b, b2, Wr, br,
                                           (const __hip_bfloat16*)xs1b, (__hip_bfloat16*)xs1b,
                                           racc, /*res=*/0, /*write=*/1);
        kb_mfma <<<3750, 256, 0, stream>>>(pos, ori, w1k, bb1, w2k, bb2,
                                           wkb + 4096, akbA, wkb + 4096, akbA, /*dual=*/0, ei, perm);
        gather1 <<<30000,256, 0, stream>>>(akbA, srcOf, rp,
                                           (const __hip_bfloat16*)xs1b, (__hip_bfloat16*)x1b);
    }

    node_mfma   <<<938,  256, 0, stream>>>(x1b, fkb + 9216, conv_b + 64, ln_g + 64, ln_b + 64,
                                           w1b + 16384, b1 + 256, w2b + 16384, b2 + 64,
                                           Wr + 128, br + 2,
                                           (const __hip_bfloat16*)xs1b, (__hip_bfloat16*)xs1b,
                                           racc, /*res=*/1, /*write=*/0);

    final_kernel<<<40,   256, 0, stream>>>(racc, ori, batch, out);
}

// Round 15
// 705.769 us; speedup vs baseline: 1.7983x; 1.0183x over previous
//
#include <hip/hip_runtime.h>
#include <hip/hip_bf16.h>
#include <math.h>

#define N_NODES 10000
#define N_EDGES 80000
#define N_ORI   12
#define N_ROWS  (N_NODES * N_ORI)

typedef __attribute__((ext_vector_type(8))) short bfrag;   // 8 bf16 = 4 VGPRs
typedef __attribute__((ext_vector_type(4))) float f32x4;

// fast gelu (tanh-approx, overflow-safe); |err| < ~3e-3 < bf16 ulp downstream
__device__ __forceinline__ float gelu_f(float x) {
    float u = 1.5957691216057308f * x * (1.0f + 0.044715f * x * x);
    float e = __expf(-u);
    return x * __builtin_amdgcn_rcpf(1.0f + e);
}
// exact gelu for the tiny f32-precision ori path
__device__ __forceinline__ float gelu_exact(float x) {
    return 0.5f * x * (1.0f + erff(x * 0.70710678118654752440f));
}
__device__ __forceinline__ short f2bf(float x) {
    __hip_bfloat16 h = __float2bfloat16(x);
    return *reinterpret_cast<short*>(&h);
}
__device__ __forceinline__ float bflo(unsigned u) { return __uint_as_float(u << 16); }
__device__ __forceinline__ float bfhi(unsigned u) { return __uint_as_float(u & 0xffff0000u); }

// packed bf16 store: 4 cols / 8 B per quad of lanes -> full 128 B lines
__device__ __forceinline__ void store_bf16_packed(
    __hip_bfloat16* base, int row64, int colBase, int m16, float val)
{
    int my = (int)(unsigned short)f2bf(val);
    int p1 = __shfl_xor(my, 1);
    int packed01 = my | (p1 << 16);
    int p2 = __shfl_xor(packed01, 2);
    if ((m16 & 3) == 0) {
        int2 st; st.x = packed01; st.y = p2;
        *(int2*)((short*)base + (size_t)row64*64 + colBase + m16) = st;
    }
}

// ---------------------------------------------------------------------------
// CSR build (dst-sorted edge list for gathers)
// ---------------------------------------------------------------------------
__global__ __launch_bounds__(256) void csr_count(
    const int* __restrict__ ei, int* __restrict__ deg)
{
    int e = blockIdx.x*256 + threadIdx.x;
    if (e < N_EDGES) atomicAdd(&deg[ei[N_EDGES + e]], 1);
}

__global__ __launch_bounds__(256) void csr_scan(
    const int* __restrict__ deg, int* __restrict__ rp, int* __restrict__ wp)
{
    __shared__ int part[256];
    __shared__ int sbase[257];
    int t = threadIdx.x;
    int cs = t*40;
    int sum = 0;
    for (int i = 0; i < 40; i++) { int idx = cs+i; if (idx < N_NODES) sum += deg[idx]; }
    part[t] = sum;
    __syncthreads();
    if (t == 0) {
        int run = 0;
        for (int i = 0; i < 256; i++) { sbase[i] = run; run += part[i]; }
        sbase[256] = run;
    }
    __syncthreads();
    int run = sbase[t];
    for (int i = 0; i < 40; i++) {
        int idx = cs+i;
        if (idx < N_NODES) { rp[idx] = run; wp[idx] = run; run += deg[idx]; }
    }
    if (t == 0) rp[N_NODES] = sbase[256];
}

__global__ __launch_bounds__(256) void csr_fill(
    const int* __restrict__ ei, int* __restrict__ wp,
    int* __restrict__ perm, int* __restrict__ srcOf)
{
    int e = blockIdx.x*256 + threadIdx.x;
    if (e >= N_EDGES) return;
    int dn = ei[N_EDGES + e];
    int j = atomicAdd(&wp[dn], 1);
    perm[j] = e;
    srcOf[j] = ei[e];
}

// ---------------------------------------------------------------------------
// K0: weight prep (unchanged)
// ---------------------------------------------------------------------------
__global__ __launch_bounds__(256) void prep_weights(
    const float* __restrict__ W1, const float* __restrict__ W2,
    const float* __restrict__ Wb1, const float* __restrict__ Wb2,
    const float* __restrict__ Wk,
    short* __restrict__ W1B, short* __restrict__ W2B,
    short* __restrict__ W1K, short* __restrict__ W2K,
    short* __restrict__ WkB)
{
    if (blockIdx.x < 2) {
        int l = blockIdx.x;
        const float* w1 = W1 + l*16384; short* w1b = W1B + l*16384;
        const float* w2 = W2 + l*16384; short* w2b = W2B + l*16384;
        for (int i = threadIdx.x; i < 16384; i += 256) {
            int k = i >> 8, t = i & 255;
            w1b[t*64 + k] = f2bf(w1[i]);
            int t2 = i >> 6, c = i & 63;
            w2b[c*256 + t2] = f2bf(w2[i]);
        }
    } else if (blockIdx.x == 2) {
        for (int i = threadIdx.x; i < 2048; i += 256) {
            int t = i >> 5, k = i & 31;
            W1K[i] = (k < 30) ? f2bf(Wb1[k*64 + t]) : (short)0;
        }
        for (int i = threadIdx.x; i < 4096; i += 256) {
            int c = i >> 6, t = i & 63;
            W2K[i] = f2bf(Wb2[t*64 + c]);
        }
    } else {
        for (int i = threadIdx.x; i < 8192; i += 256) {
            int l = i >> 12, rem = i & 4095, k = rem >> 6, c = rem & 63;
            WkB[l*4096 + c*64 + k] = f2bf(Wk[l*4096 + k*64 + c]);
        }
    }
}

// ---------------------------------------------------------------------------
// K1: kb_ori MLP + fk (exact gelu — f32 path, tiny kernel)
// ---------------------------------------------------------------------------
__global__ __launch_bounds__(64) void ori_kernel(
    const float* __restrict__ ori, const float* __restrict__ Wo1,
    const float* __restrict__ bo1, const float* __restrict__ Wo2,
    const float* __restrict__ bo2, const float* __restrict__ Wf,
    float* __restrict__ fkb)
{
    __shared__ float sh[64];
    __shared__ float skb[64];
    int i = blockIdx.x / 12, j = blockIdx.x % 12;
    int lane = threadIdx.x;
    float s = ori[3*i]*ori[3*j] + ori[3*i+1]*ori[3*j+1] + ori[3*i+2]*ori[3*j+2];
    float p1 = s, p2 = s*s, p3 = p2*s, p4 = p3*s;
    float acc = bo1[lane] + p1*Wo1[lane] + p2*Wo1[64+lane] + p3*Wo1[128+lane] + p4*Wo1[192+lane];
    sh[lane] = gelu_exact(acc);
    __syncthreads();
    float acc2 = bo2[lane];
    #pragma unroll
    for (int k = 0; k < 64; k++) acc2 += sh[k] * Wo2[k*64 + lane];
    skb[lane] = gelu_exact(acc2);
    __syncthreads();
    for (int l = 0; l < 2; l++) {
        float a = 0.f;
        #pragma unroll
        for (int k = 0; k < 64; k++) a += skb[k] * Wf[l*4096 + k*64 + lane];
        fkb[l*9216 + i*768 + j*64 + lane] = a;
    }
}

// ---------------------------------------------------------------------------
// K2: x = f @ We (unchanged)
// ---------------------------------------------------------------------------
__global__ __launch_bounds__(256) void embed_kernel(
    const float* __restrict__ f, const float* __restrict__ We, float* __restrict__ xe)
{
    int v = blockIdx.x*4 + (threadIdx.x >> 6);
    int lane = threadIdx.x & 63;
    if (v >= N_NODES) return;
    float acc = 0.f;
    #pragma unroll
    for (int k = 0; k < 16; k++) acc += f[v*16 + k] * We[k*64 + lane];
    xe[v*64 + lane] = acc;
}

// ---------------------------------------------------------------------------
// K3 (v9): kb MLP via MFMA -> akb at dst-sorted index (unchanged from r14)
// ---------------------------------------------------------------------------
#define KB_WREG 4736
__global__ __launch_bounds__(256, 4) void kb_mfma(
    const float* __restrict__ pos, const float* __restrict__ ori,
    const short* __restrict__ W1K, const float* __restrict__ bb1,
    const short* __restrict__ W2K, const float* __restrict__ bb2,
    const short* __restrict__ WkA, __hip_bfloat16* __restrict__ akbA,
    const short* __restrict__ WkB2, __hip_bfloat16* __restrict__ akbB,
    int dual, const int* __restrict__ ei, const int* __restrict__ perm)
{
    __shared__ short sU[4*KB_WREG];

    int tid = threadIdx.x;
    int w = tid >> 6, l = tid & 63;
    short* reg  = sU + w*KB_WREG;
    float* envp = (float*)(reg + 64*72);
    int blockRow = blockIdx.x * 256;

    // ---- Phase A: features (sorted row -> j -> orig edge e = perm[j]) ----
    {
        int row = blockRow + tid;
        int j = row / 12, o = row - j*12;
        int e = perm[j];
        int sn = ei[e], dn = ei[N_EDGES + e];
        float rx = pos[sn*3+0] - pos[dn*3+0];
        float ry = pos[sn*3+1] - pos[dn*3+1];
        float rz = pos[sn*3+2] - pos[dn*3+2];
        float d  = sqrtf(rx*rx + ry*ry + rz*rz);
        float u2 = d*d, u4 = u2*u2, u6 = u4*u2;
        float env = (d < 1.0f) ? (1.0f - 28.0f*u6 + 48.0f*u6*d - 21.0f*u6*u2) : 0.0f;
        envp[l] = env;

        float ox = ori[3*o], oy = ori[3*o+1], oz = ori[3*o+2];
        float a  = rx*ox + ry*oy + rz*oz;
        float qx = rx - a*ox, qy = ry - a*oy, qz = rz - a*oz;
        float b  = sqrtf(qx*qx + qy*qy + qz*qz);

        float fv[32];
        fv[0] = a; fv[1] = b;
        fv[2] = a*a; fv[3] = a*b; fv[4] = b*a; fv[5] = b*b;
        #pragma unroll
        for (int i = 0; i < 4; i++) { fv[6+2*i] = fv[2+i]*a; fv[7+2*i] = fv[2+i]*b; }
        #pragma unroll
        for (int i = 0; i < 8; i++) { fv[14+2*i] = fv[6+i]*a; fv[15+2*i] = fv[6+i]*b; }
        fv[30] = 0.f; fv[31] = 0.f;

        short* dst = reg + l*40;
        #pragma unroll
        for (int blk = 0; blk < 4; blk++) {
            union { short s[8]; int4 v4; } u;
            #pragma unroll
            for (int jj = 0; jj < 8; jj++) u.s[jj] = f2bf(fv[blk*8 + jj]);
            *(int4*)(dst + blk*8) = u.v4;
        }
    }
    __builtin_amdgcn_wave_barrier();

    int m16 = l & 15, q = l >> 4;

    bfrag a1[4];
    #pragma unroll
    for (int mt = 0; mt < 4; mt++)
        a1[mt] = *(const bfrag*)(reg + (mt*16 + m16)*40 + q*8);
    __builtin_amdgcn_wave_barrier();

    // ---- FFN1: K=32 ----
    #pragma unroll
    for (int nt = 0; nt < 4; nt++) {
        bfrag bb = *(const bfrag*)(W1K + (nt*16 + m16)*32 + q*8);
        float bias = bb1[nt*16 + m16];
        #pragma unroll
        for (int mt = 0; mt < 4; mt++) {
            f32x4 acc = (f32x4){0.f,0.f,0.f,0.f};
            acc = __builtin_amdgcn_mfma_f32_16x16x32_bf16(a1[mt], bb, acc, 0, 0, 0);
            #pragma unroll
            for (int r = 0; r < 4; r++) {
                int rl = mt*16 + q*4 + r;
                reg[rl*72 + nt*16 + m16] = f2bf(gelu_f(acc[r] + bias));
            }
        }
    }
    __builtin_amdgcn_wave_barrier();

    // ---- FFN2: K=64 -> kb back into sH ----
    bfrag a2[4][2];
    #pragma unroll
    for (int mt = 0; mt < 4; mt++)
        #pragma unroll
        for (int kc = 0; kc < 2; kc++)
            a2[mt][kc] = *(const bfrag*)(reg + (mt*16 + m16)*72 + kc*32 + q*8);
    __builtin_amdgcn_wave_barrier();

    #pragma unroll
    for (int nt = 0; nt < 4; nt++) {
        f32x4 acc[4];
        #pragma unroll
        for (int mt = 0; mt < 4; mt++) acc[mt] = (f32x4){0.f,0.f,0.f,0.f};
        #pragma unroll
        for (int kc = 0; kc < 2; kc++) {
            bfrag bb = *(const bfrag*)(W2K + (nt*16 + m16)*64 + kc*32 + q*8);
            #pragma unroll
            for (int mt = 0; mt < 4; mt++)
                acc[mt] = __builtin_amdgcn_mfma_f32_16x16x32_bf16(a2[mt][kc], bb, acc[mt], 0, 0, 0);
        }
        float bias = bb2[nt*16 + m16];
        #pragma unroll
        for (int mt = 0; mt < 4; mt++) {
            #pragma unroll
            for (int r = 0; r < 4; r++) {
                int rl = mt*16 + q*4 + r;
                reg[rl*72 + nt*16 + m16] = f2bf(gelu_f(acc[mt][r] + bias) * envp[rl]);
            }
        }
    }
    __builtin_amdgcn_wave_barrier();

    // ---- akb GEMMs + packed coalesced stores (sorted row index) ----
    bfrag a3[4][2];
    #pragma unroll
    for (int mt = 0; mt < 4; mt++)
        #pragma unroll
        for (int kc = 0; kc < 2; kc++)
            a3[mt][kc] = *(const bfrag*)(reg + (mt*16 + m16)*72 + kc*32 + q*8);

    #pragma unroll
    for (int nt = 0; nt < 4; nt++) {
        f32x4 acc[4];
        #pragma unroll
        for (int mt = 0; mt < 4; mt++) acc[mt] = (f32x4){0.f,0.f,0.f,0.f};
        #pragma unroll
        for (int kc = 0; kc < 2; kc++) {
            bfrag bb = *(const bfrag*)(WkA + (nt*16 + m16)*64 + kc*32 + q*8);
            #pragma unroll
            for (int mt = 0; mt < 4; mt++)
                acc[mt] = __builtin_amdgcn_mfma_f32_16x16x32_bf16(a3[mt][kc], bb, acc[mt], 0, 0, 0);
        }
        #pragma unroll
        for (int mt = 0; mt < 4; mt++)
            #pragma unroll
            for (int r = 0; r < 4; r++) {
                int R = blockRow + w*64 + mt*16 + q*4 + r;
                store_bf16_packed(akbA, R, nt*16, m16, acc[mt][r]);
            }
    }
    if (dual) {
        #pragma unroll
        for (int nt = 0; nt < 4; nt++) {
            f32x4 acc[4];
            #pragma unroll
            for (int mt = 0; mt < 4; mt++) acc[mt] = (f32x4){0.f,0.f,0.f,0.f};
            #pragma unroll
            for (int kc = 0; kc < 2; kc++) {
                bfrag bb = *(const bfrag*)(WkB2 + (nt*16 + m16)*64 + kc*32 + q*8);
                #pragma unroll
                for (int mt = 0; mt < 4; mt++)
                    acc[mt] = __builtin_amdgcn_mfma_f32_16x16x32_bf16(a3[mt][kc], bb, acc[mt], 0, 0, 0);
            }
            #pragma unroll
            for (int mt = 0; mt < 4; mt++)
                #pragma unroll
                for (int r = 0; r < 4; r++) {
                    int R = blockRow + w*64 + mt*16 + q*4 + r;
                    store_bf16_packed(akbB, R, nt*16, m16, acc[mt][r]);
                }
        }
    }
}

// ---------------------------------------------------------------------------
// K4a: layer-0 CSR gather — sequential akb stream, 4-way unrolled.
// ---------------------------------------------------------------------------
__global__ __launch_bounds__(256) void gather0(
    const __hip_bfloat16* __restrict__ akb,
    const int* __restrict__ srcOf, const int* __restrict__ rp,
    const float* __restrict__ xe, __hip_bfloat16* __restrict__ x1)
{
    int w = threadIdx.x >> 6, lane = threadIdx.x & 63;
    int g = blockIdx.x*4 + w;
    int v = g / 12, o = g - v*12;
    int jb = rp[v], je = rp[v+1];
    float acc = 0.f;
    int j = jb;
    for (; j + 3 < je; j += 4) {
        float a0 = __bfloat162float(akb[(size_t)j*768 + o*64 + lane]);
        float a1 = __bfloat162float(akb[(size_t)(j+1)*768 + o*64 + lane]);
        float a2 = __bfloat162float(akb[(size_t)(j+2)*768 + o*64 + lane]);
        float a3 = __bfloat162float(akb[(size_t)(j+3)*768 + o*64 + lane]);
        float x0 = xe[(size_t)srcOf[j]*64 + lane];
        float x1v= xe[(size_t)srcOf[j+1]*64 + lane];
        float x2 = xe[(size_t)srcOf[j+2]*64 + lane];
        float x3 = xe[(size_t)srcOf[j+3]*64 + lane];
        acc += a0*x0 + a1*x1v + a2*x2 + a3*x3;
    }
    for (; j < je; j++) {
        float a0 = __bfloat162float(akb[(size_t)j*768 + o*64 + lane]);
        acc += a0 * xe[(size_t)srcOf[j]*64 + lane];
    }
    x1[(size_t)v*768 + o*64 + lane] = __float2bfloat16(acc);
}

// ---------------------------------------------------------------------------
// K4b: layer-1 CSR gather — same treatment.
// ---------------------------------------------------------------------------
__global__ __launch_bounds__(256) void gather1(
    const __hip_bfloat16* __restrict__ akb,
    const int* __restrict__ srcOf, const int* __restrict__ rp,
    const __hip_bfloat16* __restrict__ x_in, __hip_bfloat16* __restrict__ x1)
{
    int w = threadIdx.x >> 6, lane = threadIdx.x & 63;
    int g = blockIdx.x*4 + w;
    int v = g / 12, o = g - v*12;
    int jb = rp[v], je = rp[v+1];
    float acc = 0.f;
    int j = jb;
    for (; j + 3 < je; j += 4) {
        float a0 = __bfloat162float(akb[(size_t)j*768 + o*64 + lane]);
        float a1 = __bfloat162float(akb[(size_t)(j+1)*768 + o*64 + lane]);
        float a2 = __bfloat162float(akb[(size_t)(j+2)*768 + o*64 + lane]);
        float a3 = __bfloat162float(akb[(size_t)(j+3)*768 + o*64 + lane]);
        float x0 = __bfloat162float(x_in[(size_t)srcOf[j]*768 + o*64 + lane]);
        float x1v= __bfloat162float(x_in[(size_t)srcOf[j+1]*768 + o*64 + lane]);
        float x2 = __bfloat162float(x_in[(size_t)srcOf[j+2]*768 + o*64 + lane]);
        float x3 = __bfloat162float(x_in[(size_t)srcOf[j+3]*768 + o*64 + lane]);
        acc += a0*x0 + a1*x1v + a2*x2 + a3*x3;
    }
    for (; j < je; j++) {
        float a0 = __bfloat162float(akb[(size_t)j*768 + o*64 + lane]);
        acc += a0 * __bfloat162float(x_in[(size_t)srcOf[j]*768 + o*64 + lane]);
    }
    x1[(size_t)v*768 + o*64 + lane] = __float2bfloat16(acc);
}

// ---------------------------------------------------------------------------
// K5 (v5): node kernel — 64-row blocks (grid 1875 exact), wave owns 16 rows,
// Phase A quarter-row per thread, LDS 17.4 KB, racc plain stores (layer slot).
// ---------------------------------------------------------------------------
#define ND_WREG2 2176   // shorts per wave region: 16 rows x 136 (sA2 view)
__global__ __launch_bounds__(256, 4) void node_mfma(
    const short* __restrict__ x1, const float* __restrict__ fk,
    const float* __restrict__ conv_b, const float* __restrict__ ln_g,
    const float* __restrict__ ln_b,
    const short* __restrict__ W1B, const float* __restrict__ b1,
    const short* __restrict__ W2B, const float* __restrict__ pb2,
    const float* __restrict__ Wr, const float* __restrict__ br,
    const __hip_bfloat16* __restrict__ x_old, __hip_bfloat16* __restrict__ x_new,
    float* __restrict__ racc, int has_res, int write_x, int lay)
{
    __shared__ short sU[4*ND_WREG2];

    int tid = threadIdx.x;
    int w   = tid >> 6;
    int blockRow = blockIdx.x * 64;
    short* reg = sU + w*ND_WREG2;

    // ---- Phase A: conv + LN, quarter-row (16 cols) per thread ----
    {
        int rl = tid >> 2;              // local row 0..63 (wave w: 16w..16w+15)
        int qt = tid & 3;               // col group of 16
        int lr = rl - 16*w;             // 0..15 within wave
        int row = blockRow + rl;
        int rc = row < N_ROWS ? row : N_ROWS - 1;
        int v = rc / 12, pp = rc % 12;
        float h[16];
        #pragma unroll
        for (int k = 0; k < 16; k++) h[k] = 0.f;
        const short* xv = x1 + (size_t)v*768 + qt*16;
        const float* fp = fk + (size_t)pp*768 + qt*16;
        for (int o = 0; o < 12; o++) {
            const int4*  xa = (const int4*)(xv + o*64);     // 2 int4 = 16 bf16
            const float4* fa = (const float4*)(fp + o*64);
            #pragma unroll
            for (int k4 = 0; k4 < 2; k4++) {
                int4 xi = xa[k4];
                float4 f0 = fa[2*k4], f1 = fa[2*k4+1];
                h[8*k4+0] += bflo((unsigned)xi.x)*f0.x; h[8*k4+1] += bfhi((unsigned)xi.x)*f0.y;
                h[8*k4+2] += bflo((unsigned)xi.y)*f0.z; h[8*k4+3] += bfhi((unsigned)xi.y)*f0.w;
                h[8*k4+4] += bflo((unsigned)xi.z)*f1.x; h[8*k4+5] += bfhi((unsigned)xi.z)*f1.y;
                h[8*k4+6] += bflo((unsigned)xi.w)*f1.z; h[8*k4+7] += bfhi((unsigned)xi.w)*f1.w;
            }
        }
        const float inv12 = 1.0f/12.0f;
        float sum = 0.f;
        #pragma unroll
        for (int k = 0; k < 16; k++) { h[k] = h[k]*inv12 + conv_b[qt*16 + k]; sum += h[k]; }
        sum += __shfl_xor(sum, 1);
        sum += __shfl_xor(sum, 2);
        float mu = sum * (1.0f/64.0f);
        float var = 0.f;
        #pragma unroll
        for (int k = 0; k < 16; k++) { float xc = h[k] - mu; var += xc*xc; }
        var += __shfl_xor(var, 1);
        var += __shfl_xor(var, 2);
        float rstd = rsqrtf(var*(1.0f/64.0f) + 1e-5f);
        short* dst = reg + lr*72 + qt*16;
        #pragma unroll
        for (int blk = 0; blk < 2; blk++) {
            union { short s[8]; int4 v4; } u;
            #pragma unroll
            for (int jj = 0; jj < 8; jj++) {
                int k = blk*8 + jj, c = qt*16 + k;
                u.s[jj] = f2bf((h[k] - mu)*rstd*ln_g[c] + ln_b[c]);
            }
            *(int4*)(dst + blk*8) = u.v4;
        }
    }
    __builtin_amdgcn_wave_barrier();

    int l   = tid & 63;
    int m16 = l & 15, q = l >> 4;

    bfrag a1[2];
    #pragma unroll
    for (int kc = 0; kc < 2; kc++)
        a1[kc] = *(const bfrag*)(reg + m16*72 + kc*32 + q*8);
    __builtin_amdgcn_wave_barrier();

    f32x4 acc2[4];
    #pragma unroll
    for (int n = 0; n < 4; n++) acc2[n] = (f32x4){0.f, 0.f, 0.f, 0.f};

    for (int ph = 0; ph < 2; ph++) {
        for (int ntl = 0; ntl < 8; ntl++) {
            int nt = ph*8 + ntl;
            f32x4 c0 = (f32x4){0.f,0.f,0.f,0.f};
            #pragma unroll
            for (int kc = 0; kc < 2; kc++) {
                bfrag bb = *(const bfrag*)(W1B + (nt*16 + m16)*64 + kc*32 + q*8);
                c0 = __builtin_amdgcn_mfma_f32_16x16x32_bf16(a1[kc], bb, c0, 0, 0, 0);
            }
            float bias = b1[nt*16 + m16];
            #pragma unroll
            for (int r = 0; r < 4; r++)
                reg[(q*4 + r)*136 + ntl*16 + m16] = f2bf(gelu_f(c0[r] + bias));
        }
        __builtin_amdgcn_wave_barrier();
        for (int kc2 = 0; kc2 < 4; kc2++) {
            bfrag a2 = *(const bfrag*)(reg + m16*136 + kc2*32 + q*8);
            #pragma unroll
            for (int nc = 0; nc < 4; nc++) {
                bfrag bb = *(const bfrag*)(W2B + (nc*16 + m16)*256 + ph*128 + kc2*32 + q*8);
                acc2[nc] = __builtin_amdgcn_mfma_f32_16x16x32_bf16(a2, bb, acc2[nc], 0, 0, 0);
            }
        }
        __builtin_amdgcn_wave_barrier();
    }

    // ---- Epilogue ----
    float p0[4], p1[4];
    #pragma unroll
    for (int r = 0; r < 4; r++) {
        int rowl = 16*w + q*4 + r;
        int row  = blockRow + rowl;
        bool ok  = row < N_ROWS;
        float vals[4];
        #pragma unroll
        for (int nc = 0; nc < 4; nc++) vals[nc] = acc2[nc][r] + pb2[nc*16 + m16];
        if (has_res && ok) {
            #pragma unroll
            for (int nc = 0; nc < 4; nc++)
                vals[nc] += __bfloat162float(x_old[(size_t)row*64 + nc*16 + m16]);
        }
        if (write_x && ok) {
            #pragma unroll
            for (int nc = 0; nc < 4; nc++)
                store_bf16_packed(x_new, row, nc*16, m16, vals[nc]);
        }
        float q0 = 0.f, q1 = 0.f;
        #pragma unroll
        for (int nc = 0; nc < 4; nc++) {
            int c = nc*16 + m16;
            q0 += vals[nc]*Wr[2*c];
            q1 += vals[nc]*Wr[2*c + 1];
        }
        p0[r] = q0; p1[r] = q1;
    }
    #pragma unroll
    for (int s = 1; s < 16; s <<= 1) {
        #pragma unroll
        for (int r = 0; r < 4; r++) {
            p0[r] += __shfl_xor(p0[r], s);
            p1[r] += __shfl_xor(p1[r], s);
        }
    }
    if (m16 == 0) {
        #pragma unroll
        for (int r = 0; r < 4; r++) {
            int row = blockRow + 16*w + q*4 + r;
            if (row < N_ROWS) {
                racc[(size_t)row*4 + lay*2 + 0] = p0[r] + br[0];
                racc[(size_t)row*4 + lay*2 + 1] = p1[r] + br[1];
            }
        }
    }
}

// ---------------------------------------------------------------------------
// K6 (v3): readout — racc layer-separated slots, two-stage reduction.
// ---------------------------------------------------------------------------
__global__ __launch_bounds__(256) void final_kernel(
    const float* __restrict__ racc, const float* __restrict__ ori,
    const int* __restrict__ batch, float* __restrict__ out)
{
    __shared__ float sAcc[64];
    int tid = threadIdx.x;
    if (tid < 64) sAcc[tid] = 0.f;
    __syncthreads();

    int v = blockIdx.x*256 + tid;
    if (v < N_NODES) {
        float srs = 0.f, vx = 0.f, vy = 0.f, vz = 0.f;
        #pragma unroll
        for (int p = 0; p < 12; p++) {
            const float* rr = racc + (size_t)(v*12 + p)*4;
            float r0 = rr[0] + rr[2];
            float r1 = rr[1] + rr[3];
            srs += r0;
            vx += r1*ori[3*p]; vy += r1*ori[3*p+1]; vz += r1*ori[3*p+2];
        }
        const float sc = 1.0f/24.0f;
        int g = batch[v];
        atomicAdd(&sAcc[g],            srs*sc);
        atomicAdd(&sAcc[16 + g*3 + 0], vx*sc);
        atomicAdd(&sAcc[16 + g*3 + 1], vy*sc);
        atomicAdd(&sAcc[16 + g*3 + 2], vz*sc);
    }
    __syncthreads();
    if (tid < 64) atomicAdd(&out[tid], sAcc[tid]);
}

extern "C" void kernel_launch(void* const* d_in, const int* in_sizes, int n_in,
                              void* d_out, int out_size, void* d_ws, size_t ws_size,
                              hipStream_t stream) {
    const float* pos    = (const float*)d_in[0];
    const float* f      = (const float*)d_in[1];
    const float* ori    = (const float*)d_in[2];
    const int*   ei     = (const int*)  d_in[3];
    const int*   batch  = (const int*)  d_in[4];
    const float* Wb1    = (const float*)d_in[5];
    const float* bb1    = (const float*)d_in[6];
    const float* Wb2    = (const float*)d_in[7];
    const float* bb2    = (const float*)d_in[8];
    const float* Wo1    = (const float*)d_in[9];
    const float* bo1    = (const float*)d_in[10];
    const float* Wo2    = (const float*)d_in[11];
    const float* bo2    = (const float*)d_in[12];
    const float* We     = (const float*)d_in[13];
    const float* Wk     = (const float*)d_in[14];
    const float* Wf     = (const float*)d_in[15];
    const float* conv_b = (const float*)d_in[16];
    const float* ln_g   = (const float*)d_in[17];
    const float* ln_b   = (const float*)d_in[18];
    const float* W1     = (const float*)d_in[19];
    const float* b1     = (const float*)d_in[20];
    const float* W2     = (const float*)d_in[21];
    const float* b2     = (const float*)d_in[22];
    const float* Wr     = (const float*)d_in[23];
    const float* br     = (const float*)d_in[24];
    float* out = (float*)d_out;

    float* ws   = (float*)d_ws;
    float* xe   = ws;                               //   640,000 f32
    short* xs1b = (short*)(xe + 640000);            // 7,680,000 bf16
    short* x1b  = xs1b + 7680000;                   // 7,680,000 bf16
    float* racc = (float*)(x1b + 7680000);          //   480,000 f32 (layered)
    float* fkb  = racc + 480000;                    //    18,432
    short* w1b  = (short*)(fkb + 18432);            //    32,768 shorts
    short* w2b  = w1b + 32768;
    short* w1k  = w2b + 32768;
    short* w2k  = w1k + 2048;
    short* wkb  = w2k + 4096;
    int*   deg  = (int*)(wkb + 8192);               //    10,000 ints
    int*   rp   = deg + 10000;
    int*   wp   = rp  + 10001;
    int*   perm = wp  + 10000;
    int*   srcOf= perm+ 80000;
    int*   pad_ = srcOf + 80000;
    __hip_bfloat16* akbA = (__hip_bfloat16*)(pad_ + 3);   // 61,440,000 bf16 (~123 MB)
    __hip_bfloat16* akbB = akbA + 61440000;               // second buffer (full mode)

    size_t need_full = ((char*)(akbB + 61440000)) - ((char*)d_ws);
    int full = (ws_size >= need_full) ? 1 : 0;

    hipMemsetAsync(out,  0, 64*sizeof(float), stream);
    hipMemsetAsync(deg,  0, 10000*sizeof(int), stream);

    csr_count<<<313, 256, 0, stream>>>(ei, deg);
    csr_scan <<<1,   256, 0, stream>>>(deg, rp, wp);
    csr_fill <<<313, 256, 0, stream>>>(ei, wp, perm, srcOf);

    prep_weights<<<4,    256, 0, stream>>>(W1, W2, Wb1, Wb2, Wk,
                                           w1b, w2b, w1k, w2k, wkb);
    ori_kernel  <<<144,  64, 0, stream>>>(ori, Wo1, bo1, Wo2, bo2, Wf, fkb);
    embed_kernel<<<2500, 256, 0, stream>>>(f, We, xe);

    if (full) {
        kb_mfma <<<3750, 256, 0, stream>>>(pos, ori, w1k, bb1, w2k, bb2,
                                           wkb, akbA, wkb + 4096, akbB, /*dual=*/1, ei, perm);
        gather0 <<<30000,256, 0, stream>>>(akbA, srcOf, rp, xe, (__hip_bfloat16*)x1b);
        node_mfma<<<1875,256, 0, stream>>>(x1b, fkb, conv_b, ln_g, ln_b,
                                           w1b, b1, w2b, b2, Wr, br,
                                           (const __hip_bfloat16*)xs1b, (__hip_bfloat16*)xs1b,
                                           racc, /*res=*/0, /*write=*/1, /*lay=*/0);
        gather1 <<<30000,256, 0, stream>>>(akbB, srcOf, rp,
                                           (const __hip_bfloat16*)xs1b, (__hip_bfloat16*)x1b);
    } else {
        kb_mfma <<<3750, 256, 0, stream>>>(pos, ori, w1k, bb1, w2k, bb2,
                                           wkb, akbA, wkb, akbA, /*dual=*/0, ei, perm);
        gather0 <<<30000,256, 0, stream>>>(akbA, srcOf, rp, xe, (__hip_bfloat16*)x1b);
        node_mfma<<<1875,256, 0, stream>>>(x1b, fkb, conv_b, ln_g, ln_b,
                                           w1b, b1, w2b, b2, Wr, br,
                                           (const __hip_bfloat16*)xs1b, (__hip_bfloat16*)xs1b,
                                           racc, /*res=*/0, /*write=*/1, /*lay=*/0);
        kb_mfma <<<3750, 256, 0, stream>>>(pos, ori, w1k, bb1, w2k, bb2,
                                           wkb + 4096, akbA, wkb + 4096, akbA, /*dual=*/0, ei, perm);
        gather1 <<<30000,256, 0, stream>>>(akbA, srcOf, rp,
                                           (const __hip_bfloat16*)xs1b, (__hip_bfloat16*)x1b);
    }

    node_mfma   <<<1875, 256, 0, stream>>>(x1b, fkb + 9216, conv_b + 64, ln_g + 64, ln_b + 64,
                                           w1b + 16384, b1 + 256, w2b + 16384, b2 + 64,
                                           Wr + 128, br + 2,
                                           (const __hip_bfloat16*)xs1b, (__hip_bfloat16*)xs1b,
                                           racc, /*res=*/1, /*write=*/0, /*lay=*/1);

    final_kernel<<<40,   256, 0, stream>>>(racc, ori, batch, out);
}

// Round 16
// 701.264 us; speedup vs baseline: 1.8098x; 1.0064x over previous
//
#include <hip/hip_runtime.h>
#include <hip/hip_bf16.h>
#include <math.h>

#define N_NODES 10000
#define N_EDGES 80000
#define N_ORI   12
#define N_ROWS  (N_NODES * N_ORI)

typedef __attribute__((ext_vector_type(8))) short bfrag;   // 8 bf16 = 4 VGPRs
typedef __attribute__((ext_vector_type(4))) float f32x4;

// fast gelu (tanh-approx, overflow-safe); |err| < ~3e-3 < bf16 ulp downstream
__device__ __forceinline__ float gelu_f(float x) {
    float u = 1.5957691216057308f * x * (1.0f + 0.044715f * x * x);
    float e = __expf(-u);
    return x * __builtin_amdgcn_rcpf(1.0f + e);
}
// exact gelu for the tiny f32-precision ori path
__device__ __forceinline__ float gelu_exact(float x) {
    return 0.5f * x * (1.0f + erff(x * 0.70710678118654752440f));
}
__device__ __forceinline__ short f2bf(float x) {
    __hip_bfloat16 h = __float2bfloat16(x);
    return *reinterpret_cast<short*>(&h);
}
__device__ __forceinline__ float bflo(unsigned u) { return __uint_as_float(u << 16); }
__device__ __forceinline__ float bfhi(unsigned u) { return __uint_as_float(u & 0xffff0000u); }

// packed bf16 store: 4 cols / 8 B per quad of lanes -> full 128 B lines
__device__ __forceinline__ void store_bf16_packed(
    __hip_bfloat16* base, int row64, int colBase, int m16, float val)
{
    int my = (int)(unsigned short)f2bf(val);
    int p1 = __shfl_xor(my, 1);
    int packed01 = my | (p1 << 16);
    int p2 = __shfl_xor(packed01, 2);
    if ((m16 & 3) == 0) {
        int2 st; st.x = packed01; st.y = p2;
        *(int2*)((short*)base + (size_t)row64*64 + colBase + m16) = st;
    }
}

// ---------------------------------------------------------------------------
// CSR build (dst-sorted edge list for gathers)
// ---------------------------------------------------------------------------
__global__ __launch_bounds__(256) void csr_count(
    const int* __restrict__ ei, int* __restrict__ deg)
{
    int e = blockIdx.x*256 + threadIdx.x;
    if (e < N_EDGES) atomicAdd(&deg[ei[N_EDGES + e]], 1);
}

__global__ __launch_bounds__(256) void csr_scan(
    const int* __restrict__ deg, int* __restrict__ rp, int* __restrict__ wp)
{
    __shared__ int part[256];
    __shared__ int sbase[257];
    int t = threadIdx.x;
    int cs = t*40;
    int sum = 0;
    for (int i = 0; i < 40; i++) { int idx = cs+i; if (idx < N_NODES) sum += deg[idx]; }
    part[t] = sum;
    __syncthreads();
    if (t == 0) {
        int run = 0;
        for (int i = 0; i < 256; i++) { sbase[i] = run; run += part[i]; }
        sbase[256] = run;
    }
    __syncthreads();
    int run = sbase[t];
    for (int i = 0; i < 40; i++) {
        int idx = cs+i;
        if (idx < N_NODES) { rp[idx] = run; wp[idx] = run; run += deg[idx]; }
    }
    if (t == 0) rp[N_NODES] = sbase[256];
}

__global__ __launch_bounds__(256) void csr_fill(
    const int* __restrict__ ei, int* __restrict__ wp,
    int* __restrict__ perm, int* __restrict__ srcOf)
{
    int e = blockIdx.x*256 + threadIdx.x;
    if (e >= N_EDGES) return;
    int dn = ei[N_EDGES + e];
    int j = atomicAdd(&wp[dn], 1);
    perm[j] = e;
    srcOf[j] = ei[e];
}

// ---------------------------------------------------------------------------
// K0 (fused setup): blocks 0-3 weight prep; 4-39 ori MLP+fk (4 wave-local
// (i,j) pairs per block); 40-2539 embed (4 nodes per block).
// ---------------------------------------------------------------------------
__global__ __launch_bounds__(256) void setup_kernel(
    const float* __restrict__ W1, const float* __restrict__ W2,
    const float* __restrict__ Wb1, const float* __restrict__ Wb2,
    const float* __restrict__ Wk,
    short* __restrict__ W1B, short* __restrict__ W2B,
    short* __restrict__ W1K, short* __restrict__ W2K,
    short* __restrict__ WkB,
    const float* __restrict__ ori, const float* __restrict__ Wo1,
    const float* __restrict__ bo1, const float* __restrict__ Wo2,
    const float* __restrict__ bo2, const float* __restrict__ Wf,
    float* __restrict__ fkb,
    const float* __restrict__ f, const float* __restrict__ We,
    float* __restrict__ xe)
{
    int b = blockIdx.x;
    if (b < 4) {
        if (b < 2) {
            int l = b;
            const float* w1 = W1 + l*16384; short* w1b = W1B + l*16384;
            const float* w2 = W2 + l*16384; short* w2b = W2B + l*16384;
            for (int i = threadIdx.x; i < 16384; i += 256) {
                int k = i >> 8, t = i & 255;
                w1b[t*64 + k] = f2bf(w1[i]);
                int t2 = i >> 6, c = i & 63;
                w2b[c*256 + t2] = f2bf(w2[i]);
            }
        } else if (b == 2) {
            for (int i = threadIdx.x; i < 2048; i += 256) {
                int t = i >> 5, k = i & 31;
                W1K[i] = (k < 30) ? f2bf(Wb1[k*64 + t]) : (short)0;
            }
            for (int i = threadIdx.x; i < 4096; i += 256) {
                int c = i >> 6, t = i & 63;
                W2K[i] = f2bf(Wb2[t*64 + c]);
            }
        } else {
            for (int i = threadIdx.x; i < 8192; i += 256) {
                int l = i >> 12, rem = i & 4095, k = rem >> 6, c = rem & 63;
                WkB[l*4096 + c*64 + k] = f2bf(Wk[l*4096 + k*64 + c]);
            }
        }
    } else if (b < 40) {
        __shared__ float sh[4][64];
        __shared__ float skb[4][64];
        int w = threadIdx.x >> 6, lane = threadIdx.x & 63;
        int p = (b - 4)*4 + w;                      // 0..143
        int i = p / 12, j = p % 12;
        float s = ori[3*i]*ori[3*j] + ori[3*i+1]*ori[3*j+1] + ori[3*i+2]*ori[3*j+2];
        float p1 = s, p2 = s*s, p3 = p2*s, p4 = p3*s;
        float acc = bo1[lane] + p1*Wo1[lane] + p2*Wo1[64+lane] + p3*Wo1[128+lane] + p4*Wo1[192+lane];
        sh[w][lane] = gelu_exact(acc);
        __builtin_amdgcn_wave_barrier();
        float acc2 = bo2[lane];
        #pragma unroll
        for (int k = 0; k < 64; k++) acc2 += sh[w][k] * Wo2[k*64 + lane];
        skb[w][lane] = gelu_exact(acc2);
        __builtin_amdgcn_wave_barrier();
        for (int l = 0; l < 2; l++) {
            float a = 0.f;
            #pragma unroll
            for (int k = 0; k < 64; k++) a += skb[w][k] * Wf[l*4096 + k*64 + lane];
            fkb[l*9216 + i*768 + j*64 + lane] = a;
        }
    } else {
        int v = (b - 40)*4 + (threadIdx.x >> 6);
        int lane = threadIdx.x & 63;
        if (v >= N_NODES) return;
        float acc = 0.f;
        #pragma unroll
        for (int k = 0; k < 16; k++) acc += f[v*16 + k] * We[k*64 + lane];
        xe[v*64 + lane] = acc;
    }
}

// ---------------------------------------------------------------------------
// K3 (v9): kb MLP via MFMA -> akb at dst-sorted index (unchanged from r15)
// ---------------------------------------------------------------------------
#define KB_WREG 4736
__global__ __launch_bounds__(256, 4) void kb_mfma(
    const float* __restrict__ pos, const float* __restrict__ ori,
    const short* __restrict__ W1K, const float* __restrict__ bb1,
    const short* __restrict__ W2K, const float* __restrict__ bb2,
    const short* __restrict__ WkA, __hip_bfloat16* __restrict__ akbA,
    const short* __restrict__ WkB2, __hip_bfloat16* __restrict__ akbB,
    int dual, const int* __restrict__ ei, const int* __restrict__ perm)
{
    __shared__ short sU[4*KB_WREG];

    int tid = threadIdx.x;
    int w = tid >> 6, l = tid & 63;
    short* reg  = sU + w*KB_WREG;
    float* envp = (float*)(reg + 64*72);
    int blockRow = blockIdx.x * 256;

    // ---- Phase A: features (sorted row -> j -> orig edge e = perm[j]) ----
    {
        int row = blockRow + tid;
        int j = row / 12, o = row - j*12;
        int e = perm[j];
        int sn = ei[e], dn = ei[N_EDGES + e];
        float rx = pos[sn*3+0] - pos[dn*3+0];
        float ry = pos[sn*3+1] - pos[dn*3+1];
        float rz = pos[sn*3+2] - pos[dn*3+2];
        float d  = sqrtf(rx*rx + ry*ry + rz*rz);
        float u2 = d*d, u4 = u2*u2, u6 = u4*u2;
        float env = (d < 1.0f) ? (1.0f - 28.0f*u6 + 48.0f*u6*d - 21.0f*u6*u2) : 0.0f;
        envp[l] = env;

        float ox = ori[3*o], oy = ori[3*o+1], oz = ori[3*o+2];
        float a  = rx*ox + ry*oy + rz*oz;
        float qx = rx - a*ox, qy = ry - a*oy, qz = rz - a*oz;
        float b  = sqrtf(qx*qx + qy*qy + qz*qz);

        float fv[32];
        fv[0] = a; fv[1] = b;
        fv[2] = a*a; fv[3] = a*b; fv[4] = b*a; fv[5] = b*b;
        #pragma unroll
        for (int i = 0; i < 4; i++) { fv[6+2*i] = fv[2+i]*a; fv[7+2*i] = fv[2+i]*b; }
        #pragma unroll
        for (int i = 0; i < 8; i++) { fv[14+2*i] = fv[6+i]*a; fv[15+2*i] = fv[6+i]*b; }
        fv[30] = 0.f; fv[31] = 0.f;

        short* dst = reg + l*40;
        #pragma unroll
        for (int blk = 0; blk < 4; blk++) {
            union { short s[8]; int4 v4; } u;
            #pragma unroll
            for (int jj = 0; jj < 8; jj++) u.s[jj] = f2bf(fv[blk*8 + jj]);
            *(int4*)(dst + blk*8) = u.v4;
        }
    }
    __builtin_amdgcn_wave_barrier();

    int m16 = l & 15, q = l >> 4;

    bfrag a1[4];
    #pragma unroll
    for (int mt = 0; mt < 4; mt++)
        a1[mt] = *(const bfrag*)(reg + (mt*16 + m16)*40 + q*8);
    __builtin_amdgcn_wave_barrier();

    // ---- FFN1: K=32 ----
    #pragma unroll
    for (int nt = 0; nt < 4; nt++) {
        bfrag bb = *(const bfrag*)(W1K + (nt*16 + m16)*32 + q*8);
        float bias = bb1[nt*16 + m16];
        #pragma unroll
        for (int mt = 0; mt < 4; mt++) {
            f32x4 acc = (f32x4){0.f,0.f,0.f,0.f};
            acc = __builtin_amdgcn_mfma_f32_16x16x32_bf16(a1[mt], bb, acc, 0, 0, 0);
            #pragma unroll
            for (int r = 0; r < 4; r++) {
                int rl = mt*16 + q*4 + r;
                reg[rl*72 + nt*16 + m16] = f2bf(gelu_f(acc[r] + bias));
            }
        }
    }
    __builtin_amdgcn_wave_barrier();

    // ---- FFN2: K=64 -> kb back into sH ----
    bfrag a2[4][2];
    #pragma unroll
    for (int mt = 0; mt < 4; mt++)
        #pragma unroll
        for (int kc = 0; kc < 2; kc++)
            a2[mt][kc] = *(const bfrag*)(reg + (mt*16 + m16)*72 + kc*32 + q*8);
    __builtin_amdgcn_wave_barrier();

    #pragma unroll
    for (int nt = 0; nt < 4; nt++) {
        f32x4 acc[4];
        #pragma unroll
        for (int mt = 0; mt < 4; mt++) acc[mt] = (f32x4){0.f,0.f,0.f,0.f};
        #pragma unroll
        for (int kc = 0; kc < 2; kc++) {
            bfrag bb = *(const bfrag*)(W2K + (nt*16 + m16)*64 + kc*32 + q*8);
            #pragma unroll
            for (int mt = 0; mt < 4; mt++)
                acc[mt] = __builtin_amdgcn_mfma_f32_16x16x32_bf16(a2[mt][kc], bb, acc[mt], 0, 0, 0);
        }
        float bias = bb2[nt*16 + m16];
        #pragma unroll
        for (int mt = 0; mt < 4; mt++) {
            #pragma unroll
            for (int r = 0; r < 4; r++) {
                int rl = mt*16 + q*4 + r;
                reg[rl*72 + nt*16 + m16] = f2bf(gelu_f(acc[mt][r] + bias) * envp[rl]);
            }
        }
    }
    __builtin_amdgcn_wave_barrier();

    // ---- akb GEMMs + packed coalesced stores (sorted row index) ----
    bfrag a3[4][2];
    #pragma unroll
    for (int mt = 0; mt < 4; mt++)
        #pragma unroll
        for (int kc = 0; kc < 2; kc++)
            a3[mt][kc] = *(const bfrag*)(reg + (mt*16 + m16)*72 + kc*32 + q*8);

    #pragma unroll
    for (int nt = 0; nt < 4; nt++) {
        f32x4 acc[4];
        #pragma unroll
        for (int mt = 0; mt < 4; mt++) acc[mt] = (f32x4){0.f,0.f,0.f,0.f};
        #pragma unroll
        for (int kc = 0; kc < 2; kc++) {
            bfrag bb = *(const bfrag*)(WkA + (nt*16 + m16)*64 + kc*32 + q*8);
            #pragma unroll
            for (int mt = 0; mt < 4; mt++)
                acc[mt] = __builtin_amdgcn_mfma_f32_16x16x32_bf16(a3[mt][kc], bb, acc[mt], 0, 0, 0);
        }
        #pragma unroll
        for (int mt = 0; mt < 4; mt++)
            #pragma unroll
            for (int r = 0; r < 4; r++) {
                int R = blockRow + w*64 + mt*16 + q*4 + r;
                store_bf16_packed(akbA, R, nt*16, m16, acc[mt][r]);
            }
    }
    if (dual) {
        #pragma unroll
        for (int nt = 0; nt < 4; nt++) {
            f32x4 acc[4];
            #pragma unroll
            for (int mt = 0; mt < 4; mt++) acc[mt] = (f32x4){0.f,0.f,0.f,0.f};
            #pragma unroll
            for (int kc = 0; kc < 2; kc++) {
                bfrag bb = *(const bfrag*)(WkB2 + (nt*16 + m16)*64 + kc*32 + q*8);
                #pragma unroll
                for (int mt = 0; mt < 4; mt++)
                    acc[mt] = __builtin_amdgcn_mfma_f32_16x16x32_bf16(a3[mt][kc], bb, acc[mt], 0, 0, 0);
            }
            #pragma unroll
            for (int mt = 0; mt < 4; mt++)
                #pragma unroll
                for (int r = 0; r < 4; r++) {
                    int R = blockRow + w*64 + mt*16 + q*4 + r;
                    store_bf16_packed(akbB, R, nt*16, m16, acc[mt][r]);
                }
        }
    }
}

// ---------------------------------------------------------------------------
// K4a: layer-0 CSR gather — 8-way unrolled (16 outstanding loads/wave).
// ---------------------------------------------------------------------------
__global__ __launch_bounds__(256) void gather0(
    const __hip_bfloat16* __restrict__ akb,
    const int* __restrict__ srcOf, const int* __restrict__ rp,
    const float* __restrict__ xe, __hip_bfloat16* __restrict__ x1)
{
    int w = threadIdx.x >> 6, lane = threadIdx.x & 63;
    int g = blockIdx.x*4 + w;
    int v = g / 12, o = g - v*12;
    int jb = rp[v], je = rp[v+1];
    float acc = 0.f;
    int j = jb;
    for (; j + 7 < je; j += 8) {
        float a[8], x[8];
        #pragma unroll
        for (int ii = 0; ii < 8; ii++)
            a[ii] = __bfloat162float(akb[(size_t)(j+ii)*768 + o*64 + lane]);
        #pragma unroll
        for (int ii = 0; ii < 8; ii++)
            x[ii] = xe[(size_t)srcOf[j+ii]*64 + lane];
        #pragma unroll
        for (int ii = 0; ii < 8; ii++) acc += a[ii]*x[ii];
    }
    for (; j < je; j++) {
        float a0 = __bfloat162float(akb[(size_t)j*768 + o*64 + lane]);
        acc += a0 * xe[(size_t)srcOf[j]*64 + lane];
    }
    x1[(size_t)v*768 + o*64 + lane] = __float2bfloat16(acc);
}

// ---------------------------------------------------------------------------
// K4b: layer-1 CSR gather — 8-way unrolled.
// ---------------------------------------------------------------------------
__global__ __launch_bounds__(256) void gather1(
    const __hip_bfloat16* __restrict__ akb,
    const int* __restrict__ srcOf, const int* __restrict__ rp,
    const __hip_bfloat16* __restrict__ x_in, __hip_bfloat16* __restrict__ x1)
{
    int w = threadIdx.x >> 6, lane = threadIdx.x & 63;
    int g = blockIdx.x*4 + w;
    int v = g / 12, o = g - v*12;
    int jb = rp[v], je = rp[v+1];
    float acc = 0.f;
    int j = jb;
    for (; j + 7 < je; j += 8) {
        float a[8], x[8];
        #pragma unroll
        for (int ii = 0; ii < 8; ii++)
            a[ii] = __bfloat162float(akb[(size_t)(j+ii)*768 + o*64 + lane]);
        #pragma unroll
        for (int ii = 0; ii < 8; ii++)
            x[ii] = __bfloat162float(x_in[(size_t)srcOf[j+ii]*768 + o*64 + lane]);
        #pragma unroll
        for (int ii = 0; ii < 8; ii++) acc += a[ii]*x[ii];
    }
    for (; j < je; j++) {
        float a0 = __bfloat162float(akb[(size_t)j*768 + o*64 + lane]);
        acc += a0 * __bfloat162float(x_in[(size_t)srcOf[j]*768 + o*64 + lane]);
    }
    x1[(size_t)v*768 + o*64 + lane] = __float2bfloat16(acc);
}

// ---------------------------------------------------------------------------
// K5 (v6): node kernel — 64-row blocks; Phase A conv loop force-unrolled.
// ---------------------------------------------------------------------------
#define ND_WREG2 2176
__global__ __launch_bounds__(256, 4) void node_mfma(
    const short* __restrict__ x1, const float* __restrict__ fk,
    const float* __restrict__ conv_b, const float* __restrict__ ln_g,
    const float* __restrict__ ln_b,
    const short* __restrict__ W1B, const float* __restrict__ b1,
    const short* __restrict__ W2B, const float* __restrict__ pb2,
    const float* __restrict__ Wr, const float* __restrict__ br,
    const __hip_bfloat16* __restrict__ x_old, __hip_bfloat16* __restrict__ x_new,
    float* __restrict__ racc, int has_res, int write_x, int lay)
{
    __shared__ short sU[4*ND_WREG2];

    int tid = threadIdx.x;
    int w   = tid >> 6;
    int blockRow = blockIdx.x * 64;
    short* reg = sU + w*ND_WREG2;

    // ---- Phase A: conv + LN, quarter-row (16 cols) per thread ----
    {
        int rl = tid >> 2;
        int qt = tid & 3;
        int lr = rl - 16*w;
        int row = blockRow + rl;
        int rc = row < N_ROWS ? row : N_ROWS - 1;
        int v = rc / 12, pp = rc % 12;
        float h[16];
        #pragma unroll
        for (int k = 0; k < 16; k++) h[k] = 0.f;
        const short* xv = x1 + (size_t)v*768 + qt*16;
        const float* fp = fk + (size_t)pp*768 + qt*16;
        #pragma unroll
        for (int o = 0; o < 12; o++) {
            const int4*  xa = (const int4*)(xv + o*64);
            const float4* fa = (const float4*)(fp + o*64);
            #pragma unroll
            for (int k4 = 0; k4 < 2; k4++) {
                int4 xi = xa[k4];
                float4 f0 = fa[2*k4], f1 = fa[2*k4+1];
                h[8*k4+0] += bflo((unsigned)xi.x)*f0.x; h[8*k4+1] += bfhi((unsigned)xi.x)*f0.y;
                h[8*k4+2] += bflo((unsigned)xi.y)*f0.z; h[8*k4+3] += bfhi((unsigned)xi.y)*f0.w;
                h[8*k4+4] += bflo((unsigned)xi.z)*f1.x; h[8*k4+5] += bfhi((unsigned)xi.z)*f1.y;
                h[8*k4+6] += bflo((unsigned)xi.w)*f1.z; h[8*k4+7] += bfhi((unsigned)xi.w)*f1.w;
            }
        }
        const float inv12 = 1.0f/12.0f;
        float sum = 0.f;
        #pragma unroll
        for (int k = 0; k < 16; k++) { h[k] = h[k]*inv12 + conv_b[qt*16 + k]; sum += h[k]; }
        sum += __shfl_xor(sum, 1);
        sum += __shfl_xor(sum, 2);
        float mu = sum * (1.0f/64.0f);
        float var = 0.f;
        #pragma unroll
        for (int k = 0; k < 16; k++) { float xc = h[k] - mu; var += xc*xc; }
        var += __shfl_xor(var, 1);
        var += __shfl_xor(var, 2);
        float rstd = rsqrtf(var*(1.0f/64.0f) + 1e-5f);
        short* dst = reg + lr*72 + qt*16;
        #pragma unroll
        for (int blk = 0; blk < 2; blk++) {
            union { short s[8]; int4 v4; } u;
            #pragma unroll
            for (int jj = 0; jj < 8; jj++) {
                int k = blk*8 + jj, c = qt*16 + k;
                u.s[jj] = f2bf((h[k] - mu)*rstd*ln_g[c] + ln_b[c]);
            }
            *(int4*)(dst + blk*8) = u.v4;
        }
    }
    __builtin_amdgcn_wave_barrier();

    int l   = tid & 63;
    int m16 = l & 15, q = l >> 4;

    bfrag a1[2];
    #pragma unroll
    for (int kc = 0; kc < 2; kc++)
        a1[kc] = *(const bfrag*)(reg + m16*72 + kc*32 + q*8);
    __builtin_amdgcn_wave_barrier();

    f32x4 acc2[4];
    #pragma unroll
    for (int n = 0; n < 4; n++) acc2[n] = (f32x4){0.f, 0.f, 0.f, 0.f};

    for (int ph = 0; ph < 2; ph++) {
        for (int ntl = 0; ntl < 8; ntl++) {
            int nt = ph*8 + ntl;
            f32x4 c0 = (f32x4){0.f,0.f,0.f,0.f};
            #pragma unroll
            for (int kc = 0; kc < 2; kc++) {
                bfrag bb = *(const bfrag*)(W1B + (nt*16 + m16)*64 + kc*32 + q*8);
                c0 = __builtin_amdgcn_mfma_f32_16x16x32_bf16(a1[kc], bb, c0, 0, 0, 0);
            }
            float bias = b1[nt*16 + m16];
            #pragma unroll
            for (int r = 0; r < 4; r++)
                reg[(q*4 + r)*136 + ntl*16 + m16] = f2bf(gelu_f(c0[r] + bias));
        }
        __builtin_amdgcn_wave_barrier();
        for (int kc2 = 0; kc2 < 4; kc2++) {
            bfrag a2 = *(const bfrag*)(reg + m16*136 + kc2*32 + q*8);
            #pragma unroll
            for (int nc = 0; nc < 4; nc++) {
                bfrag bb = *(const bfrag*)(W2B + (nc*16 + m16)*256 + ph*128 + kc2*32 + q*8);
                acc2[nc] = __builtin_amdgcn_mfma_f32_16x16x32_bf16(a2, bb, acc2[nc], 0, 0, 0);
            }
        }
        __builtin_amdgcn_wave_barrier();
    }

    // ---- Epilogue ----
    float p0[4], p1[4];
    #pragma unroll
    for (int r = 0; r < 4; r++) {
        int rowl = 16*w + q*4 + r;
        int row  = blockRow + rowl;
        bool ok  = row < N_ROWS;
        float vals[4];
        #pragma unroll
        for (int nc = 0; nc < 4; nc++) vals[nc] = acc2[nc][r] + pb2[nc*16 + m16];
        if (has_res && ok) {
            #pragma unroll
            for (int nc = 0; nc < 4; nc++)
                vals[nc] += __bfloat162float(x_old[(size_t)row*64 + nc*16 + m16]);
        }
        if (write_x && ok) {
            #pragma unroll
            for (int nc = 0; nc < 4; nc++)
                store_bf16_packed(x_new, row, nc*16, m16, vals[nc]);
        }
        float q0 = 0.f, q1 = 0.f;
        #pragma unroll
        for (int nc = 0; nc < 4; nc++) {
            int c = nc*16 + m16;
            q0 += vals[nc]*Wr[2*c];
            q1 += vals[nc]*Wr[2*c + 1];
        }
        p0[r] = q0; p1[r] = q1;
    }
    #pragma unroll
    for (int s = 1; s < 16; s <<= 1) {
        #pragma unroll
        for (int r = 0; r < 4; r++) {
            p0[r] += __shfl_xor(p0[r], s);
            p1[r] += __shfl_xor(p1[r], s);
        }
    }
    if (m16 == 0) {
        #pragma unroll
        for (int r = 0; r < 4; r++) {
            int row = blockRow + 16*w + q*4 + r;
            if (row < N_ROWS) {
                racc[(size_t)row*4 + lay*2 + 0] = p0[r] + br[0];
                racc[(size_t)row*4 + lay*2 + 1] = p1[r] + br[1];
            }
        }
    }
}

// ---------------------------------------------------------------------------
// K6 (v3): readout — layer-separated racc, two-stage reduction (unchanged)
// ---------------------------------------------------------------------------
__global__ __launch_bounds__(256) void final_kernel(
    const float* __restrict__ racc, const float* __restrict__ ori,
    const int* __restrict__ batch, float* __restrict__ out)
{
    __shared__ float sAcc[64];
    int tid = threadIdx.x;
    if (tid < 64) sAcc[tid] = 0.f;
    __syncthreads();

    int v = blockIdx.x*256 + tid;
    if (v < N_NODES) {
        float srs = 0.f, vx = 0.f, vy = 0.f, vz = 0.f;
        #pragma unroll
        for (int p = 0; p < 12; p++) {
            const float* rr = racc + (size_t)(v*12 + p)*4;
            float r0 = rr[0] + rr[2];
            float r1 = rr[1] + rr[3];
            srs += r0;
            vx += r1*ori[3*p]; vy += r1*ori[3*p+1]; vz += r1*ori[3*p+2];
        }
        const float sc = 1.0f/24.0f;
        int g = batch[v];
        atomicAdd(&sAcc[g],            srs*sc);
        atomicAdd(&sAcc[16 + g*3 + 0], vx*sc);
        atomicAdd(&sAcc[16 + g*3 + 1], vy*sc);
        atomicAdd(&sAcc[16 + g*3 + 2], vz*sc);
    }
    __syncthreads();
    if (tid < 64) atomicAdd(&out[tid], sAcc[tid]);
}

extern "C" void kernel_launch(void* const* d_in, const int* in_sizes, int n_in,
                              void* d_out, int out_size, void* d_ws, size_t ws_size,
                              hipStream_t stream) {
    const float* pos    = (const float*)d_in[0];
    const float* f      = (const float*)d_in[1];
    const float* ori    = (const float*)d_in[2];
    const int*   ei     = (const int*)  d_in[3];
    const int*   batch  = (const int*)  d_in[4];
    const float* Wb1    = (const float*)d_in[5];
    const float* bb1    = (const float*)d_in[6];
    const float* Wb2    = (const float*)d_in[7];
    const float* bb2    = (const float*)d_in[8];
    const float* Wo1    = (const float*)d_in[9];
    const float* bo1    = (const float*)d_in[10];
    const float* Wo2    = (const float*)d_in[11];
    const float* bo2    = (const float*)d_in[12];
    const float* We     = (const float*)d_in[13];
    const float* Wk     = (const float*)d_in[14];
    const float* Wf     = (const float*)d_in[15];
    const float* conv_b = (const float*)d_in[16];
    const float* ln_g   = (const float*)d_in[17];
    const float* ln_b   = (const float*)d_in[18];
    const float* W1     = (const float*)d_in[19];
    const float* b1     = (const float*)d_in[20];
    const float* W2     = (const float*)d_in[21];
    const float* b2     = (const float*)d_in[22];
    const float* Wr     = (const float*)d_in[23];
    const float* br     = (const float*)d_in[24];
    float* out = (float*)d_out;

    float* ws   = (float*)d_ws;
    float* xe   = ws;                               //   640,000 f32
    short* xs1b = (short*)(xe + 640000);            // 7,680,000 bf16
    short* x1b  = xs1b + 7680000;                   // 7,680,000 bf16
    float* racc = (float*)(x1b + 7680000);          //   480,000 f32 (layered)
    float* fkb  = racc + 480000;                    //    18,432
    short* w1b  = (short*)(fkb + 18432);            //    32,768 shorts
    short* w2b  = w1b + 32768;
    short* w1k  = w2b + 32768;
    short* w2k  = w1k + 2048;
    short* wkb  = w2k + 4096;
    int*   deg  = (int*)(wkb + 8192);               //    10,000 ints
    int*   rp   = deg + 10000;
    int*   wp   = rp  + 10001;
    int*   perm = wp  + 10000;
    int*   srcOf= perm+ 80000;
    int*   pad_ = srcOf + 80000;
    __hip_bfloat16* akbA = (__hip_bfloat16*)(pad_ + 3);   // 61,440,000 bf16 (~123 MB)
    __hip_bfloat16* akbB = akbA + 61440000;               // second buffer (full mode)

    size_t need_full = ((char*)(akbB + 61440000)) - ((char*)d_ws);
    int full = (ws_size >= need_full) ? 1 : 0;

    hipMemsetAsync(out,  0, 64*sizeof(float), stream);
    hipMemsetAsync(deg,  0, 10000*sizeof(int), stream);

    csr_count<<<313, 256, 0, stream>>>(ei, deg);
    csr_scan <<<1,   256, 0, stream>>>(deg, rp, wp);
    csr_fill <<<313, 256, 0, stream>>>(ei, wp, perm, srcOf);

    setup_kernel<<<2540, 256, 0, stream>>>(W1, W2, Wb1, Wb2, Wk,
                                           w1b, w2b, w1k, w2k, wkb,
                                           ori, Wo1, bo1, Wo2, bo2, Wf, fkb,
                                           f, We, xe);

    if (full) {
        kb_mfma <<<3750, 256, 0, stream>>>(pos, ori, w1k, bb1, w2k, bb2,
                                           wkb, akbA, wkb + 4096, akbB, /*dual=*/1, ei, perm);
        gather0 <<<30000,256, 0, stream>>>(akbA, srcOf, rp, xe, (__hip_bfloat16*)x1b);
        node_mfma<<<1875,256, 0, stream>>>(x1b, fkb, conv_b, ln_g, ln_b,
                                           w1b, b1, w2b, b2, Wr, br,
                                           (const __hip_bfloat16*)xs1b, (__hip_bfloat16*)xs1b,
                                           racc, /*res=*/0, /*write=*/1, /*lay=*/0);
        gather1 <<<30000,256, 0, stream>>>(akbB, srcOf, rp,
                                           (const __hip_bfloat16*)xs1b, (__hip_bfloat16*)x1b);
    } else {
        kb_mfma <<<3750, 256, 0, stream>>>(pos, ori, w1k, bb1, w2k, bb2,
                                           wkb, akbA, wkb, akbA, /*dual=*/0, ei, perm);
        gather0 <<<30000,256, 0, stream>>>(akbA, srcOf, rp, xe, (__hip_bfloat16*)x1b);
        node_mfma<<<1875,256, 0, stream>>>(x1b, fkb, conv_b, ln_g, ln_b,
                                           w1b, b1, w2b, b2, Wr, br,
                                           (const __hip_bfloat16*)xs1b, (__hip_bfloat16*)xs1b,
                                           racc, /*res=*/0, /*write=*/1, /*lay=*/0);
        kb_mfma <<<3750, 256, 0, stream>>>(pos, ori, w1k, bb1, w2k, bb2,
                                           wkb + 4096, akbA, wkb + 4096, akbA, /*dual=*/0, ei, perm);
        gather1 <<<30000,256, 0, stream>>>(akbA, srcOf, rp,
                                           (const __hip_bfloat16*)xs1b, (__hip_bfloat16*)x1b);
    }

    node_mfma   <<<1875, 256, 0, stream>>>(x1b, fkb + 9216, conv_b + 64, ln_g + 64, ln_b + 64,
                                           w1b + 16384, b1 + 256, w2b + 16384, b2 + 64,
                                           Wr + 128, br + 2,
                                           (const __hip_bfloat16*)xs1b, (__hip_bfloat16*)xs1b,
                                           racc, /*res=*/1, /*write=*/0, /*lay=*/1);

    final_kernel<<<40,   256, 0, stream>>>(racc, ori, batch, out);
}

// Round 17
// 694.920 us; speedup vs baseline: 1.8264x; 1.0091x over previous
//
#include <hip/hip_runtime.h>
#include <hip/hip_bf16.h>
#include <math.h>

#define N_NODES 10000
#define N_EDGES 80000
#define N_ORI   12
#define N_ROWS  (N_NODES * N_ORI)

typedef __attribute__((ext_vector_type(8))) short bfrag;   // 8 bf16 = 4 VGPRs
typedef __attribute__((ext_vector_type(4))) float f32x4;

// fast gelu (tanh-approx, overflow-safe); |err| < ~3e-3 < bf16 ulp downstream
__device__ __forceinline__ float gelu_f(float x) {
    float u = 1.5957691216057308f * x * (1.0f + 0.044715f * x * x);
    float e = __expf(-u);
    return x * __builtin_amdgcn_rcpf(1.0f + e);
}
// exact gelu for the tiny f32-precision ori path
__device__ __forceinline__ float gelu_exact(float x) {
    return 0.5f * x * (1.0f + erff(x * 0.70710678118654752440f));
}
__device__ __forceinline__ short f2bf(float x) {
    __hip_bfloat16 h = __float2bfloat16(x);
    return *reinterpret_cast<short*>(&h);
}
__device__ __forceinline__ float bflo(unsigned u) { return __uint_as_float(u << 16); }
__device__ __forceinline__ float bfhi(unsigned u) { return __uint_as_float(u & 0xffff0000u); }

// packed bf16 store: 4 cols / 8 B per quad of lanes -> full 128 B lines
__device__ __forceinline__ void store_bf16_packed(
    __hip_bfloat16* base, int row64, int colBase, int m16, float val)
{
    int my = (int)(unsigned short)f2bf(val);
    int p1 = __shfl_xor(my, 1);
    int packed01 = my | (p1 << 16);
    int p2 = __shfl_xor(packed01, 2);
    if ((m16 & 3) == 0) {
        int2 st; st.x = packed01; st.y = p2;
        *(int2*)((short*)base + (size_t)row64*64 + colBase + m16) = st;
    }
}

// ---------------------------------------------------------------------------
// CSR build (dst-sorted edge list for gathers)
// ---------------------------------------------------------------------------
__global__ __launch_bounds__(256) void csr_count(
    const int* __restrict__ ei, int* __restrict__ deg)
{
    int e = blockIdx.x*256 + threadIdx.x;
    if (e < N_EDGES) atomicAdd(&deg[ei[N_EDGES + e]], 1);
}

__global__ __launch_bounds__(256) void csr_scan(
    const int* __restrict__ deg, int* __restrict__ rp, int* __restrict__ wp)
{
    __shared__ int part[256];
    __shared__ int sbase[257];
    int t = threadIdx.x;
    int cs = t*40;
    int sum = 0;
    for (int i = 0; i < 40; i++) { int idx = cs+i; if (idx < N_NODES) sum += deg[idx]; }
    part[t] = sum;
    __syncthreads();
    if (t == 0) {
        int run = 0;
        for (int i = 0; i < 256; i++) { sbase[i] = run; run += part[i]; }
        sbase[256] = run;
    }
    __syncthreads();
    int run = sbase[t];
    for (int i = 0; i < 40; i++) {
        int idx = cs+i;
        if (idx < N_NODES) { rp[idx] = run; wp[idx] = run; run += deg[idx]; }
    }
    if (t == 0) rp[N_NODES] = sbase[256];
}

__global__ __launch_bounds__(256) void csr_fill(
    const int* __restrict__ ei, int* __restrict__ wp,
    int* __restrict__ perm, int* __restrict__ srcOf)
{
    int e = blockIdx.x*256 + threadIdx.x;
    if (e >= N_EDGES) return;
    int dn = ei[N_EDGES + e];
    int j = atomicAdd(&wp[dn], 1);
    perm[j] = e;
    srcOf[j] = ei[e];
}

// ---------------------------------------------------------------------------
// K0 (fused setup): blocks 0-3 weight prep; 4-39 ori MLP+fk; 40-2539 embed.
// ---------------------------------------------------------------------------
__global__ __launch_bounds__(256) void setup_kernel(
    const float* __restrict__ W1, const float* __restrict__ W2,
    const float* __restrict__ Wb1, const float* __restrict__ Wb2,
    const float* __restrict__ Wk,
    short* __restrict__ W1B, short* __restrict__ W2B,
    short* __restrict__ W1K, short* __restrict__ W2K,
    short* __restrict__ WkB,
    const float* __restrict__ ori, const float* __restrict__ Wo1,
    const float* __restrict__ bo1, const float* __restrict__ Wo2,
    const float* __restrict__ bo2, const float* __restrict__ Wf,
    float* __restrict__ fkb,
    const float* __restrict__ f, const float* __restrict__ We,
    float* __restrict__ xe)
{
    int b = blockIdx.x;
    if (b < 4) {
        if (b < 2) {
            int l = b;
            const float* w1 = W1 + l*16384; short* w1b = W1B + l*16384;
            const float* w2 = W2 + l*16384; short* w2b = W2B + l*16384;
            for (int i = threadIdx.x; i < 16384; i += 256) {
                int k = i >> 8, t = i & 255;
                w1b[t*64 + k] = f2bf(w1[i]);
                int t2 = i >> 6, c = i & 63;
                w2b[c*256 + t2] = f2bf(w2[i]);
            }
        } else if (b == 2) {
            for (int i = threadIdx.x; i < 2048; i += 256) {
                int t = i >> 5, k = i & 31;
                W1K[i] = (k < 30) ? f2bf(Wb1[k*64 + t]) : (short)0;
            }
            for (int i = threadIdx.x; i < 4096; i += 256) {
                int c = i >> 6, t = i & 63;
                W2K[i] = f2bf(Wb2[t*64 + c]);
            }
        } else {
            for (int i = threadIdx.x; i < 8192; i += 256) {
                int l = i >> 12, rem = i & 4095, k = rem >> 6, c = rem & 63;
                WkB[l*4096 + c*64 + k] = f2bf(Wk[l*4096 + k*64 + c]);
            }
        }
    } else if (b < 40) {
        __shared__ float sh[4][64];
        __shared__ float skb[4][64];
        int w = threadIdx.x >> 6, lane = threadIdx.x & 63;
        int p = (b - 4)*4 + w;                      // 0..143
        int i = p / 12, j = p % 12;
        float s = ori[3*i]*ori[3*j] + ori[3*i+1]*ori[3*j+1] + ori[3*i+2]*ori[3*j+2];
        float p1 = s, p2 = s*s, p3 = p2*s, p4 = p3*s;
        float acc = bo1[lane] + p1*Wo1[lane] + p2*Wo1[64+lane] + p3*Wo1[128+lane] + p4*Wo1[192+lane];
        sh[w][lane] = gelu_exact(acc);
        __builtin_amdgcn_wave_barrier();
        float acc2 = bo2[lane];
        #pragma unroll
        for (int k = 0; k < 64; k++) acc2 += sh[w][k] * Wo2[k*64 + lane];
        skb[w][lane] = gelu_exact(acc2);
        __builtin_amdgcn_wave_barrier();
        for (int l = 0; l < 2; l++) {
            float a = 0.f;
            #pragma unroll
            for (int k = 0; k < 64; k++) a += skb[w][k] * Wf[l*4096 + k*64 + lane];
            fkb[l*9216 + i*768 + j*64 + lane] = a;
        }
    } else {
        int v = (b - 40)*4 + (threadIdx.x >> 6);
        int lane = threadIdx.x & 63;
        if (v >= N_NODES) return;
        float acc = 0.f;
        #pragma unroll
        for (int k = 0; k < 16; k++) acc += f[v*16 + k] * We[k*64 + lane];
        xe[v*64 + lane] = acc;
    }
}

// ---------------------------------------------------------------------------
// K3 (v9): kb MLP via MFMA -> akb at dst-sorted index (unchanged)
// ---------------------------------------------------------------------------
#define KB_WREG 4736
__global__ __launch_bounds__(256, 4) void kb_mfma(
    const float* __restrict__ pos, const float* __restrict__ ori,
    const short* __restrict__ W1K, const float* __restrict__ bb1,
    const short* __restrict__ W2K, const float* __restrict__ bb2,
    const short* __restrict__ WkA, __hip_bfloat16* __restrict__ akbA,
    const short* __restrict__ WkB2, __hip_bfloat16* __restrict__ akbB,
    int dual, const int* __restrict__ ei, const int* __restrict__ perm)
{
    __shared__ short sU[4*KB_WREG];

    int tid = threadIdx.x;
    int w = tid >> 6, l = tid & 63;
    short* reg  = sU + w*KB_WREG;
    float* envp = (float*)(reg + 64*72);
    int blockRow = blockIdx.x * 256;

    // ---- Phase A: features (sorted row -> j -> orig edge e = perm[j]) ----
    {
        int row = blockRow + tid;
        int j = row / 12, o = row - j*12;
        int e = perm[j];
        int sn = ei[e], dn = ei[N_EDGES + e];
        float rx = pos[sn*3+0] - pos[dn*3+0];
        float ry = pos[sn*3+1] - pos[dn*3+1];
        float rz = pos[sn*3+2] - pos[dn*3+2];
        float d  = sqrtf(rx*rx + ry*ry + rz*rz);
        float u2 = d*d, u4 = u2*u2, u6 = u4*u2;
        float env = (d < 1.0f) ? (1.0f - 28.0f*u6 + 48.0f*u6*d - 21.0f*u6*u2) : 0.0f;
        envp[l] = env;

        float ox = ori[3*o], oy = ori[3*o+1], oz = ori[3*o+2];
        float a  = rx*ox + ry*oy + rz*oz;
        float qx = rx - a*ox, qy = ry - a*oy, qz = rz - a*oz;
        float b  = sqrtf(qx*qx + qy*qy + qz*qz);

        float fv[32];
        fv[0] = a; fv[1] = b;
        fv[2] = a*a; fv[3] = a*b; fv[4] = b*a; fv[5] = b*b;
        #pragma unroll
        for (int i = 0; i < 4; i++) { fv[6+2*i] = fv[2+i]*a; fv[7+2*i] = fv[2+i]*b; }
        #pragma unroll
        for (int i = 0; i < 8; i++) { fv[14+2*i] = fv[6+i]*a; fv[15+2*i] = fv[6+i]*b; }
        fv[30] = 0.f; fv[31] = 0.f;

        short* dst = reg + l*40;
        #pragma unroll
        for (int blk = 0; blk < 4; blk++) {
            union { short s[8]; int4 v4; } u;
            #pragma unroll
            for (int jj = 0; jj < 8; jj++) u.s[jj] = f2bf(fv[blk*8 + jj]);
            *(int4*)(dst + blk*8) = u.v4;
        }
    }
    __builtin_amdgcn_wave_barrier();

    int m16 = l & 15, q = l >> 4;

    bfrag a1[4];
    #pragma unroll
    for (int mt = 0; mt < 4; mt++)
        a1[mt] = *(const bfrag*)(reg + (mt*16 + m16)*40 + q*8);
    __builtin_amdgcn_wave_barrier();

    // ---- FFN1: K=32 ----
    #pragma unroll
    for (int nt = 0; nt < 4; nt++) {
        bfrag bb = *(const bfrag*)(W1K + (nt*16 + m16)*32 + q*8);
        float bias = bb1[nt*16 + m16];
        #pragma unroll
        for (int mt = 0; mt < 4; mt++) {
            f32x4 acc = (f32x4){0.f,0.f,0.f,0.f};
            acc = __builtin_amdgcn_mfma_f32_16x16x32_bf16(a1[mt], bb, acc, 0, 0, 0);
            #pragma unroll
            for (int r = 0; r < 4; r++) {
                int rl = mt*16 + q*4 + r;
                reg[rl*72 + nt*16 + m16] = f2bf(gelu_f(acc[r] + bias));
            }
        }
    }
    __builtin_amdgcn_wave_barrier();

    // ---- FFN2: K=64 -> kb back into sH ----
    bfrag a2[4][2];
    #pragma unroll
    for (int mt = 0; mt < 4; mt++)
        #pragma unroll
        for (int kc = 0; kc < 2; kc++)
            a2[mt][kc] = *(const bfrag*)(reg + (mt*16 + m16)*72 + kc*32 + q*8);
    __builtin_amdgcn_wave_barrier();

    #pragma unroll
    for (int nt = 0; nt < 4; nt++) {
        f32x4 acc[4];
        #pragma unroll
        for (int mt = 0; mt < 4; mt++) acc[mt] = (f32x4){0.f,0.f,0.f,0.f};
        #pragma unroll
        for (int kc = 0; kc < 2; kc++) {
            bfrag bb = *(const bfrag*)(W2K + (nt*16 + m16)*64 + kc*32 + q*8);
            #pragma unroll
            for (int mt = 0; mt < 4; mt++)
                acc[mt] = __builtin_amdgcn_mfma_f32_16x16x32_bf16(a2[mt][kc], bb, acc[mt], 0, 0, 0);
        }
        float bias = bb2[nt*16 + m16];
        #pragma unroll
        for (int mt = 0; mt < 4; mt++) {
            #pragma unroll
            for (int r = 0; r < 4; r++) {
                int rl = mt*16 + q*4 + r;
                reg[rl*72 + nt*16 + m16] = f2bf(gelu_f(acc[mt][r] + bias) * envp[rl]);
            }
        }
    }
    __builtin_amdgcn_wave_barrier();

    // ---- akb GEMMs + packed coalesced stores (sorted row index) ----
    bfrag a3[4][2];
    #pragma unroll
    for (int mt = 0; mt < 4; mt++)
        #pragma unroll
        for (int kc = 0; kc < 2; kc++)
            a3[mt][kc] = *(const bfrag*)(reg + (mt*16 + m16)*72 + kc*32 + q*8);

    #pragma unroll
    for (int nt = 0; nt < 4; nt++) {
        f32x4 acc[4];
        #pragma unroll
        for (int mt = 0; mt < 4; mt++) acc[mt] = (f32x4){0.f,0.f,0.f,0.f};
        #pragma unroll
        for (int kc = 0; kc < 2; kc++) {
            bfrag bb = *(const bfrag*)(WkA + (nt*16 + m16)*64 + kc*32 + q*8);
            #pragma unroll
            for (int mt = 0; mt < 4; mt++)
                acc[mt] = __builtin_amdgcn_mfma_f32_16x16x32_bf16(a3[mt][kc], bb, acc[mt], 0, 0, 0);
        }
        #pragma unroll
        for (int mt = 0; mt < 4; mt++)
            #pragma unroll
            for (int r = 0; r < 4; r++) {
                int R = blockRow + w*64 + mt*16 + q*4 + r;
                store_bf16_packed(akbA, R, nt*16, m16, acc[mt][r]);
            }
    }
    if (dual) {
        #pragma unroll
        for (int nt = 0; nt < 4; nt++) {
            f32x4 acc[4];
            #pragma unroll
            for (int mt = 0; mt < 4; mt++) acc[mt] = (f32x4){0.f,0.f,0.f,0.f};
            #pragma unroll
            for (int kc = 0; kc < 2; kc++) {
                bfrag bb = *(const bfrag*)(WkB2 + (nt*16 + m16)*64 + kc*32 + q*8);
                #pragma unroll
                for (int mt = 0; mt < 4; mt++)
                    acc[mt] = __builtin_amdgcn_mfma_f32_16x16x32_bf16(a3[mt][kc], bb, acc[mt], 0, 0, 0);
            }
            #pragma unroll
            for (int mt = 0; mt < 4; mt++)
                #pragma unroll
                for (int r = 0; r < 4; r++) {
                    int R = blockRow + w*64 + mt*16 + q*4 + r;
                    store_bf16_packed(akbB, R, nt*16, m16, acc[mt][r]);
                }
        }
    }
}

// ---------------------------------------------------------------------------
// K4a: layer-0 CSR gather — 8-way unrolled, max-occupancy hint.
// ---------------------------------------------------------------------------
__global__ __launch_bounds__(256, 8) void gather0(
    const __hip_bfloat16* __restrict__ akb,
    const int* __restrict__ srcOf, const int* __restrict__ rp,
    const float* __restrict__ xe, __hip_bfloat16* __restrict__ x1)
{
    int w = threadIdx.x >> 6, lane = threadIdx.x & 63;
    int g = blockIdx.x*4 + w;
    int v = g / 12, o = g - v*12;
    int jb = rp[v], je = rp[v+1];
    float acc = 0.f;
    int j = jb;
    for (; j + 7 < je; j += 8) {
        float a[8], x[8];
        #pragma unroll
        for (int ii = 0; ii < 8; ii++)
            a[ii] = __bfloat162float(akb[(size_t)(j+ii)*768 + o*64 + lane]);
        #pragma unroll
        for (int ii = 0; ii < 8; ii++)
            x[ii] = xe[(size_t)srcOf[j+ii]*64 + lane];
        #pragma unroll
        for (int ii = 0; ii < 8; ii++) acc += a[ii]*x[ii];
    }
    for (; j < je; j++) {
        float a0 = __bfloat162float(akb[(size_t)j*768 + o*64 + lane]);
        acc += a0 * xe[(size_t)srcOf[j]*64 + lane];
    }
    x1[(size_t)v*768 + o*64 + lane] = __float2bfloat16(acc);
}

// ---------------------------------------------------------------------------
// K4b: layer-1 CSR gather — 8-way unrolled, max-occupancy hint.
// ---------------------------------------------------------------------------
__global__ __launch_bounds__(256, 8) void gather1(
    const __hip_bfloat16* __restrict__ akb,
    const int* __restrict__ srcOf, const int* __restrict__ rp,
    const __hip_bfloat16* __restrict__ x_in, __hip_bfloat16* __restrict__ x1)
{
    int w = threadIdx.x >> 6, lane = threadIdx.x & 63;
    int g = blockIdx.x*4 + w;
    int v = g / 12, o = g - v*12;
    int jb = rp[v], je = rp[v+1];
    float acc = 0.f;
    int j = jb;
    for (; j + 7 < je; j += 8) {
        float a[8], x[8];
        #pragma unroll
        for (int ii = 0; ii < 8; ii++)
            a[ii] = __bfloat162float(akb[(size_t)(j+ii)*768 + o*64 + lane]);
        #pragma unroll
        for (int ii = 0; ii < 8; ii++)
            x[ii] = __bfloat162float(x_in[(size_t)srcOf[j+ii]*768 + o*64 + lane]);
        #pragma unroll
        for (int ii = 0; ii < 8; ii++) acc += a[ii]*x[ii];
    }
    for (; j < je; j++) {
        float a0 = __bfloat162float(akb[(size_t)j*768 + o*64 + lane]);
        acc += a0 * __bfloat162float(x_in[(size_t)srcOf[j]*768 + o*64 + lane]);
    }
    x1[(size_t)v*768 + o*64 + lane] = __float2bfloat16(acc);
}

// ---------------------------------------------------------------------------
// K5 (v7): node kernel — 64-row blocks; occupancy raised 4 -> 8 blocks/CU
// (LDS 17.4 KB allows 9; VGPR target 64). Watch VGPR_Count for spills.
// ---------------------------------------------------------------------------
#define ND_WREG2 2176
__global__ __launch_bounds__(256, 8) void node_mfma(
    const short* __restrict__ x1, const float* __restrict__ fk,
    const float* __restrict__ conv_b, const float* __restrict__ ln_g,
    const float* __restrict__ ln_b,
    const short* __restrict__ W1B, const float* __restrict__ b1,
    const short* __restrict__ W2B, const float* __restrict__ pb2,
    const float* __restrict__ Wr, const float* __restrict__ br,
    const __hip_bfloat16* __restrict__ x_old, __hip_bfloat16* __restrict__ x_new,
    float* __restrict__ racc, int has_res, int write_x, int lay)
{
    __shared__ short sU[4*ND_WREG2];

    int tid = threadIdx.x;
    int w   = tid >> 6;
    int blockRow = blockIdx.x * 64;
    short* reg = sU + w*ND_WREG2;

    // ---- Phase A: conv + LN, quarter-row (16 cols) per thread ----
    {
        int rl = tid >> 2;
        int qt = tid & 3;
        int lr = rl - 16*w;
        int row = blockRow + rl;
        int rc = row < N_ROWS ? row : N_ROWS - 1;
        int v = rc / 12, pp = rc % 12;
        float h[16];
        #pragma unroll
        for (int k = 0; k < 16; k++) h[k] = 0.f;
        const short* xv = x1 + (size_t)v*768 + qt*16;
        const float* fp = fk + (size_t)pp*768 + qt*16;
        #pragma unroll
        for (int o = 0; o < 12; o++) {
            const int4*  xa = (const int4*)(xv + o*64);
            const float4* fa = (const float4*)(fp + o*64);
            #pragma unroll
            for (int k4 = 0; k4 < 2; k4++) {
                int4 xi = xa[k4];
                float4 f0 = fa[2*k4], f1 = fa[2*k4+1];
                h[8*k4+0] += bflo((unsigned)xi.x)*f0.x; h[8*k4+1] += bfhi((unsigned)xi.x)*f0.y;
                h[8*k4+2] += bflo((unsigned)xi.y)*f0.z; h[8*k4+3] += bfhi((unsigned)xi.y)*f0.w;
                h[8*k4+4] += bflo((unsigned)xi.z)*f1.x; h[8*k4+5] += bfhi((unsigned)xi.z)*f1.y;
                h[8*k4+6] += bflo((unsigned)xi.w)*f1.z; h[8*k4+7] += bfhi((unsigned)xi.w)*f1.w;
            }
        }
        const float inv12 = 1.0f/12.0f;
        float sum = 0.f;
        #pragma unroll
        for (int k = 0; k < 16; k++) { h[k] = h[k]*inv12 + conv_b[qt*16 + k]; sum += h[k]; }
        sum += __shfl_xor(sum, 1);
        sum += __shfl_xor(sum, 2);
        float mu = sum * (1.0f/64.0f);
        float var = 0.f;
        #pragma unroll
        for (int k = 0; k < 16; k++) { float xc = h[k] - mu; var += xc*xc; }
        var += __shfl_xor(var, 1);
        var += __shfl_xor(var, 2);
        float rstd = rsqrtf(var*(1.0f/64.0f) + 1e-5f);
        short* dst = reg + lr*72 + qt*16;
        #pragma unroll
        for (int blk = 0; blk < 2; blk++) {
            union { short s[8]; int4 v4; } u;
            #pragma unroll
            for (int jj = 0; jj < 8; jj++) {
                int k = blk*8 + jj, c = qt*16 + k;
                u.s[jj] = f2bf((h[k] - mu)*rstd*ln_g[c] + ln_b[c]);
            }
            *(int4*)(dst + blk*8) = u.v4;
        }
    }
    __builtin_amdgcn_wave_barrier();

    int l   = tid & 63;
    int m16 = l & 15, q = l >> 4;

    bfrag a1[2];
    #pragma unroll
    for (int kc = 0; kc < 2; kc++)
        a1[kc] = *(const bfrag*)(reg + m16*72 + kc*32 + q*8);
    __builtin_amdgcn_wave_barrier();

    f32x4 acc2[4];
    #pragma unroll
    for (int n = 0; n < 4; n++) acc2[n] = (f32x4){0.f, 0.f, 0.f, 0.f};

    for (int ph = 0; ph < 2; ph++) {
        for (int ntl = 0; ntl < 8; ntl++) {
            int nt = ph*8 + ntl;
            f32x4 c0 = (f32x4){0.f,0.f,0.f,0.f};
            #pragma unroll
            for (int kc = 0; kc < 2; kc++) {
                bfrag bb = *(const bfrag*)(W1B + (nt*16 + m16)*64 + kc*32 + q*8);
                c0 = __builtin_amdgcn_mfma_f32_16x16x32_bf16(a1[kc], bb, c0, 0, 0, 0);
            }
            float bias = b1[nt*16 + m16];
            #pragma unroll
            for (int r = 0; r < 4; r++)
                reg[(q*4 + r)*136 + ntl*16 + m16] = f2bf(gelu_f(c0[r] + bias));
        }
        __builtin_amdgcn_wave_barrier();
        for (int kc2 = 0; kc2 < 4; kc2++) {
            bfrag a2 = *(const bfrag*)(reg + m16*136 + kc2*32 + q*8);
            #pragma unroll
            for (int nc = 0; nc < 4; nc++) {
                bfrag bb = *(const bfrag*)(W2B + (nc*16 + m16)*256 + ph*128 + kc2*32 + q*8);
                acc2[nc] = __builtin_amdgcn_mfma_f32_16x16x32_bf16(a2, bb, acc2[nc], 0, 0, 0);
            }
        }
        __builtin_amdgcn_wave_barrier();
    }

    // ---- Epilogue ----
    float p0[4], p1[4];
    #pragma unroll
    for (int r = 0; r < 4; r++) {
        int rowl = 16*w + q*4 + r;
        int row  = blockRow + rowl;
        bool ok  = row < N_ROWS;
        float vals[4];
        #pragma unroll
        for (int nc = 0; nc < 4; nc++) vals[nc] = acc2[nc][r] + pb2[nc*16 + m16];
        if (has_res && ok) {
            #pragma unroll
            for (int nc = 0; nc < 4; nc++)
                vals[nc] += __bfloat162float(x_old[(size_t)row*64 + nc*16 + m16]);
        }
        if (write_x && ok) {
            #pragma unroll
            for (int nc = 0; nc < 4; nc++)
                store_bf16_packed(x_new, row, nc*16, m16, vals[nc]);
        }
        float q0 = 0.f, q1 = 0.f;
        #pragma unroll
        for (int nc = 0; nc < 4; nc++) {
            int c = nc*16 + m16;
            q0 += vals[nc]*Wr[2*c];
            q1 += vals[nc]*Wr[2*c + 1];
        }
        p0[r] = q0; p1[r] = q1;
    }
    #pragma unroll
    for (int s = 1; s < 16; s <<= 1) {
        #pragma unroll
        for (int r = 0; r < 4; r++) {
            p0[r] += __shfl_xor(p0[r], s);
            p1[r] += __shfl_xor(p1[r], s);
        }
    }
    if (m16 == 0) {
        #pragma unroll
        for (int r = 0; r < 4; r++) {
            int row = blockRow + 16*w + q*4 + r;
            if (row < N_ROWS) {
                racc[(size_t)row*4 + lay*2 + 0] = p0[r] + br[0];
                racc[(size_t)row*4 + lay*2 + 1] = p1[r] + br[1];
            }
        }
    }
}

// ---------------------------------------------------------------------------
// K6 (v3): readout — layer-separated racc, two-stage reduction (unchanged)
// ---------------------------------------------------------------------------
__global__ __launch_bounds__(256) void final_kernel(
    const float* __restrict__ racc, const float* __restrict__ ori,
    const int* __restrict__ batch, float* __restrict__ out)
{
    __shared__ float sAcc[64];
    int tid = threadIdx.x;
    if (tid < 64) sAcc[tid] = 0.f;
    __syncthreads();

    int v = blockIdx.x*256 + tid;
    if (v < N_NODES) {
        float srs = 0.f, vx = 0.f, vy = 0.f, vz = 0.f;
        #pragma unroll
        for (int p = 0; p < 12; p++) {
            const float* rr = racc + (size_t)(v*12 + p)*4;
            float r0 = rr[0] + rr[2];
            float r1 = rr[1] + rr[3];
            srs += r0;
            vx += r1*ori[3*p]; vy += r1*ori[3*p+1]; vz += r1*ori[3*p+2];
        }
        const float sc = 1.0f/24.0f;
        int g = batch[v];
        atomicAdd(&sAcc[g],            srs*sc);
        atomicAdd(&sAcc[16 + g*3 + 0], vx*sc);
        atomicAdd(&sAcc[16 + g*3 + 1], vy*sc);
        atomicAdd(&sAcc[16 + g*3 + 2], vz*sc);
    }
    __syncthreads();
    if (tid < 64) atomicAdd(&out[tid], sAcc[tid]);
}

extern "C" void kernel_launch(void* const* d_in, const int* in_sizes, int n_in,
                              void* d_out, int out_size, void* d_ws, size_t ws_size,
                              hipStream_t stream) {
    const float* pos    = (const float*)d_in[0];
    const float* f      = (const float*)d_in[1];
    const float* ori    = (const float*)d_in[2];
    const int*   ei     = (const int*)  d_in[3];
    const int*   batch  = (const int*)  d_in[4];
    const float* Wb1    = (const float*)d_in[5];
    const float* bb1    = (const float*)d_in[6];
    const float* Wb2    = (const float*)d_in[7];
    const float* bb2    = (const float*)d_in[8];
    const float* Wo1    = (const float*)d_in[9];
    const float* bo1    = (const float*)d_in[10];
    const float* Wo2    = (const float*)d_in[11];
    const float* bo2    = (const float*)d_in[12];
    const float* We     = (const float*)d_in[13];
    const float* Wk     = (const float*)d_in[14];
    const float* Wf     = (const float*)d_in[15];
    const float* conv_b = (const float*)d_in[16];
    const float* ln_g   = (const float*)d_in[17];
    const float* ln_b   = (const float*)d_in[18];
    const float* W1     = (const float*)d_in[19];
    const float* b1     = (const float*)d_in[20];
    const float* W2     = (const float*)d_in[21];
    const float* b2     = (const float*)d_in[22];
    const float* Wr     = (const float*)d_in[23];
    const float* br     = (const float*)d_in[24];
    float* out = (float*)d_out;

    float* ws   = (float*)d_ws;
    float* xe   = ws;                               //   640,000 f32
    short* xs1b = (short*)(xe + 640000);            // 7,680,000 bf16
    short* x1b  = xs1b + 7680000;                   // 7,680,000 bf16
    float* racc = (float*)(x1b + 7680000);          //   480,000 f32 (layered)
    float* fkb  = racc + 480000;                    //    18,432
    short* w1b  = (short*)(fkb + 18432);            //    32,768 shorts
    short* w2b  = w1b + 32768;
    short* w1k  = w2b + 32768;
    short* w2k  = w1k + 2048;
    short* wkb  = w2k + 4096;
    int*   deg  = (int*)(wkb + 8192);               //    10,000 ints
    int*   rp   = deg + 10000;
    int*   wp   = rp  + 10001;
    int*   perm = wp  + 10000;
    int*   srcOf= perm+ 80000;
    int*   pad_ = srcOf + 80000;
    __hip_bfloat16* akbA = (__hip_bfloat16*)(pad_ + 3);   // 61,440,000 bf16 (~123 MB)
    __hip_bfloat16* akbB = akbA + 61440000;               // second buffer (full mode)

    size_t need_full = ((char*)(akbB + 61440000)) - ((char*)d_ws);
    int full = (ws_size >= need_full) ? 1 : 0;

    hipMemsetAsync(out,  0, 64*sizeof(float), stream);
    hipMemsetAsync(deg,  0, 10000*sizeof(int), stream);

    csr_count<<<313, 256, 0, stream>>>(ei, deg);
    csr_scan <<<1,   256, 0, stream>>>(deg, rp, wp);
    csr_fill <<<313, 256, 0, stream>>>(ei, wp, perm, srcOf);

    setup_kernel<<<2540, 256, 0, stream>>>(W1, W2, Wb1, Wb2, Wk,
                                           w1b, w2b, w1k, w2k, wkb,
                                           ori, Wo1, bo1, Wo2, bo2, Wf, fkb,
                                           f, We, xe);

    if (full) {
        kb_mfma <<<3750, 256, 0, stream>>>(pos, ori, w1k, bb1, w2k, bb2,
                                           wkb, akbA, wkb + 4096, akbB, /*dual=*/1, ei, perm);
        gather0 <<<30000,256, 0, stream>>>(akbA, srcOf, rp, xe, (__hip_bfloat16*)x1b);
        node_mfma<<<1875,256, 0, stream>>>(x1b, fkb, conv_b, ln_g, ln_b,
                                           w1b, b1, w2b, b2, Wr, br,
                                           (const __hip_bfloat16*)xs1b, (__hip_bfloat16*)xs1b,
                                           racc, /*res=*/0, /*write=*/1, /*lay=*/0);
        gather1 <<<30000,256, 0, stream>>>(akbB, srcOf, rp,
                                           (const __hip_bfloat16*)xs1b, (__hip_bfloat16*)x1b);
    } else {
        kb_mfma <<<3750, 256, 0, stream>>>(pos, ori, w1k, bb1, w2k, bb2,
                                           wkb, akbA, wkb, akbA, /*dual=*/0, ei, perm);
        gather0 <<<30000,256, 0, stream>>>(akbA, srcOf, rp, xe, (__hip_bfloat16*)x1b);
        node_mfma<<<1875,256, 0, stream>>>(x1b, fkb, conv_b, ln_g, ln_b,
                                           w1b, b1, w2b, b2, Wr, br,
                                           (const __hip_bfloat16*)xs1b, (__hip_bfloat16*)xs1b,
                                           racc, /*res=*/0, /*write=*/1, /*lay=*/0);
        kb_mfma <<<3750, 256, 0, stream>>>(pos, ori, w1k, bb1, w2k, bb2,
                                           wkb + 4096, akbA, wkb + 4096, akbA, /*dual=*/0, ei, perm);
        gather1 <<<30000,256, 0, stream>>>(akbA, srcOf, rp,
                                           (const __hip_bfloat16*)xs1b, (__hip_bfloat16*)x1b);
    }

    node_mfma   <<<1875, 256, 0, stream>>>(x1b, fkb + 9216, conv_b + 64, ln_g + 64, ln_b + 64,
                                           w1b + 16384, b1 + 256, w2b + 16384, b2 + 64,
                                           Wr + 128, br + 2,
                                           (const __hip_bfloat16*)xs1b, (__hip_bfloat16*)xs1b,
                                           racc, /*res=*/1, /*write=*/0, /*lay=*/1);

    final_kernel<<<40,   256, 0, stream>>>(racc, ori, batch, out);
}